// Round 1
// baseline (1887.980 us; speedup 1.0000x reference)
//
#include <hip/hip_runtime.h>
#include <math.h>

#define NPG 28
#define EPG 64
#define NB  256
#define NG  512
#define NN  14336
#define NE  32768
#define TEMPINV 10.0f
#define SINK_ITERS 20
#define CW 0.9f

// ---------------------------------------------------------------------------
// Generic fp32 tiled GEMM: C[m, col0+n] (=|+=) relu?(A@W + bias)
// BM=BN=128, BK=8, 256 threads, 8x8 micro-tile per thread.
// CONCAT: A-operand is [A | A2] along K (each 128 wide).
// ---------------------------------------------------------------------------
template<bool RELU, bool ACCUM, bool CONCAT>
__global__ __launch_bounds__(256) void gemm_kernel(
    const float* __restrict__ A, const float* __restrict__ A2, int lda, int K,
    const float* __restrict__ W, int ldw, const float* __restrict__ bias,
    float* __restrict__ C, int ldc, int col0)
{
    __shared__ float As[8][132];   // transposed: As[k][m], pad 132 -> conflict-free
    __shared__ float Bs[8][132];
    const int tid = threadIdx.x;
    const int m0 = blockIdx.x * 128;
    const int n0 = blockIdx.y * 128;
    const int tx = tid & 15, ty = tid >> 4;
    const int arow = tid >> 1;
    const int akq  = (tid & 1) * 4;
    const int brow = tid >> 5;
    const int bcol = (tid & 31) * 4;
    float acc[8][8];
#pragma unroll
    for (int i = 0; i < 8; ++i)
#pragma unroll
        for (int j = 0; j < 8; ++j) acc[i][j] = 0.f;
    const int nch = K >> 3;
    for (int ch = 0; ch < nch; ++ch) {
        const int kc = ch << 3;
        const int ak = kc + akq;
        float4 av;
        if (CONCAT) {
            const float* src = (ak < 128) ? (A  + (size_t)(m0 + arow) * 128 + ak)
                                          : (A2 + (size_t)(m0 + arow) * 128 + (ak - 128));
            av = *(const float4*)src;
        } else {
            av = *(const float4*)(A + (size_t)(m0 + arow) * lda + ak);
        }
        const float4 bv = *(const float4*)(W + (size_t)(kc + brow) * ldw + n0 + bcol);
        As[akq + 0][arow] = av.x;
        As[akq + 1][arow] = av.y;
        As[akq + 2][arow] = av.z;
        As[akq + 3][arow] = av.w;
        *(float4*)&Bs[brow][bcol] = bv;
        __syncthreads();
#pragma unroll
        for (int kk = 0; kk < 8; ++kk) {
            float afr[8], bfr[8];
            *(float4*)&afr[0] = *(const float4*)&As[kk][ty * 8];
            *(float4*)&afr[4] = *(const float4*)&As[kk][ty * 8 + 4];
            *(float4*)&bfr[0] = *(const float4*)&Bs[kk][tx * 8];
            *(float4*)&bfr[4] = *(const float4*)&Bs[kk][tx * 8 + 4];
#pragma unroll
            for (int i = 0; i < 8; ++i)
#pragma unroll
                for (int j = 0; j < 8; ++j) acc[i][j] = fmaf(afr[i], bfr[j], acc[i][j]);
        }
        __syncthreads();
    }
#pragma unroll
    for (int i = 0; i < 8; ++i) {
        const int row = m0 + ty * 8 + i;
        float* crow = C + (size_t)row * ldc + col0 + n0 + tx * 8;
#pragma unroll
        for (int j = 0; j < 8; ++j) {
            float v = acc[i][j];
            if (bias) v += bias[n0 + tx * 8 + j];
            if (RELU) v = fmaxf(v, 0.f);
            if (ACCUM) v += crow[j];
            crow[j] = v;
        }
    }
}

// ---------------------------------------------------------------------------
// Message kernel: one block per graph (64 edges). Assembles the ReLU'd layer-1
// hidden (HP gathers + EC) in LDS in two 128-col halves, GEMMs against W2
// (K=256 -> 128 outputs). pass 0 = forward msg, pass 1 = reverse msg.
// Epilogue: segment-sum into LDS (agg mode) or write f+r (EM mode).
// ---------------------------------------------------------------------------
__device__ __forceinline__ void msg_gemm_pass(
    float (&acc)[4][8], const float* __restrict__ HP, const float* __restrict__ EC,
    const float* __restrict__ W2, int g, int tid, int tx, int ty,
    const int* fidx, const int* tidx, int pass,
    float (*hid_s)[132], float (*Bs)[132])
{
#pragma unroll
    for (int i = 0; i < 4; ++i)
#pragma unroll
        for (int j = 0; j < 8; ++j) acc[i][j] = 0.f;
    for (int half = 0; half < 2; ++half) {
        const int cbase = half << 7;
        {   // build hidden columns [cbase, cbase+128)
            const int i = tid >> 2;
            const int e = g * 64 + i;
            const int fi = fidx[i], ti = tidx[i];
            const float *p1, *p2, *pe;
            if (pass == 0) {
                p1 = HP + (size_t)fi * 1024 + cbase;
                p2 = HP + (size_t)ti * 1024 + 256 + cbase;
                pe = EC + (size_t)e * 512 + cbase;
            } else {
                p1 = HP + (size_t)ti * 1024 + 512 + cbase;
                p2 = HP + (size_t)fi * 1024 + 768 + cbase;
                pe = EC + (size_t)e * 512 + 256 + cbase;
            }
#pragma unroll
            for (int u = 0; u < 8; ++u) {
                const int c = ((tid & 3) << 2) + (u << 4);
                const float4 v1 = *(const float4*)(p1 + c);
                const float4 v2 = *(const float4*)(p2 + c);
                const float4 ve = *(const float4*)(pe + c);
                hid_s[i][c + 0] = fmaxf(v1.x + v2.x + ve.x, 0.f);
                hid_s[i][c + 1] = fmaxf(v1.y + v2.y + ve.y, 0.f);
                hid_s[i][c + 2] = fmaxf(v1.z + v2.z + ve.z, 0.f);
                hid_s[i][c + 3] = fmaxf(v1.w + v2.w + ve.w, 0.f);
            }
        }
        __syncthreads();
        for (int ch = 0; ch < 16; ++ch) {
            const int kc = ch << 3;
            const int brow = tid >> 5, bcol = (tid & 31) << 2;
            const float4 bv = *(const float4*)(W2 + (size_t)(cbase + kc + brow) * 128 + bcol);
            *(float4*)&Bs[brow][bcol] = bv;
            __syncthreads();
#pragma unroll
            for (int kk = 0; kk < 8; ++kk) {
                float bfr[8];
                *(float4*)&bfr[0] = *(const float4*)&Bs[kk][tx * 8];
                *(float4*)&bfr[4] = *(const float4*)&Bs[kk][tx * 8 + 4];
                const float a0 = hid_s[ty +  0][kc + kk];
                const float a1 = hid_s[ty + 16][kc + kk];
                const float a2 = hid_s[ty + 32][kc + kk];
                const float a3 = hid_s[ty + 48][kc + kk];
#pragma unroll
                for (int j = 0; j < 8; ++j) {
                    acc[0][j] = fmaf(a0, bfr[j], acc[0][j]);
                    acc[1][j] = fmaf(a1, bfr[j], acc[1][j]);
                    acc[2][j] = fmaf(a2, bfr[j], acc[2][j]);
                    acc[3][j] = fmaf(a3, bfr[j], acc[3][j]);
                }
            }
            __syncthreads();
        }
    }
}

template<bool EMIT_EM>
__global__ __launch_bounds__(256) void msg_kernel(
    const float* __restrict__ HP, const float* __restrict__ EC,
    const float* __restrict__ W2f, const float* __restrict__ b2f,
    const float* __restrict__ W2r, const float* __restrict__ b2r,
    const int* __restrict__ from_idx, const int* __restrict__ to_idx,
    float* __restrict__ outbuf)   // agg (NN*128) or EM (NE*128)
{
    __shared__ float hid_s[64][132];
    __shared__ float Bs[8][132];
    __shared__ float acc_s[NPG][128];
    __shared__ int fidx[64], tidx[64];
    const int g = blockIdx.x;
    const int tid = threadIdx.x;
    if (tid < 64) {
        fidx[tid] = from_idx[g * 64 + tid];
        tidx[tid] = to_idx[g * 64 + tid];
    }
    if (!EMIT_EM) {
        for (int u = tid; u < NPG * 128; u += 256) (&acc_s[0][0])[u] = 0.f;
    }
    __syncthreads();
    const int tx = tid & 15, ty = tid >> 4;
    float facc[4][8], racc[4][8];
    msg_gemm_pass(facc, HP, EC, W2f, g, tid, tx, ty, fidx, tidx, 0, hid_s, Bs);
    msg_gemm_pass(racc, HP, EC, W2r, g, tid, tx, ty, fidx, tidx, 1, hid_s, Bs);
    if (EMIT_EM) {
#pragma unroll
        for (int i = 0; i < 4; ++i) {
            const int r = ty + 16 * i;
            float* dst = outbuf + (size_t)(g * 64 + r) * 128 + tx * 8;
#pragma unroll
            for (int j = 0; j < 8; ++j) {
                const int col = tx * 8 + j;
                dst[j] = facc[i][j] + b2f[col] + racc[i][j] + b2r[col];
            }
        }
    } else {
#pragma unroll
        for (int i = 0; i < 4; ++i) {
            const int r = ty + 16 * i;
            const int tl = tidx[r] - g * NPG;
            const int fl = fidx[r] - g * NPG;
#pragma unroll
            for (int j = 0; j < 8; ++j) {
                const int col = tx * 8 + j;
                atomicAdd(&acc_s[tl][col], facc[i][j] + b2f[col]);
                atomicAdd(&acc_s[fl][col], racc[i][j] + b2r[col]);
            }
        }
        __syncthreads();
        for (int u = tid; u < NPG * 128; u += 256) {
            const int p = u >> 7, c = u & 127;
            outbuf[(size_t)(g * NPG + p) * 128 + c] = acc_s[p][c];
        }
    }
}

// ---------------------------------------------------------------------------
// Node head: per-batch sk-MLP, mask, 32x32 scores, Sinkhorn(20), node align.
// One block (256 threads) per batch element.
// ---------------------------------------------------------------------------
__global__ __launch_bounds__(256) void node_kernel(
    const float* __restrict__ h,
    const float* __restrict__ w1, const float* __restrict__ b1,
    const float* __restrict__ w2, const float* __restrict__ b2,
    const int* __restrict__ qsz, const int* __restrict__ csz,
    float* __restrict__ plan_out, float* __restrict__ loss_out)
{
    __shared__ float qn[32][128];
    __shared__ float cn[32][128];
    __shared__ float t1[32][64];
    __shared__ float mq[32][68];
    __shared__ float mc[32][68];
    __shared__ float la[32][33];
    __shared__ float red[4];
    const int bb = blockIdx.x;
    const int tid = threadIdx.x;
    const int qs = qsz[bb], cs = csz[bb];
    for (int u = tid * 4; u < 4096; u += 1024) {
        const int p = u >> 7, d = u & 127;
        float4 zq = make_float4(0.f, 0.f, 0.f, 0.f), zc = zq;
        if (p < NPG) {
            zq = *(const float4*)(h + (size_t)((2 * bb) * NPG + p) * 128 + d);
            zc = *(const float4*)(h + (size_t)((2 * bb + 1) * NPG + p) * 128 + d);
        }
        *(float4*)&qn[p][d] = zq;
        *(float4*)&cn[p][d] = zc;
    }
    __syncthreads();
    const int col = tid & 63;
    const int rg  = tid >> 6;
    for (int s = 0; s < 2; ++s) {
        const float (*src)[128] = s ? cn : qn;
        float (*dst)[68] = s ? mc : mq;
        const int sz = s ? cs : qs;
        float a8[8];
#pragma unroll
        for (int u = 0; u < 8; ++u) a8[u] = b1[col];
        for (int k = 0; k < 128; ++k) {
            const float wv = w1[k * 64 + col];
#pragma unroll
            for (int u = 0; u < 8; ++u) a8[u] = fmaf(src[rg + 4 * u][k], wv, a8[u]);
        }
#pragma unroll
        for (int u = 0; u < 8; ++u) t1[rg + 4 * u][col] = fmaxf(a8[u], 0.f);
        __syncthreads();
#pragma unroll
        for (int u = 0; u < 8; ++u) a8[u] = b2[col];
        for (int k = 0; k < 64; ++k) {
            const float wv = w2[k * 64 + col];
#pragma unroll
            for (int u = 0; u < 8; ++u) a8[u] = fmaf(t1[rg + 4 * u][k], wv, a8[u]);
        }
#pragma unroll
        for (int u = 0; u < 8; ++u) {
            const int r = rg + 4 * u;
            dst[r][col] = (r < sz) ? a8[u] : 0.f;
        }
        __syncthreads();
    }
    {   // scores / temp
        const int q = tid >> 3, cg = tid & 7;
#pragma unroll
        for (int u = 0; u < 4; ++u) {
            const int c = cg + 8 * u;
            float s = 0.f;
            for (int d = 0; d < 64; ++d) s = fmaf(mq[q][d], mc[c][d], s);
            la[q][c] = s * TEMPINV;
        }
    }
    __syncthreads();
    const int l8 = tid & 7, rq = tid >> 3;
    for (int it = 0; it < SINK_ITERS; ++it) {
        {   // row (axis=2) logsumexp
            float x[4];
#pragma unroll
            for (int u = 0; u < 4; ++u) x[u] = la[rq][l8 * 4 + u];
            float m = fmaxf(fmaxf(x[0], x[1]), fmaxf(x[2], x[3]));
            m = fmaxf(m, __shfl_xor(m, 1));
            m = fmaxf(m, __shfl_xor(m, 2));
            m = fmaxf(m, __shfl_xor(m, 4));
            float s = expf(x[0] - m) + expf(x[1] - m) + expf(x[2] - m) + expf(x[3] - m);
            s += __shfl_xor(s, 1);
            s += __shfl_xor(s, 2);
            s += __shfl_xor(s, 4);
            const float lse = m + logf(s);
#pragma unroll
            for (int u = 0; u < 4; ++u) la[rq][l8 * 4 + u] = x[u] - lse;
        }
        __syncthreads();
        {   // col (axis=1) logsumexp
            float x[4];
#pragma unroll
            for (int u = 0; u < 4; ++u) x[u] = la[l8 * 4 + u][rq];
            float m = fmaxf(fmaxf(x[0], x[1]), fmaxf(x[2], x[3]));
            m = fmaxf(m, __shfl_xor(m, 1));
            m = fmaxf(m, __shfl_xor(m, 2));
            m = fmaxf(m, __shfl_xor(m, 4));
            float s = expf(x[0] - m) + expf(x[1] - m) + expf(x[2] - m) + expf(x[3] - m);
            s += __shfl_xor(s, 1);
            s += __shfl_xor(s, 2);
            s += __shfl_xor(s, 4);
            const float lse = m + logf(s);
#pragma unroll
            for (int u = 0; u < 4; ++u) la[l8 * 4 + u][rq] = x[u] - lse;
        }
        __syncthreads();
    }
    for (int u = tid; u < 1024; u += 256) {
        const int q = u >> 5, c = u & 31;
        const float p = expf(la[q][c]);
        la[q][c] = p;
        plan_out[(size_t)bb * 1024 + u] = p;
    }
    __syncthreads();
    float lsum = 0.f;
    {
        const int q = tid >> 3, dg = tid & 7;
        for (int u = 0; u < 16; ++u) {
            const int d = dg + 8 * u;
            float pc = 0.f;
#pragma unroll
            for (int c = 0; c < 32; ++c) pc = fmaf(la[q][c], cn[c][d], pc);
            lsum += fmaxf(qn[q][d] - pc, 0.f);
        }
    }
#pragma unroll
    for (int off = 1; off < 64; off <<= 1) lsum += __shfl_xor(lsum, off);
    if ((tid & 63) == 0) red[tid >> 6] = lsum;
    __syncthreads();
    if (tid == 0) loss_out[bb] = -(red[0] + red[1] + red[2] + red[3]);
}

// ---------------------------------------------------------------------------
// Edge head: kron scores from node plan, Sinkhorn(20) on 64x64, edge align.
// One block per batch element. Accumulates CW * loss into loss_out.
// ---------------------------------------------------------------------------
__global__ __launch_bounds__(256) void edge_kernel(
    const float* __restrict__ plan, const float* __restrict__ EM,
    const int* __restrict__ from_idx, const int* __restrict__ to_idx,
    float* __restrict__ loss_out)
{
    __shared__ float T[32][33];
    __shared__ float la[64][65];
    __shared__ float ce[64][128];
    __shared__ int qf[64], qt[64], cfi[64], cti[64];
    __shared__ float red[4];
    const int bb = blockIdx.x;
    const int tid = threadIdx.x;
    for (int u = tid; u < 1024; u += 256) T[u >> 5][u & 31] = plan[(size_t)bb * 1024 + u];
    if (tid < 64) {
        const int gq = 2 * bb, gc = 2 * bb + 1;
        qf[tid]  = from_idx[gq * 64 + tid] - gq * NPG;
        qt[tid]  = to_idx  [gq * 64 + tid] - gq * NPG;
        cfi[tid] = from_idx[gc * 64 + tid] - gc * NPG;
        cti[tid] = to_idx  [gc * 64 + tid] - gc * NPG;
    }
    {
        const int gc = 2 * bb + 1;
        for (int u = tid * 4; u < 8192; u += 1024) {
            const int i = u >> 7, d = u & 127;
            *(float4*)&ce[i][d] = *(const float4*)(EM + (size_t)(gc * 64 + i) * 128 + d);
        }
    }
    __syncthreads();
    {
        const int i = tid >> 2, jg = tid & 3;
        const int a = qf[i], b_ = qt[i];
#pragma unroll
        for (int u = 0; u < 16; ++u) {
            const int j = jg + 4 * u;
            const float s = T[a][cfi[j]] * T[b_][cti[j]] + T[a][cti[j]] * T[b_][cfi[j]];
            la[i][j] = s * TEMPINV;
        }
    }
    __syncthreads();
    const int l4 = tid & 3, rr = tid >> 2;
    for (int it = 0; it < SINK_ITERS; ++it) {
        {
            float x[16];
#pragma unroll
            for (int u = 0; u < 16; ++u) x[u] = la[rr][l4 + 4 * u];
            float m = x[0];
#pragma unroll
            for (int u = 1; u < 16; ++u) m = fmaxf(m, x[u]);
            m = fmaxf(m, __shfl_xor(m, 1));
            m = fmaxf(m, __shfl_xor(m, 2));
            float s = 0.f;
#pragma unroll
            for (int u = 0; u < 16; ++u) s += expf(x[u] - m);
            s += __shfl_xor(s, 1);
            s += __shfl_xor(s, 2);
            const float lse = m + logf(s);
#pragma unroll
            for (int u = 0; u < 16; ++u) la[rr][l4 + 4 * u] = x[u] - lse;
        }
        __syncthreads();
        {
            float x[16];
#pragma unroll
            for (int u = 0; u < 16; ++u) x[u] = la[l4 + 4 * u][rr];
            float m = x[0];
#pragma unroll
            for (int u = 1; u < 16; ++u) m = fmaxf(m, x[u]);
            m = fmaxf(m, __shfl_xor(m, 1));
            m = fmaxf(m, __shfl_xor(m, 2));
            float s = 0.f;
#pragma unroll
            for (int u = 0; u < 16; ++u) s += expf(x[u] - m);
            s += __shfl_xor(s, 1);
            s += __shfl_xor(s, 2);
            const float lse = m + logf(s);
#pragma unroll
            for (int u = 0; u < 16; ++u) la[l4 + 4 * u][rr] = x[u] - lse;
        }
        __syncthreads();
    }
    for (int u = tid; u < 4096; u += 256) la[u >> 6][u & 63] = expf(la[u >> 6][u & 63]);
    __syncthreads();
    float lsum = 0.f;
    {
        const int q = tid >> 2, dg = tid & 3;
        const float* qe = EM + (size_t)((2 * bb) * 64 + q) * 128;
        for (int u = 0; u < 32; ++u) {
            const int d = dg + 4 * u;
            float pc = 0.f;
            for (int c = 0; c < 64; ++c) pc = fmaf(la[q][c], ce[c][d], pc);
            lsum += fmaxf(qe[d] - pc, 0.f);
        }
    }
#pragma unroll
    for (int off = 1; off < 64; off <<= 1) lsum += __shfl_xor(lsum, off);
    if ((tid & 63) == 0) red[tid >> 6] = lsum;
    __syncthreads();
    if (tid == 0) loss_out[bb] -= CW * (red[0] + red[1] + red[2] + red[3]);
}

// ---------------------------------------------------------------------------
extern "C" void kernel_launch(void* const* d_in, const int* in_sizes, int n_in,
                              void* d_out, int out_size, void* d_ws, size_t ws_size,
                              hipStream_t stream)
{
    const float* node_features = (const float*)d_in[0];
    const float* edge_features = (const float*)d_in[1];
    const float* enc_nw  = (const float*)d_in[2];
    const float* enc_nb  = (const float*)d_in[3];
    const float* enc_ew  = (const float*)d_in[4];
    const float* enc_eb  = (const float*)d_in[5];
    const float* msg_w1  = (const float*)d_in[6];
    const float* msg_b1  = (const float*)d_in[7];
    const float* msg_w2  = (const float*)d_in[8];
    const float* msg_b2  = (const float*)d_in[9];
    const float* rmsg_w1 = (const float*)d_in[10];
    const float* rmsg_b1 = (const float*)d_in[11];
    const float* rmsg_w2 = (const float*)d_in[12];
    const float* rmsg_b2 = (const float*)d_in[13];
    const float* upd_w1  = (const float*)d_in[14];
    const float* upd_b1  = (const float*)d_in[15];
    const float* upd_w2  = (const float*)d_in[16];
    const float* upd_b2  = (const float*)d_in[17];
    const float* sk_w1   = (const float*)d_in[18];
    const float* sk_b1   = (const float*)d_in[19];
    const float* sk_w2   = (const float*)d_in[20];
    const float* sk_b2   = (const float*)d_in[21];
    const int* from_idx  = (const int*)d_in[22];
    const int* to_idx    = (const int*)d_in[23];
    const int* qsizes    = (const int*)d_in[24];
    const int* csizes    = (const int*)d_in[25];
    float* out = (float*)d_out;

    // workspace layout (fp32), total 43,253,760 floats = 165 MB
    float* ws   = (float*)d_ws;
    float* h    = ws;                         // NN*128
    float* HP   = h   + (size_t)NN * 128;     // NN*1024
    float* EC   = HP  + (size_t)NN * 1024;    // NE*512 (bias folded in)
    float* EM   = EC  + (size_t)NE * 512;     // NE*128 (also e_enc scratch)
    float* agg  = EM  + (size_t)NE * 128;     // NN*128
    float* hid  = agg + (size_t)NN * 128;     // NN*256
    float* plan = hid + (size_t)NN * 256;     // NB*1024

    const dim3 blk(256);

    // encoders (gemm with K=32)
    gemm_kernel<false, false, false><<<dim3(NN / 128, 1), blk, 0, stream>>>(
        node_features, nullptr, 32, 32, enc_nw, 128, enc_nb, h, 128, 0);
    gemm_kernel<false, false, false><<<dim3(NE / 128, 1), blk, 0, stream>>>(
        edge_features, nullptr, 32, 32, enc_ew, 128, enc_eb, EM, 128, 0);

    // EC = e_enc @ W1[256:384] + b1  (f part cols 0:256, r part cols 256:512)
    gemm_kernel<false, false, false><<<dim3(NE / 128, 2), blk, 0, stream>>>(
        EM, nullptr, 128, 128, msg_w1 + 256 * 256, 256, msg_b1, EC, 512, 0);
    gemm_kernel<false, false, false><<<dim3(NE / 128, 2), blk, 0, stream>>>(
        EM, nullptr, 128, 128, rmsg_w1 + 256 * 256, 256, rmsg_b1, EC, 512, 256);

    for (int step = 0; step < 3; ++step) {
        // HP = h @ {msgW1[0:128], msgW1[128:256], rmsgW1[0:128], rmsgW1[128:256]}
        gemm_kernel<false, false, false><<<dim3(NN / 128, 2), blk, 0, stream>>>(
            h, nullptr, 128, 128, msg_w1, 256, nullptr, HP, 1024, 0);
        gemm_kernel<false, false, false><<<dim3(NN / 128, 2), blk, 0, stream>>>(
            h, nullptr, 128, 128, msg_w1 + 128 * 256, 256, nullptr, HP, 1024, 256);
        gemm_kernel<false, false, false><<<dim3(NN / 128, 2), blk, 0, stream>>>(
            h, nullptr, 128, 128, rmsg_w1, 256, nullptr, HP, 1024, 512);
        gemm_kernel<false, false, false><<<dim3(NN / 128, 2), blk, 0, stream>>>(
            h, nullptr, 128, 128, rmsg_w1 + 128 * 256, 256, nullptr, HP, 1024, 768);
        // messages + segment sum -> agg
        msg_kernel<false><<<NG, blk, 0, stream>>>(
            HP, EC, msg_w2, msg_b2, rmsg_w2, rmsg_b2, from_idx, to_idx, agg);
        // update MLP: hid = relu([agg|h] @ upd_w1 + b1); h += hid @ upd_w2 + b2
        gemm_kernel<true, false, true><<<dim3(NN / 128, 2), blk, 0, stream>>>(
            agg, h, 128, 256, upd_w1, 256, upd_b1, hid, 256, 0);
        gemm_kernel<false, true, false><<<dim3(NN / 128, 1), blk, 0, stream>>>(
            hid, nullptr, 256, 256, upd_w2, 128, upd_b2, h, 128, 0);
    }

    // final messages -> EM = f + r
    gemm_kernel<false, false, false><<<dim3(NN / 128, 2), blk, 0, stream>>>(
        h, nullptr, 128, 128, msg_w1, 256, nullptr, HP, 1024, 0);
    gemm_kernel<false, false, false><<<dim3(NN / 128, 2), blk, 0, stream>>>(
        h, nullptr, 128, 128, msg_w1 + 128 * 256, 256, nullptr, HP, 1024, 256);
    gemm_kernel<false, false, false><<<dim3(NN / 128, 2), blk, 0, stream>>>(
        h, nullptr, 128, 128, rmsg_w1, 256, nullptr, HP, 1024, 512);
    gemm_kernel<false, false, false><<<dim3(NN / 128, 2), blk, 0, stream>>>(
        h, nullptr, 128, 128, rmsg_w1 + 128 * 256, 256, nullptr, HP, 1024, 768);
    msg_kernel<true><<<NG, blk, 0, stream>>>(
        HP, EC, msg_w2, msg_b2, rmsg_w2, rmsg_b2, from_idx, to_idx, EM);

    // heads
    node_kernel<<<NB, blk, 0, stream>>>(
        h, sk_w1, sk_b1, sk_w2, sk_b2, qsizes, csizes, plan, out);
    edge_kernel<<<NB, blk, 0, stream>>>(
        plan, EM, from_idx, to_idx, out);
}

// Round 2
// 1468.144 us; speedup vs baseline: 1.2860x; 1.2860x over previous
//
#include <hip/hip_runtime.h>
#include <math.h>

#define NPG 28
#define EPG 64
#define NB  256
#define NG  512
#define NN  14336
#define NE  32768
#define TEMPINV 10.0f
#define SINK_ITERS 20
#define CW 0.9f

// ---------------------------------------------------------------------------
// Generic fp32 tiled GEMM v2: C[m,n] (=|+=) relu?(A@W + bias)
// BM = TM*16, BN=128, BK=16, 256 threads, TM x 8 micro-tile.
// Software pipeline: prefetch chunk ch+1 into regs while computing chunk ch.
// CONCAT: A-operand is [A | A2] along K (each 128 wide, lda=128).
// ---------------------------------------------------------------------------
template<int TM, bool RELU, bool ACCUM, bool CONCAT>
__global__ __launch_bounds__(256) void gemm2(
    const float* __restrict__ A, const float* __restrict__ A2, int lda, int K,
    const float* __restrict__ W, int ldw, const float* __restrict__ bias,
    float* __restrict__ C, int ldc)
{
    constexpr int BM = TM * 16;
    constexpr int AV = BM / 64;          // float4 A-loads per thread (1 or 2)
    __shared__ float As[16][BM + 4];     // transposed [k][m]
    __shared__ float Bs[16][132];
    const int tid = threadIdx.x;
    const int m0 = blockIdx.x * BM;
    const int n0 = blockIdx.y * 128;
    const int tx = tid & 15, ty = tid >> 4;
    const int arow = (AV == 2) ? (tid >> 1) : (tid >> 2);
    const int a0   = (AV == 2) ? ((tid & 1) * 8) : ((tid & 3) * 4);
    const int brow = ty;                  // 0..15
    const int bcol = tx * 8;
    const int nch = K >> 4;

    float4 aC[AV], bC[2], aN[AV], bN[2];
    float acc[TM][8];
#pragma unroll
    for (int i = 0; i < TM; ++i)
#pragma unroll
        for (int j = 0; j < 8; ++j) acc[i][j] = 0.f;

    {   // prologue: load chunk 0
        const int kk = a0;
        const float* src;
        if (CONCAT) src = A + (size_t)(m0 + arow) * 128 + kk;   // kc=0 < 128
        else        src = A + (size_t)(m0 + arow) * lda + kk;
        aC[0] = *(const float4*)src;
        if (AV == 2) aC[1] = *(const float4*)(src + 4);
        const float* bsrc = W + (size_t)brow * ldw + n0 + bcol;
        bC[0] = *(const float4*)bsrc;
        bC[1] = *(const float4*)(bsrc + 4);
    }

    for (int ch = 0; ch < nch; ++ch) {
        {   // store current chunk to LDS
            const float* f = (const float*)aC;
#pragma unroll
            for (int i = 0; i < AV * 4; ++i) As[a0 + i][arow] = f[i];
            *(float4*)&Bs[brow][bcol]     = bC[0];
            *(float4*)&Bs[brow][bcol + 4] = bC[1];
        }
        __syncthreads();
        if (ch + 1 < nch) {   // prefetch next chunk
            const int kc = (ch + 1) << 4;
            const int kk = kc + a0;
            const float* src;
            if (CONCAT) {
                src = (kc < 128) ? (A  + (size_t)(m0 + arow) * 128 + kk)
                                 : (A2 + (size_t)(m0 + arow) * 128 + (kk - 128));
            } else {
                src = A + (size_t)(m0 + arow) * lda + kk;
            }
            aN[0] = *(const float4*)src;
            if (AV == 2) aN[1] = *(const float4*)(src + 4);
            const float* bsrc = W + (size_t)(kc + brow) * ldw + n0 + bcol;
            bN[0] = *(const float4*)bsrc;
            bN[1] = *(const float4*)(bsrc + 4);
        }
#pragma unroll
        for (int kk = 0; kk < 16; ++kk) {
            float afr[TM], bfr[8];
#pragma unroll
            for (int i = 0; i < TM; i += 4)
                *(float4*)&afr[i] = *(const float4*)&As[kk][ty * TM + i];
            *(float4*)&bfr[0] = *(const float4*)&Bs[kk][tx * 8];
            *(float4*)&bfr[4] = *(const float4*)&Bs[kk][tx * 8 + 4];
#pragma unroll
            for (int i = 0; i < TM; ++i)
#pragma unroll
                for (int j = 0; j < 8; ++j) acc[i][j] = fmaf(afr[i], bfr[j], acc[i][j]);
        }
        __syncthreads();
#pragma unroll
        for (int i = 0; i < AV; ++i) aC[i] = aN[i];
        bC[0] = bN[0]; bC[1] = bN[1];
    }
#pragma unroll
    for (int i = 0; i < TM; ++i) {
        const int row = m0 + ty * TM + i;
        float* crow = C + (size_t)row * ldc + n0 + tx * 8;
#pragma unroll
        for (int j = 0; j < 8; ++j) {
            float v = acc[i][j];
            if (bias) v += bias[n0 + tx * 8 + j];
            if (RELU) v = fmaxf(v, 0.f);
            if (ACCUM) v += crow[j];
            crow[j] = v;
        }
    }
}

// ---------------------------------------------------------------------------
// Message gather-GEMM: out[e,:] = relu(HP[i1]+HP[i2]+EC[e]) @ W2 + b2.
// BM=128 edges, N=128, K=256. blockIdx.y: 0=forward(F), 1=reverse(R).
// Same pipelined structure as gemm2; A assembled from 3 gathered sources.
// ---------------------------------------------------------------------------
__global__ __launch_bounds__(256) void msg_gemm(
    const float* __restrict__ HP, const float* __restrict__ EC,
    const float* __restrict__ W2f, const float* __restrict__ b2f,
    const float* __restrict__ W2r, const float* __restrict__ b2r,
    const int* __restrict__ from_idx, const int* __restrict__ to_idx,
    float* __restrict__ F, float* __restrict__ R)
{
    __shared__ float As[16][132];
    __shared__ float Bs[16][132];
    const int tid = threadIdx.x;
    const int m0 = blockIdx.x * 128;
    const int rev = blockIdx.y;
    const int tx = tid & 15, ty = tid >> 4;
    const int arow = tid >> 1;
    const int a0 = (tid & 1) * 8;
    const int e = m0 + arow;

    const float* W2 = rev ? W2r : W2f;
    const float* b2 = rev ? b2r : b2f;
    float* out = rev ? R : F;
    const int fi = from_idx[e], ti = to_idx[e];
    const float* p1 = rev ? (HP + (size_t)ti * 1024 + 512) : (HP + (size_t)fi * 1024);
    const float* p2 = rev ? (HP + (size_t)fi * 1024 + 768) : (HP + (size_t)ti * 1024 + 256);
    const float* pe = EC + (size_t)e * 512 + (rev ? 256 : 0);

    float4 a1C[2], a2C[2], aeC[2], bC[2];
    float4 a1N[2], a2N[2], aeN[2], bN[2];
    float acc[8][8];
#pragma unroll
    for (int i = 0; i < 8; ++i)
#pragma unroll
        for (int j = 0; j < 8; ++j) acc[i][j] = 0.f;

    {   // prologue chunk 0
        a1C[0] = *(const float4*)(p1 + a0); a1C[1] = *(const float4*)(p1 + a0 + 4);
        a2C[0] = *(const float4*)(p2 + a0); a2C[1] = *(const float4*)(p2 + a0 + 4);
        aeC[0] = *(const float4*)(pe + a0); aeC[1] = *(const float4*)(pe + a0 + 4);
        const float* bsrc = W2 + (size_t)ty * 128 + tx * 8;
        bC[0] = *(const float4*)bsrc; bC[1] = *(const float4*)(bsrc + 4);
    }

    for (int ch = 0; ch < 16; ++ch) {
        {   // combine + relu + store
            const float* f1 = (const float*)a1C;
            const float* f2 = (const float*)a2C;
            const float* fe = (const float*)aeC;
#pragma unroll
            for (int i = 0; i < 8; ++i)
                As[a0 + i][arow] = fmaxf(f1[i] + f2[i] + fe[i], 0.f);
            *(float4*)&Bs[ty][tx * 8]     = bC[0];
            *(float4*)&Bs[ty][tx * 8 + 4] = bC[1];
        }
        __syncthreads();
        if (ch + 1 < 16) {
            const int k = ((ch + 1) << 4) + a0;
            a1N[0] = *(const float4*)(p1 + k); a1N[1] = *(const float4*)(p1 + k + 4);
            a2N[0] = *(const float4*)(p2 + k); a2N[1] = *(const float4*)(p2 + k + 4);
            aeN[0] = *(const float4*)(pe + k); aeN[1] = *(const float4*)(pe + k + 4);
            const float* bsrc = W2 + (size_t)(((ch + 1) << 4) + ty) * 128 + tx * 8;
            bN[0] = *(const float4*)bsrc; bN[1] = *(const float4*)(bsrc + 4);
        }
#pragma unroll
        for (int kk = 0; kk < 16; ++kk) {
            float afr[8], bfr[8];
            *(float4*)&afr[0] = *(const float4*)&As[kk][ty * 8];
            *(float4*)&afr[4] = *(const float4*)&As[kk][ty * 8 + 4];
            *(float4*)&bfr[0] = *(const float4*)&Bs[kk][tx * 8];
            *(float4*)&bfr[4] = *(const float4*)&Bs[kk][tx * 8 + 4];
#pragma unroll
            for (int i = 0; i < 8; ++i)
#pragma unroll
                for (int j = 0; j < 8; ++j) acc[i][j] = fmaf(afr[i], bfr[j], acc[i][j]);
        }
        __syncthreads();
#pragma unroll
        for (int i = 0; i < 2; ++i) { a1C[i] = a1N[i]; a2C[i] = a2N[i]; aeC[i] = aeN[i]; bC[i] = bN[i]; }
    }
#pragma unroll
    for (int i = 0; i < 8; ++i) {
        const int row = m0 + ty * 8 + i;
        float* crow = out + (size_t)row * 128 + tx * 8;
#pragma unroll
        for (int j = 0; j < 8; ++j) crow[j] = acc[i][j] + b2[tx * 8 + j];
    }
}

// ---------------------------------------------------------------------------
// Per-graph segment-sum: agg[n] = sum_{e: to=n} F[e] + sum_{e: from=n} R[e]
// ---------------------------------------------------------------------------
__global__ __launch_bounds__(256) void segsum_kernel(
    const float* __restrict__ F, const float* __restrict__ R,
    const int* __restrict__ from_idx, const int* __restrict__ to_idx,
    float* __restrict__ agg)
{
    __shared__ float acc_s[NPG][128];
    __shared__ int fl[64], tl[64];
    const int g = blockIdx.x;
    const int tid = threadIdx.x;
    for (int u = tid; u < NPG * 128; u += 256) (&acc_s[0][0])[u] = 0.f;
    if (tid < 64) {
        fl[tid] = from_idx[g * 64 + tid] - g * NPG;
        tl[tid] = to_idx[g * 64 + tid] - g * NPG;
    }
    __syncthreads();
    const int col = tid & 127;
    const int eg = tid >> 7;
    for (int i = 0; i < 32; ++i) {
        const int el = eg * 32 + i;
        atomicAdd(&acc_s[tl[el]][col], F[(size_t)(g * 64 + el) * 128 + col]);
        atomicAdd(&acc_s[fl[el]][col], R[(size_t)(g * 64 + el) * 128 + col]);
    }
    __syncthreads();
    for (int u = tid; u < NPG * 128; u += 256)
        agg[(size_t)g * NPG * 128 + u] = (&acc_s[0][0])[u];
}

// F += R (element-wise), used to form EM for the final messages
__global__ __launch_bounds__(256) void add_kernel(float* __restrict__ F, const float* __restrict__ R)
{
    const size_t i = ((size_t)blockIdx.x * 256 + threadIdx.x) * 4;
    float4 a = *(float4*)(F + i);
    const float4 b = *(const float4*)(R + i);
    a.x += b.x; a.y += b.y; a.z += b.z; a.w += b.w;
    *(float4*)(F + i) = a;
}

// ---------------------------------------------------------------------------
// Weight packing (runs once per launch):
//  Whp (128x1024)  = [msg_w1[0:128] | msg_w1[128:256] | rmsg_w1[0:128] | rmsg_w1[128:256]]
//  Wcomb (32x512)  = enc_ew @ [msg_w1[256:384] | rmsg_w1[256:384]]
//  bcomb (512)     = enc_eb @ [...] + [msg_b1 | rmsg_b1]
// ---------------------------------------------------------------------------
__global__ __launch_bounds__(256) void pack_kernel(
    const float* __restrict__ msg_w1, const float* __restrict__ rmsg_w1,
    const float* __restrict__ msg_b1, const float* __restrict__ rmsg_b1,
    const float* __restrict__ enc_ew, const float* __restrict__ enc_eb,
    float* __restrict__ Whp, float* __restrict__ Wcomb, float* __restrict__ bcomb)
{
    const int gid = blockIdx.x, tid = threadIdx.x;
    if (gid < 64) {
        const int idx = gid * 256 + tid;        // 32*512
        const int a = idx >> 9, n = idx & 511;
        const float* Wsrc = (n < 256) ? msg_w1 : rmsg_w1;
        const int nc = n & 255;
        float s = 0.f;
        for (int j = 0; j < 128; ++j)
            s = fmaf(enc_ew[a * 128 + j], Wsrc[(256 + j) * 256 + nc], s);
        Wcomb[idx] = s;
    } else if (gid < 66) {
        const int n = (gid - 64) * 256 + tid;   // 512
        const float* Wsrc = (n < 256) ? msg_w1 : rmsg_w1;
        const float* bsrc = (n < 256) ? msg_b1 : rmsg_b1;
        const int nc = n & 255;
        float s = bsrc[nc];
        for (int j = 0; j < 128; ++j)
            s = fmaf(enc_eb[j], Wsrc[(256 + j) * 256 + nc], s);
        bcomb[n] = s;
    } else {
        const int idx = (gid - 66) * 256 + tid; // 128*1024
        const int k = idx >> 10, n = idx & 1023;
        const int blk = n >> 8, nc = n & 255;
        const float* Wsrc = (blk < 2) ? msg_w1 : rmsg_w1;
        const int krow = (blk & 1) ? (128 + k) : k;
        Whp[idx] = Wsrc[krow * 256 + nc];
    }
}

// ---------------------------------------------------------------------------
// Node head (unchanged from verified round-1 kernel)
// ---------------------------------------------------------------------------
__global__ __launch_bounds__(256) void node_kernel(
    const float* __restrict__ h,
    const float* __restrict__ w1, const float* __restrict__ b1,
    const float* __restrict__ w2, const float* __restrict__ b2,
    const int* __restrict__ qsz, const int* __restrict__ csz,
    float* __restrict__ plan_out, float* __restrict__ loss_out)
{
    __shared__ float qn[32][128];
    __shared__ float cn[32][128];
    __shared__ float t1[32][64];
    __shared__ float mq[32][68];
    __shared__ float mc[32][68];
    __shared__ float la[32][33];
    __shared__ float red[4];
    const int bb = blockIdx.x;
    const int tid = threadIdx.x;
    const int qs = qsz[bb], cs = csz[bb];
    for (int u = tid * 4; u < 4096; u += 1024) {
        const int p = u >> 7, d = u & 127;
        float4 zq = make_float4(0.f, 0.f, 0.f, 0.f), zc = zq;
        if (p < NPG) {
            zq = *(const float4*)(h + (size_t)((2 * bb) * NPG + p) * 128 + d);
            zc = *(const float4*)(h + (size_t)((2 * bb + 1) * NPG + p) * 128 + d);
        }
        *(float4*)&qn[p][d] = zq;
        *(float4*)&cn[p][d] = zc;
    }
    __syncthreads();
    const int col = tid & 63;
    const int rg  = tid >> 6;
    for (int s = 0; s < 2; ++s) {
        const float (*src)[128] = s ? cn : qn;
        float (*dst)[68] = s ? mc : mq;
        const int sz = s ? cs : qs;
        float a8[8];
#pragma unroll
        for (int u = 0; u < 8; ++u) a8[u] = b1[col];
        for (int k = 0; k < 128; ++k) {
            const float wv = w1[k * 64 + col];
#pragma unroll
            for (int u = 0; u < 8; ++u) a8[u] = fmaf(src[rg + 4 * u][k], wv, a8[u]);
        }
#pragma unroll
        for (int u = 0; u < 8; ++u) t1[rg + 4 * u][col] = fmaxf(a8[u], 0.f);
        __syncthreads();
#pragma unroll
        for (int u = 0; u < 8; ++u) a8[u] = b2[col];
        for (int k = 0; k < 64; ++k) {
            const float wv = w2[k * 64 + col];
#pragma unroll
            for (int u = 0; u < 8; ++u) a8[u] = fmaf(t1[rg + 4 * u][k], wv, a8[u]);
        }
#pragma unroll
        for (int u = 0; u < 8; ++u) {
            const int r = rg + 4 * u;
            dst[r][col] = (r < sz) ? a8[u] : 0.f;
        }
        __syncthreads();
    }
    {
        const int q = tid >> 3, cg = tid & 7;
#pragma unroll
        for (int u = 0; u < 4; ++u) {
            const int c = cg + 8 * u;
            float s = 0.f;
            for (int d = 0; d < 64; ++d) s = fmaf(mq[q][d], mc[c][d], s);
            la[q][c] = s * TEMPINV;
        }
    }
    __syncthreads();
    const int l8 = tid & 7, rq = tid >> 3;
    for (int it = 0; it < SINK_ITERS; ++it) {
        {
            float x[4];
#pragma unroll
            for (int u = 0; u < 4; ++u) x[u] = la[rq][l8 * 4 + u];
            float m = fmaxf(fmaxf(x[0], x[1]), fmaxf(x[2], x[3]));
            m = fmaxf(m, __shfl_xor(m, 1));
            m = fmaxf(m, __shfl_xor(m, 2));
            m = fmaxf(m, __shfl_xor(m, 4));
            float s = expf(x[0] - m) + expf(x[1] - m) + expf(x[2] - m) + expf(x[3] - m);
            s += __shfl_xor(s, 1);
            s += __shfl_xor(s, 2);
            s += __shfl_xor(s, 4);
            const float lse = m + logf(s);
#pragma unroll
            for (int u = 0; u < 4; ++u) la[rq][l8 * 4 + u] = x[u] - lse;
        }
        __syncthreads();
        {
            float x[4];
#pragma unroll
            for (int u = 0; u < 4; ++u) x[u] = la[l8 * 4 + u][rq];
            float m = fmaxf(fmaxf(x[0], x[1]), fmaxf(x[2], x[3]));
            m = fmaxf(m, __shfl_xor(m, 1));
            m = fmaxf(m, __shfl_xor(m, 2));
            m = fmaxf(m, __shfl_xor(m, 4));
            float s = expf(x[0] - m) + expf(x[1] - m) + expf(x[2] - m) + expf(x[3] - m);
            s += __shfl_xor(s, 1);
            s += __shfl_xor(s, 2);
            s += __shfl_xor(s, 4);
            const float lse = m + logf(s);
#pragma unroll
            for (int u = 0; u < 4; ++u) la[l8 * 4 + u][rq] = x[u] - lse;
        }
        __syncthreads();
    }
    for (int u = tid; u < 1024; u += 256) {
        const int q = u >> 5, c = u & 31;
        const float p = expf(la[q][c]);
        la[q][c] = p;
        plan_out[(size_t)bb * 1024 + u] = p;
    }
    __syncthreads();
    float lsum = 0.f;
    {
        const int q = tid >> 3, dg = tid & 7;
        for (int u = 0; u < 16; ++u) {
            const int d = dg + 8 * u;
            float pc = 0.f;
#pragma unroll
            for (int c = 0; c < 32; ++c) pc = fmaf(la[q][c], cn[c][d], pc);
            lsum += fmaxf(qn[q][d] - pc, 0.f);
        }
    }
#pragma unroll
    for (int off = 1; off < 64; off <<= 1) lsum += __shfl_xor(lsum, off);
    if ((tid & 63) == 0) red[tid >> 6] = lsum;
    __syncthreads();
    if (tid == 0) loss_out[bb] = -(red[0] + red[1] + red[2] + red[3]);
}

// ---------------------------------------------------------------------------
// Edge head (unchanged from verified round-1 kernel; EM passed as F after F+=R)
// ---------------------------------------------------------------------------
__global__ __launch_bounds__(256) void edge_kernel(
    const float* __restrict__ plan, const float* __restrict__ EM,
    const int* __restrict__ from_idx, const int* __restrict__ to_idx,
    float* __restrict__ loss_out)
{
    __shared__ float T[32][33];
    __shared__ float la[64][65];
    __shared__ float ce[64][128];
    __shared__ int qf[64], qt[64], cfi[64], cti[64];
    __shared__ float red[4];
    const int bb = blockIdx.x;
    const int tid = threadIdx.x;
    for (int u = tid; u < 1024; u += 256) T[u >> 5][u & 31] = plan[(size_t)bb * 1024 + u];
    if (tid < 64) {
        const int gq = 2 * bb, gc = 2 * bb + 1;
        qf[tid]  = from_idx[gq * 64 + tid] - gq * NPG;
        qt[tid]  = to_idx  [gq * 64 + tid] - gq * NPG;
        cfi[tid] = from_idx[gc * 64 + tid] - gc * NPG;
        cti[tid] = to_idx  [gc * 64 + tid] - gc * NPG;
    }
    {
        const int gc = 2 * bb + 1;
        for (int u = tid * 4; u < 8192; u += 1024) {
            const int i = u >> 7, d = u & 127;
            *(float4*)&ce[i][d] = *(const float4*)(EM + (size_t)(gc * 64 + i) * 128 + d);
        }
    }
    __syncthreads();
    {
        const int i = tid >> 2, jg = tid & 3;
        const int a = qf[i], b_ = qt[i];
#pragma unroll
        for (int u = 0; u < 16; ++u) {
            const int j = jg + 4 * u;
            const float s = T[a][cfi[j]] * T[b_][cti[j]] + T[a][cti[j]] * T[b_][cfi[j]];
            la[i][j] = s * TEMPINV;
        }
    }
    __syncthreads();
    const int l4 = tid & 3, rr = tid >> 2;
    for (int it = 0; it < SINK_ITERS; ++it) {
        {
            float x[16];
#pragma unroll
            for (int u = 0; u < 16; ++u) x[u] = la[rr][l4 + 4 * u];
            float m = x[0];
#pragma unroll
            for (int u = 1; u < 16; ++u) m = fmaxf(m, x[u]);
            m = fmaxf(m, __shfl_xor(m, 1));
            m = fmaxf(m, __shfl_xor(m, 2));
            float s = 0.f;
#pragma unroll
            for (int u = 0; u < 16; ++u) s += expf(x[u] - m);
            s += __shfl_xor(s, 1);
            s += __shfl_xor(s, 2);
            const float lse = m + logf(s);
#pragma unroll
            for (int u = 0; u < 16; ++u) la[rr][l4 + 4 * u] = x[u] - lse;
        }
        __syncthreads();
        {
            float x[16];
#pragma unroll
            for (int u = 0; u < 16; ++u) x[u] = la[l4 + 4 * u][rr];
            float m = x[0];
#pragma unroll
            for (int u = 1; u < 16; ++u) m = fmaxf(m, x[u]);
            m = fmaxf(m, __shfl_xor(m, 1));
            m = fmaxf(m, __shfl_xor(m, 2));
            float s = 0.f;
#pragma unroll
            for (int u = 0; u < 16; ++u) s += expf(x[u] - m);
            s += __shfl_xor(s, 1);
            s += __shfl_xor(s, 2);
            const float lse = m + logf(s);
#pragma unroll
            for (int u = 0; u < 16; ++u) la[l4 + 4 * u][rr] = x[u] - lse;
        }
        __syncthreads();
    }
    for (int u = tid; u < 4096; u += 256) la[u >> 6][u & 63] = expf(la[u >> 6][u & 63]);
    __syncthreads();
    float lsum = 0.f;
    {
        const int q = tid >> 2, dg = tid & 3;
        const float* qe = EM + (size_t)((2 * bb) * 64 + q) * 128;
        for (int u = 0; u < 32; ++u) {
            const int d = dg + 4 * u;
            float pc = 0.f;
            for (int c = 0; c < 64; ++c) pc = fmaf(la[q][c], ce[c][d], pc);
            lsum += fmaxf(qe[d] - pc, 0.f);
        }
    }
#pragma unroll
    for (int off = 1; off < 64; off <<= 1) lsum += __shfl_xor(lsum, off);
    if ((tid & 63) == 0) red[tid >> 6] = lsum;
    __syncthreads();
    if (tid == 0) loss_out[bb] -= CW * (red[0] + red[1] + red[2] + red[3]);
}

// ---------------------------------------------------------------------------
extern "C" void kernel_launch(void* const* d_in, const int* in_sizes, int n_in,
                              void* d_out, int out_size, void* d_ws, size_t ws_size,
                              hipStream_t stream)
{
    const float* node_features = (const float*)d_in[0];
    const float* edge_features = (const float*)d_in[1];
    const float* enc_nw  = (const float*)d_in[2];
    const float* enc_nb  = (const float*)d_in[3];
    const float* enc_ew  = (const float*)d_in[4];
    const float* enc_eb  = (const float*)d_in[5];
    const float* msg_w1  = (const float*)d_in[6];
    const float* msg_b1  = (const float*)d_in[7];
    const float* msg_w2  = (const float*)d_in[8];
    const float* msg_b2  = (const float*)d_in[9];
    const float* rmsg_w1 = (const float*)d_in[10];
    const float* rmsg_b1 = (const float*)d_in[11];
    const float* rmsg_w2 = (const float*)d_in[12];
    const float* rmsg_b2 = (const float*)d_in[13];
    const float* upd_w1  = (const float*)d_in[14];
    const float* upd_b1  = (const float*)d_in[15];
    const float* upd_w2  = (const float*)d_in[16];
    const float* upd_b2  = (const float*)d_in[17];
    const float* sk_w1   = (const float*)d_in[18];
    const float* sk_b1   = (const float*)d_in[19];
    const float* sk_w2   = (const float*)d_in[20];
    const float* sk_b2   = (const float*)d_in[21];
    const int* from_idx  = (const int*)d_in[22];
    const int* to_idx    = (const int*)d_in[23];
    const int* qsizes    = (const int*)d_in[24];
    const int* csizes    = (const int*)d_in[25];
    float* out = (float*)d_out;

    // workspace layout (fp32), ~42.1M floats = 168.4 MB
    float* ws    = (float*)d_ws;
    float* h     = ws;                           // NN*128
    float* EC    = h    + (size_t)NN * 128;      // NE*512
    float* HP    = EC   + (size_t)NE * 512;      // NN*1024 (agg/hid alias inside)
    float* F     = HP   + (size_t)NN * 1024;     // NE*128 (becomes EM after F+=R)
    float* R     = F    + (size_t)NE * 128;      // NE*128
    float* plan  = R    + (size_t)NE * 128;      // NB*1024
    float* Whp   = plan + (size_t)NB * 1024;     // 128*1024
    float* Wcomb = Whp  + 131072;                // 32*512
    float* bcomb = Wcomb + 16384;                // 512
    float* agg   = HP;                           // NN*128 (alias: HP free at that point)
    float* hid   = HP + 2097152;                 // NN*256 (alias, disjoint from agg)

    const dim3 blk(256);

    pack_kernel<<<578, blk, 0, stream>>>(msg_w1, rmsg_w1, msg_b1, rmsg_b1,
                                         enc_ew, enc_eb, Whp, Wcomb, bcomb);
    // node encoder: h = nf(NN x 32) @ enc_nw + enc_nb
    gemm2<4, false, false, false><<<dim3(NN / 64, 1), blk, 0, stream>>>(
        node_features, nullptr, 32, 32, enc_nw, 128, enc_nb, h, 128);
    // EC = ef(NE x 32) @ Wcomb(32 x 512) + bcomb   (edge encoder folded in)
    gemm2<8, false, false, false><<<dim3(NE / 128, 4), blk, 0, stream>>>(
        edge_features, nullptr, 32, 32, Wcomb, 512, bcomb, EC, 512);

    for (int step = 0; step < 3; ++step) {
        gemm2<8, false, false, false><<<dim3(NN / 128, 8), blk, 0, stream>>>(
            h, nullptr, 128, 128, Whp, 1024, nullptr, HP, 1024);
        msg_gemm<<<dim3(NE / 128, 2), blk, 0, stream>>>(
            HP, EC, msg_w2, msg_b2, rmsg_w2, rmsg_b2, from_idx, to_idx, F, R);
        segsum_kernel<<<NG, blk, 0, stream>>>(F, R, from_idx, to_idx, agg);
        gemm2<4, true, false, true><<<dim3(NN / 64, 2), blk, 0, stream>>>(
            agg, h, 128, 256, upd_w1, 256, upd_b1, hid, 256);
        gemm2<4, false, true, false><<<dim3(NN / 64, 1), blk, 0, stream>>>(
            hid, nullptr, 256, 256, upd_w2, 128, upd_b2, h, 128);
    }

    // final messages -> EM = F + R (stored in F)
    gemm2<8, false, false, false><<<dim3(NN / 128, 8), blk, 0, stream>>>(
        h, nullptr, 128, 128, Whp, 1024, nullptr, HP, 1024);
    msg_gemm<<<dim3(NE / 128, 2), blk, 0, stream>>>(
        HP, EC, msg_w2, msg_b2, rmsg_w2, rmsg_b2, from_idx, to_idx, F, R);
    add_kernel<<<dim3((NE * 128) / 1024), blk, 0, stream>>>(F, R);

    node_kernel<<<NB, blk, 0, stream>>>(
        h, sk_w1, sk_b1, sk_w2, sk_b2, qsizes, csizes, plan, out);
    edge_kernel<<<NB, blk, 0, stream>>>(
        plan, F, from_idx, to_idx, out);
}

// Round 3
// 720.056 us; speedup vs baseline: 2.6220x; 2.0389x over previous
//
#include <hip/hip_runtime.h>
#include <math.h>

#define NPG 28
#define EPG 64
#define NB  256
#define NG  512
#define NN  14336
#define NE  32768
#define TEMPINV 10.0f
#define SINK_ITERS 20
#define CW 0.9f

typedef unsigned int uint;
typedef unsigned short ushort;
typedef __attribute__((ext_vector_type(8))) __bf16 bf16x8;
typedef __attribute__((ext_vector_type(4))) float f32x4;

__device__ __forceinline__ ushort f2bf(float x) {
    uint u = __float_as_uint(x);
    u += 0x7fffu + ((u >> 16) & 1u);
    return (ushort)(u >> 16);
}
__device__ __forceinline__ float bflo(uint w) { return __uint_as_float(w << 16); }
__device__ __forceinline__ float bfhi(uint w) { return __uint_as_float(w & 0xffff0000u); }
__device__ __forceinline__ uint relu_sum_pk(uint w1, uint w2, uint w3) {
    float lo = fmaxf(bflo(w1) + bflo(w2) + bflo(w3), 0.f);
    float hi = fmaxf(bfhi(w1) + bfhi(w2) + bfhi(w3), 0.f);
    return (uint)f2bf(lo) | ((uint)f2bf(hi) << 16);
}
__device__ __forceinline__ f32x4 mfma16(bf16x8 a, bf16x8 b, f32x4 c) {
    return __builtin_amdgcn_mfma_f32_16x16x32_bf16(a, b, c, 0, 0, 0);
}

// ---------------------------------------------------------------------------
// Direct-fragment bf16 MFMA GEMM. A: M x (KT*32) row-major bf16 (lda elems).
// BT: N x (KT*32) row-major bf16 (weights pre-transposed, k contiguous).
// Block = 256 thr = 4 waves (2x2), tile 128x128, wave tile 64x64 (4x4 MFMA).
// CONCAT: k < KT*16 from A, else from A2 (both lda wide).
// ---------------------------------------------------------------------------
template<int KT, bool BIAS, bool RELU, bool ACCUM, bool OUTBF, bool OUT2, bool CONCAT>
__global__ __launch_bounds__(256) void mfma_gemm(
    const ushort* __restrict__ A, const ushort* __restrict__ A2, int lda,
    const ushort* __restrict__ BT, const float* __restrict__ bias,
    float* __restrict__ Cf, ushort* __restrict__ Cb, int ldc)
{
    const int tid = threadIdx.x;
    const int w = tid >> 6, lane = tid & 63;
    const int li = lane & 15, quad = lane >> 4;
    const int wm = w >> 1, wn = w & 1;
    const int m0 = blockIdx.x * 128 + wm * 64;
    const int n0 = blockIdx.y * 128 + wn * 64;

    const ushort* pa[4]; const ushort* pa2[4]; const ushort* pb[4];
#pragma unroll
    for (int mi = 0; mi < 4; ++mi) {
        const int row = m0 + mi * 16 + li;
        pa[mi] = A + (size_t)row * lda + quad * 8;
        if (CONCAT) pa2[mi] = A2 + (size_t)row * lda + quad * 8;
    }
#pragma unroll
    for (int ni = 0; ni < 4; ++ni)
        pb[ni] = BT + (size_t)(n0 + ni * 16 + li) * (KT * 32) + quad * 8;

    f32x4 acc[4][4];
#pragma unroll
    for (int i = 0; i < 4; ++i)
#pragma unroll
        for (int j = 0; j < 4; ++j) acc[i][j] = f32x4{0.f, 0.f, 0.f, 0.f};

    uint4 ar[4], br[4], an[4], bn[4];
#pragma unroll
    for (int mi = 0; mi < 4; ++mi) ar[mi] = *(const uint4*)pa[mi];
#pragma unroll
    for (int ni = 0; ni < 4; ++ni) br[ni] = *(const uint4*)pb[ni];

#pragma unroll
    for (int kb = 0; kb < KT; ++kb) {
        if (kb + 1 < KT) {
            const int off = (kb + 1) * 32;
#pragma unroll
            for (int mi = 0; mi < 4; ++mi) {
                if (CONCAT && (kb + 1) >= KT / 2)
                    an[mi] = *(const uint4*)(pa2[mi] + off - (KT / 2) * 32);
                else
                    an[mi] = *(const uint4*)(pa[mi] + off);
            }
#pragma unroll
            for (int ni = 0; ni < 4; ++ni) bn[ni] = *(const uint4*)(pb[ni] + off);
        }
        bf16x8 a[4], b[4];
#pragma unroll
        for (int mi = 0; mi < 4; ++mi) a[mi] = __builtin_bit_cast(bf16x8, ar[mi]);
#pragma unroll
        for (int ni = 0; ni < 4; ++ni) b[ni] = __builtin_bit_cast(bf16x8, br[ni]);
#pragma unroll
        for (int mi = 0; mi < 4; ++mi)
#pragma unroll
            for (int ni = 0; ni < 4; ++ni)
                acc[mi][ni] = mfma16(a[mi], b[ni], acc[mi][ni]);
        if (kb + 1 < KT) {
#pragma unroll
            for (int mi = 0; mi < 4; ++mi) ar[mi] = an[mi];
#pragma unroll
            for (int ni = 0; ni < 4; ++ni) br[ni] = bn[ni];
        }
    }

    float bv[4];
#pragma unroll
    for (int ni = 0; ni < 4; ++ni) bv[ni] = BIAS ? bias[n0 + ni * 16 + li] : 0.f;
#pragma unroll
    for (int mi = 0; mi < 4; ++mi) {
#pragma unroll
        for (int ni = 0; ni < 4; ++ni) {
            const int ncol = n0 + ni * 16 + li;
#pragma unroll
            for (int r = 0; r < 4; ++r) {
                const int rowr = m0 + mi * 16 + quad * 4 + r;
                float v = acc[mi][ni][r] + bv[ni];
                if (RELU) v = fmaxf(v, 0.f);
                const size_t idx = (size_t)rowr * ldc + ncol;
                if (ACCUM) v += Cf[idx];
                if (OUTBF) {
                    Cb[idx] = f2bf(v);
                } else {
                    Cf[idx] = v;
                    if (OUT2) Cb[idx] = f2bf(v);
                }
            }
        }
    }
}

// ---------------------------------------------------------------------------
// Message MFMA GEMM: out[e,n] = relu(HP[i1]+HP[i2]+EC[e]) @ W2T + b2.
// K=256 (8 kb). grid (NE/128, 2): y=0 forward -> F, y=1 reverse -> R.
// A-fragments assembled on the fly (bf16 gather + fp32 relu-sum + RNE repack).
// ---------------------------------------------------------------------------
__global__ __launch_bounds__(256) void msg_mfma(
    const ushort* __restrict__ HP, const ushort* __restrict__ EC,
    const ushort* __restrict__ W2fT, const ushort* __restrict__ W2rT,
    const float* __restrict__ b2f, const float* __restrict__ b2r,
    const int* __restrict__ from_idx, const int* __restrict__ to_idx,
    float* __restrict__ F, float* __restrict__ R)
{
    const int tid = threadIdx.x;
    const int w = tid >> 6, lane = tid & 63;
    const int li = lane & 15, quad = lane >> 4;
    const int wm = w >> 1, wn = w & 1;
    const int m0 = blockIdx.x * 128 + wm * 64;
    const int n0 = wn * 64;
    const int rev = blockIdx.y;
    const ushort* BT = rev ? W2rT : W2fT;
    const float* bias = rev ? b2r : b2f;
    float* out = rev ? R : F;

    const ushort *p1[4], *p2[4], *pe[4];
#pragma unroll
    for (int mi = 0; mi < 4; ++mi) {
        const int e = m0 + mi * 16 + li;
        const int fi = from_idx[e], ti = to_idx[e];
        const int i1 = rev ? ti : fi;
        const int i2 = rev ? fi : ti;
        p1[mi] = HP + (size_t)i1 * 1024 + (rev ? 512 : 0) + quad * 8;
        p2[mi] = HP + (size_t)i2 * 1024 + (rev ? 768 : 256) + quad * 8;
        pe[mi] = EC + (size_t)e * 512 + (rev ? 256 : 0) + quad * 8;
    }
    const ushort* pb[4];
#pragma unroll
    for (int ni = 0; ni < 4; ++ni)
        pb[ni] = BT + (size_t)(n0 + ni * 16 + li) * 256 + quad * 8;

    f32x4 acc[4][4];
#pragma unroll
    for (int i = 0; i < 4; ++i)
#pragma unroll
        for (int j = 0; j < 4; ++j) acc[i][j] = f32x4{0.f, 0.f, 0.f, 0.f};

#pragma unroll
    for (int kb = 0; kb < 8; ++kb) {
        const int off = kb * 32;
        bf16x8 a[4], b[4];
#pragma unroll
        for (int ni = 0; ni < 4; ++ni)
            b[ni] = __builtin_bit_cast(bf16x8, *(const uint4*)(pb[ni] + off));
#pragma unroll
        for (int mi = 0; mi < 4; ++mi) {
            const uint4 u1 = *(const uint4*)(p1[mi] + off);
            const uint4 u2 = *(const uint4*)(p2[mi] + off);
            const uint4 ue = *(const uint4*)(pe[mi] + off);
            uint4 o;
            o.x = relu_sum_pk(u1.x, u2.x, ue.x);
            o.y = relu_sum_pk(u1.y, u2.y, ue.y);
            o.z = relu_sum_pk(u1.z, u2.z, ue.z);
            o.w = relu_sum_pk(u1.w, u2.w, ue.w);
            a[mi] = __builtin_bit_cast(bf16x8, o);
        }
#pragma unroll
        for (int mi = 0; mi < 4; ++mi)
#pragma unroll
            for (int ni = 0; ni < 4; ++ni)
                acc[mi][ni] = mfma16(a[mi], b[ni], acc[mi][ni]);
    }

    float bv[4];
#pragma unroll
    for (int ni = 0; ni < 4; ++ni) bv[ni] = bias[n0 + ni * 16 + li];
#pragma unroll
    for (int mi = 0; mi < 4; ++mi) {
#pragma unroll
        for (int ni = 0; ni < 4; ++ni) {
            const int ncol = n0 + ni * 16 + li;
#pragma unroll
            for (int r = 0; r < 4; ++r) {
                const int rowr = m0 + mi * 16 + quad * 4 + r;
                out[(size_t)rowr * 128 + ncol] = acc[mi][ni][r] + bv[ni];
            }
        }
    }
}

// ---------------------------------------------------------------------------
// Generic fp32 tiled GEMM (round-2 verified core) for the K=32 encoders.
// ---------------------------------------------------------------------------
template<int TM, bool OUTBF>
__global__ __launch_bounds__(256) void gemm2(
    const float* __restrict__ A, int lda, int K,
    const float* __restrict__ W, int ldw, const float* __restrict__ bias,
    float* __restrict__ C, ushort* __restrict__ Cb, int ldc)
{
    constexpr int BM = TM * 16;
    constexpr int AV = BM / 64;
    __shared__ float As[16][BM + 4];
    __shared__ float Bs[16][132];
    const int tid = threadIdx.x;
    const int m0 = blockIdx.x * BM;
    const int n0 = blockIdx.y * 128;
    const int tx = tid & 15, ty = tid >> 4;
    const int arow = (AV == 2) ? (tid >> 1) : (tid >> 2);
    const int a0   = (AV == 2) ? ((tid & 1) * 8) : ((tid & 3) * 4);
    const int brow = ty;
    const int bcol = tx * 8;
    const int nch = K >> 4;

    float4 aC[AV], bC[2], aN[AV], bN[2];
    float acc[TM][8];
#pragma unroll
    for (int i = 0; i < TM; ++i)
#pragma unroll
        for (int j = 0; j < 8; ++j) acc[i][j] = 0.f;

    {
        const float* src = A + (size_t)(m0 + arow) * lda + a0;
        aC[0] = *(const float4*)src;
        if (AV == 2) aC[1] = *(const float4*)(src + 4);
        const float* bsrc = W + (size_t)brow * ldw + n0 + bcol;
        bC[0] = *(const float4*)bsrc;
        bC[1] = *(const float4*)(bsrc + 4);
    }

    for (int ch = 0; ch < nch; ++ch) {
        {
            const float* f = (const float*)aC;
#pragma unroll
            for (int i = 0; i < AV * 4; ++i) As[a0 + i][arow] = f[i];
            *(float4*)&Bs[brow][bcol]     = bC[0];
            *(float4*)&Bs[brow][bcol + 4] = bC[1];
        }
        __syncthreads();
        if (ch + 1 < nch) {
            const int kc = (ch + 1) << 4;
            const float* src = A + (size_t)(m0 + arow) * lda + kc + a0;
            aN[0] = *(const float4*)src;
            if (AV == 2) aN[1] = *(const float4*)(src + 4);
            const float* bsrc = W + (size_t)(kc + brow) * ldw + n0 + bcol;
            bN[0] = *(const float4*)bsrc;
            bN[1] = *(const float4*)(bsrc + 4);
        }
#pragma unroll
        for (int kk = 0; kk < 16; ++kk) {
            float afr[TM], bfr[8];
#pragma unroll
            for (int i = 0; i < TM; i += 4)
                *(float4*)&afr[i] = *(const float4*)&As[kk][ty * TM + i];
            *(float4*)&bfr[0] = *(const float4*)&Bs[kk][tx * 8];
            *(float4*)&bfr[4] = *(const float4*)&Bs[kk][tx * 8 + 4];
#pragma unroll
            for (int i = 0; i < TM; ++i)
#pragma unroll
                for (int j = 0; j < 8; ++j) acc[i][j] = fmaf(afr[i], bfr[j], acc[i][j]);
        }
        __syncthreads();
#pragma unroll
        for (int i = 0; i < AV; ++i) aC[i] = aN[i];
        bC[0] = bN[0]; bC[1] = bN[1];
    }
#pragma unroll
    for (int i = 0; i < TM; ++i) {
        const int row = m0 + ty * TM + i;
#pragma unroll
        for (int j = 0; j < 8; ++j) {
            const int col = n0 + tx * 8 + j;
            float v = acc[i][j] + bias[col];
            if (OUTBF) Cb[(size_t)row * ldc + col] = f2bf(v);
            else       C [(size_t)row * ldc + col] = v;
        }
    }
}

// fp32 -> bf16 convert (8 elems/thread)
__global__ __launch_bounds__(256) void cvt_bf(const float* __restrict__ src, ushort* __restrict__ dst)
{
    const size_t i = ((size_t)blockIdx.x * 256 + threadIdx.x) * 8;
    const float4 v0 = *(const float4*)(src + i);
    const float4 v1 = *(const float4*)(src + i + 4);
    uint4 o;
    o.x = (uint)f2bf(v0.x) | ((uint)f2bf(v0.y) << 16);
    o.y = (uint)f2bf(v0.z) | ((uint)f2bf(v0.w) << 16);
    o.z = (uint)f2bf(v1.x) | ((uint)f2bf(v1.y) << 16);
    o.w = (uint)f2bf(v1.z) | ((uint)f2bf(v1.w) << 16);
    *(uint4*)(dst + i) = o;
}

// ---------------------------------------------------------------------------
// Per-graph segment-sum (fp32 in, bf16 out for upd1's A operand)
// ---------------------------------------------------------------------------
__global__ __launch_bounds__(256) void segsum_kernel(
    const float* __restrict__ F, const float* __restrict__ R,
    const int* __restrict__ from_idx, const int* __restrict__ to_idx,
    ushort* __restrict__ agg)
{
    __shared__ float acc_s[NPG][128];
    __shared__ int fl[64], tl[64];
    const int g = blockIdx.x;
    const int tid = threadIdx.x;
    for (int u = tid; u < NPG * 128; u += 256) (&acc_s[0][0])[u] = 0.f;
    if (tid < 64) {
        fl[tid] = from_idx[g * 64 + tid] - g * NPG;
        tl[tid] = to_idx[g * 64 + tid] - g * NPG;
    }
    __syncthreads();
    const int col = tid & 127;
    const int eg = tid >> 7;
    for (int i = 0; i < 32; ++i) {
        const int el = eg * 32 + i;
        atomicAdd(&acc_s[tl[el]][col], F[(size_t)(g * 64 + el) * 128 + col]);
        atomicAdd(&acc_s[fl[el]][col], R[(size_t)(g * 64 + el) * 128 + col]);
    }
    __syncthreads();
    for (int u = tid; u < NPG * 128; u += 256)
        agg[(size_t)g * NPG * 128 + u] = f2bf((&acc_s[0][0])[u]);
}

__global__ __launch_bounds__(256) void add_kernel(float* __restrict__ F, const float* __restrict__ R)
{
    const size_t i = ((size_t)blockIdx.x * 256 + threadIdx.x) * 4;
    float4 a = *(float4*)(F + i);
    const float4 b = *(const float4*)(R + i);
    a.x += b.x; a.y += b.y; a.z += b.z; a.w += b.w;
    *(float4*)(F + i) = a;
}

// ---------------------------------------------------------------------------
// Weight packing: Wcomb/bcomb fp32 (edge-encoder fold), all GEMM weights to
// bf16 in N x K (transposed, k-contiguous) fragment-friendly layout.
// ---------------------------------------------------------------------------
__global__ __launch_bounds__(256) void pack2(
    const float* __restrict__ msg_w1, const float* __restrict__ rmsg_w1,
    const float* __restrict__ msg_b1, const float* __restrict__ rmsg_b1,
    const float* __restrict__ enc_ew, const float* __restrict__ enc_eb,
    const float* __restrict__ msg_w2, const float* __restrict__ rmsg_w2,
    const float* __restrict__ upd_w1, const float* __restrict__ upd_w2,
    float* __restrict__ Wcomb, float* __restrict__ bcomb,
    ushort* __restrict__ WhpT, ushort* __restrict__ W2fT, ushort* __restrict__ W2rT,
    ushort* __restrict__ UW1T, ushort* __restrict__ UW2T)
{
    const int gid = blockIdx.x, tid = threadIdx.x;
    if (gid < 64) {                       // Wcomb: 32 x 512 fp32
        const int idx = gid * 256 + tid;
        const int a = idx >> 9, n = idx & 511;
        const float* Wsrc = (n < 256) ? msg_w1 : rmsg_w1;
        const int nc = n & 255;
        float s = 0.f;
        for (int j = 0; j < 128; ++j)
            s = fmaf(enc_ew[a * 128 + j], Wsrc[(256 + j) * 256 + nc], s);
        Wcomb[idx] = s;
    } else if (gid < 66) {                // bcomb: 512 fp32
        const int n = (gid - 64) * 256 + tid;
        const float* Wsrc = (n < 256) ? msg_w1 : rmsg_w1;
        const float* bsrc = (n < 256) ? msg_b1 : rmsg_b1;
        const int nc = n & 255;
        float s = bsrc[nc];
        for (int j = 0; j < 128; ++j)
            s = fmaf(enc_eb[j], Wsrc[(256 + j) * 256 + nc], s);
        bcomb[n] = s;
    } else if (gid < 578) {               // WhpT: 1024 x 128 bf16
        const int idx = (gid - 66) * 256 + tid;
        const int n = idx >> 7, k = idx & 127;
        const float* Wsrc = (n < 512) ? msg_w1 : rmsg_w1;
        const int part = (n >> 8) & 1, col = n & 255;
        WhpT[idx] = f2bf(Wsrc[(part * 128 + k) * 256 + col]);
    } else if (gid < 706) {               // W2fT: 128 x 256 bf16
        const int idx = (gid - 578) * 256 + tid;
        const int n = idx >> 8, k = idx & 255;
        W2fT[idx] = f2bf(msg_w2[k * 128 + n]);
    } else if (gid < 834) {               // W2rT: 128 x 256 bf16
        const int idx = (gid - 706) * 256 + tid;
        const int n = idx >> 8, k = idx & 255;
        W2rT[idx] = f2bf(rmsg_w2[k * 128 + n]);
    } else if (gid < 1090) {              // UW1T: 256 x 256 bf16
        const int idx = (gid - 834) * 256 + tid;
        const int n = idx >> 8, k = idx & 255;
        UW1T[idx] = f2bf(upd_w1[k * 256 + n]);
    } else {                              // UW2T: 128 x 256 bf16
        const int idx = (gid - 1090) * 256 + tid;
        const int n = idx >> 8, k = idx & 255;
        UW2T[idx] = f2bf(upd_w2[k * 128 + n]);
    }
}

// ---------------------------------------------------------------------------
// Node head (verified) — reads fp32 h
// ---------------------------------------------------------------------------
__global__ __launch_bounds__(256) void node_kernel(
    const float* __restrict__ h,
    const float* __restrict__ w1, const float* __restrict__ b1,
    const float* __restrict__ w2, const float* __restrict__ b2,
    const int* __restrict__ qsz, const int* __restrict__ csz,
    float* __restrict__ plan_out, float* __restrict__ loss_out)
{
    __shared__ float qn[32][128];
    __shared__ float cn[32][128];
    __shared__ float t1[32][64];
    __shared__ float mq[32][68];
    __shared__ float mc[32][68];
    __shared__ float la[32][33];
    __shared__ float red[4];
    const int bb = blockIdx.x;
    const int tid = threadIdx.x;
    const int qs = qsz[bb], cs = csz[bb];
    for (int u = tid * 4; u < 4096; u += 1024) {
        const int p = u >> 7, d = u & 127;
        float4 zq = make_float4(0.f, 0.f, 0.f, 0.f), zc = zq;
        if (p < NPG) {
            zq = *(const float4*)(h + (size_t)((2 * bb) * NPG + p) * 128 + d);
            zc = *(const float4*)(h + (size_t)((2 * bb + 1) * NPG + p) * 128 + d);
        }
        *(float4*)&qn[p][d] = zq;
        *(float4*)&cn[p][d] = zc;
    }
    __syncthreads();
    const int col = tid & 63;
    const int rg  = tid >> 6;
    for (int s = 0; s < 2; ++s) {
        const float (*src)[128] = s ? cn : qn;
        float (*dst)[68] = s ? mc : mq;
        const int sz = s ? cs : qs;
        float a8[8];
#pragma unroll
        for (int u = 0; u < 8; ++u) a8[u] = b1[col];
        for (int k = 0; k < 128; ++k) {
            const float wv = w1[k * 64 + col];
#pragma unroll
            for (int u = 0; u < 8; ++u) a8[u] = fmaf(src[rg + 4 * u][k], wv, a8[u]);
        }
#pragma unroll
        for (int u = 0; u < 8; ++u) t1[rg + 4 * u][col] = fmaxf(a8[u], 0.f);
        __syncthreads();
#pragma unroll
        for (int u = 0; u < 8; ++u) a8[u] = b2[col];
        for (int k = 0; k < 64; ++k) {
            const float wv = w2[k * 64 + col];
#pragma unroll
            for (int u = 0; u < 8; ++u) a8[u] = fmaf(t1[rg + 4 * u][k], wv, a8[u]);
        }
#pragma unroll
        for (int u = 0; u < 8; ++u) {
            const int r = rg + 4 * u;
            dst[r][col] = (r < sz) ? a8[u] : 0.f;
        }
        __syncthreads();
    }
    {
        const int q = tid >> 3, cg = tid & 7;
#pragma unroll
        for (int u = 0; u < 4; ++u) {
            const int c = cg + 8 * u;
            float s = 0.f;
            for (int d = 0; d < 64; ++d) s = fmaf(mq[q][d], mc[c][d], s);
            la[q][c] = s * TEMPINV;
        }
    }
    __syncthreads();
    const int l8 = tid & 7, rq = tid >> 3;
    for (int it = 0; it < SINK_ITERS; ++it) {
        {
            float x[4];
#pragma unroll
            for (int u = 0; u < 4; ++u) x[u] = la[rq][l8 * 4 + u];
            float m = fmaxf(fmaxf(x[0], x[1]), fmaxf(x[2], x[3]));
            m = fmaxf(m, __shfl_xor(m, 1));
            m = fmaxf(m, __shfl_xor(m, 2));
            m = fmaxf(m, __shfl_xor(m, 4));
            float s = expf(x[0] - m) + expf(x[1] - m) + expf(x[2] - m) + expf(x[3] - m);
            s += __shfl_xor(s, 1);
            s += __shfl_xor(s, 2);
            s += __shfl_xor(s, 4);
            const float lse = m + logf(s);
#pragma unroll
            for (int u = 0; u < 4; ++u) la[rq][l8 * 4 + u] = x[u] - lse;
        }
        __syncthreads();
        {
            float x[4];
#pragma unroll
            for (int u = 0; u < 4; ++u) x[u] = la[l8 * 4 + u][rq];
            float m = fmaxf(fmaxf(x[0], x[1]), fmaxf(x[2], x[3]));
            m = fmaxf(m, __shfl_xor(m, 1));
            m = fmaxf(m, __shfl_xor(m, 2));
            m = fmaxf(m, __shfl_xor(m, 4));
            float s = expf(x[0] - m) + expf(x[1] - m) + expf(x[2] - m) + expf(x[3] - m);
            s += __shfl_xor(s, 1);
            s += __shfl_xor(s, 2);
            s += __shfl_xor(s, 4);
            const float lse = m + logf(s);
#pragma unroll
            for (int u = 0; u < 4; ++u) la[l8 * 4 + u][rq] = x[u] - lse;
        }
        __syncthreads();
    }
    for (int u = tid; u < 1024; u += 256) {
        const int q = u >> 5, c = u & 31;
        const float p = expf(la[q][c]);
        la[q][c] = p;
        plan_out[(size_t)bb * 1024 + u] = p;
    }
    __syncthreads();
    float lsum = 0.f;
    {
        const int q = tid >> 3, dg = tid & 7;
        for (int u = 0; u < 16; ++u) {
            const int d = dg + 8 * u;
            float pc = 0.f;
#pragma unroll
            for (int c = 0; c < 32; ++c) pc = fmaf(la[q][c], cn[c][d], pc);
            lsum += fmaxf(qn[q][d] - pc, 0.f);
        }
    }
#pragma unroll
    for (int off = 1; off < 64; off <<= 1) lsum += __shfl_xor(lsum, off);
    if ((tid & 63) == 0) red[tid >> 6] = lsum;
    __syncthreads();
    if (tid == 0) loss_out[bb] = -(red[0] + red[1] + red[2] + red[3]);
}

// ---------------------------------------------------------------------------
// Edge head (verified) — EM passed as F after F += R
// ---------------------------------------------------------------------------
__global__ __launch_bounds__(256) void edge_kernel(
    const float* __restrict__ plan, const float* __restrict__ EM,
    const int* __restrict__ from_idx, const int* __restrict__ to_idx,
    float* __restrict__ loss_out)
{
    __shared__ float T[32][33];
    __shared__ float la[64][65];
    __shared__ float ce[64][128];
    __shared__ int qf[64], qt[64], cfi[64], cti[64];
    __shared__ float red[4];
    const int bb = blockIdx.x;
    const int tid = threadIdx.x;
    for (int u = tid; u < 1024; u += 256) T[u >> 5][u & 31] = plan[(size_t)bb * 1024 + u];
    if (tid < 64) {
        const int gq = 2 * bb, gc = 2 * bb + 1;
        qf[tid]  = from_idx[gq * 64 + tid] - gq * NPG;
        qt[tid]  = to_idx  [gq * 64 + tid] - gq * NPG;
        cfi[tid] = from_idx[gc * 64 + tid] - gc * NPG;
        cti[tid] = to_idx  [gc * 64 + tid] - gc * NPG;
    }
    {
        const int gc = 2 * bb + 1;
        for (int u = tid * 4; u < 8192; u += 1024) {
            const int i = u >> 7, d = u & 127;
            *(float4*)&ce[i][d] = *(const float4*)(EM + (size_t)(gc * 64 + i) * 128 + d);
        }
    }
    __syncthreads();
    {
        const int i = tid >> 2, jg = tid & 3;
        const int a = qf[i], b_ = qt[i];
#pragma unroll
        for (int u = 0; u < 16; ++u) {
            const int j = jg + 4 * u;
            const float s = T[a][cfi[j]] * T[b_][cti[j]] + T[a][cti[j]] * T[b_][cfi[j]];
            la[i][j] = s * TEMPINV;
        }
    }
    __syncthreads();
    const int l4 = tid & 3, rr = tid >> 2;
    for (int it = 0; it < SINK_ITERS; ++it) {
        {
            float x[16];
#pragma unroll
            for (int u = 0; u < 16; ++u) x[u] = la[rr][l4 + 4 * u];
            float m = x[0];
#pragma unroll
            for (int u = 1; u < 16; ++u) m = fmaxf(m, x[u]);
            m = fmaxf(m, __shfl_xor(m, 1));
            m = fmaxf(m, __shfl_xor(m, 2));
            float s = 0.f;
#pragma unroll
            for (int u = 0; u < 16; ++u) s += expf(x[u] - m);
            s += __shfl_xor(s, 1);
            s += __shfl_xor(s, 2);
            const float lse = m + logf(s);
#pragma unroll
            for (int u = 0; u < 16; ++u) la[rr][l4 + 4 * u] = x[u] - lse;
        }
        __syncthreads();
        {
            float x[16];
#pragma unroll
            for (int u = 0; u < 16; ++u) x[u] = la[l4 + 4 * u][rr];
            float m = x[0];
#pragma unroll
            for (int u = 1; u < 16; ++u) m = fmaxf(m, x[u]);
            m = fmaxf(m, __shfl_xor(m, 1));
            m = fmaxf(m, __shfl_xor(m, 2));
            float s = 0.f;
#pragma unroll
            for (int u = 0; u < 16; ++u) s += expf(x[u] - m);
            s += __shfl_xor(s, 1);
            s += __shfl_xor(s, 2);
            const float lse = m + logf(s);
#pragma unroll
            for (int u = 0; u < 16; ++u) la[l4 + 4 * u][rr] = x[u] - lse;
        }
        __syncthreads();
    }
    for (int u = tid; u < 4096; u += 256) la[u >> 6][u & 63] = expf(la[u >> 6][u & 63]);
    __syncthreads();
    float lsum = 0.f;
    {
        const int q = tid >> 2, dg = tid & 3;
        const float* qe = EM + (size_t)((2 * bb) * 64 + q) * 128;
        for (int u = 0; u < 32; ++u) {
            const int d = dg + 4 * u;
            float pc = 0.f;
            for (int c = 0; c < 64; ++c) pc = fmaf(la[q][c], ce[c][d], pc);
            lsum += fmaxf(qe[d] - pc, 0.f);
        }
    }
#pragma unroll
    for (int off = 1; off < 64; off <<= 1) lsum += __shfl_xor(lsum, off);
    if ((tid & 63) == 0) red[tid >> 6] = lsum;
    __syncthreads();
    if (tid == 0) loss_out[bb] -= CW * (red[0] + red[1] + red[2] + red[3]);
}

// ---------------------------------------------------------------------------
extern "C" void kernel_launch(void* const* d_in, const int* in_sizes, int n_in,
                              void* d_out, int out_size, void* d_ws, size_t ws_size,
                              hipStream_t stream)
{
    const float* node_features = (const float*)d_in[0];
    const float* edge_features = (const float*)d_in[1];
    const float* enc_nw  = (const float*)d_in[2];
    const float* enc_nb  = (const float*)d_in[3];
    const float* enc_ew  = (const float*)d_in[4];
    const float* enc_eb  = (const float*)d_in[5];
    const float* msg_w1  = (const float*)d_in[6];
    const float* msg_b1  = (const float*)d_in[7];
    const float* msg_w2  = (const float*)d_in[8];
    const float* msg_b2  = (const float*)d_in[9];
    const float* rmsg_w1 = (const float*)d_in[10];
    const float* rmsg_b1 = (const float*)d_in[11];
    const float* rmsg_w2 = (const float*)d_in[12];
    const float* rmsg_b2 = (const float*)d_in[13];
    const float* upd_w1  = (const float*)d_in[14];
    const float* upd_b1  = (const float*)d_in[15];
    const float* upd_w2  = (const float*)d_in[16];
    const float* upd_b2  = (const float*)d_in[17];
    const float* sk_w1   = (const float*)d_in[18];
    const float* sk_b1   = (const float*)d_in[19];
    const float* sk_w2   = (const float*)d_in[20];
    const float* sk_b2   = (const float*)d_in[21];
    const int* from_idx  = (const int*)d_in[22];
    const int* to_idx    = (const int*)d_in[23];
    const int* qsizes    = (const int*)d_in[24];
    const int* csizes    = (const int*)d_in[25];
    float* out = (float*)d_out;

    // workspace: fp32 region then bf16 region (~120 MB total)
    float* ws    = (float*)d_ws;
    float* h     = ws;                      // NN*128
    float* F     = h + 1835008;             // NE*128
    float* R     = F + 4194304;             // NE*128
    float* plan  = R + 4194304;             // NB*1024
    float* Wcomb = plan + 262144;           // 32*512
    float* bcomb = Wcomb + 16384;           // 512
    ushort* h_bf   = (ushort*)(bcomb + 512);    // NN*128
    ushort* HP     = h_bf + 1835008;            // NN*1024
    ushort* EC     = HP + 14680064;             // NE*512
    ushort* agg_bf = EC + 16777216;             // NN*128
    ushort* hid_bf = agg_bf + 1835008;          // NN*256
    ushort* WhpT   = hid_bf + 3670016;          // 1024*128
    ushort* W2fT   = WhpT + 131072;             // 128*256
    ushort* W2rT   = W2fT + 32768;              // 128*256
    ushort* UW1T   = W2rT + 32768;              // 256*256
    ushort* UW2T   = UW1T + 65536;              // 128*256

    const dim3 blk(256);

    pack2<<<1218, blk, 0, stream>>>(msg_w1, rmsg_w1, msg_b1, rmsg_b1,
                                    enc_ew, enc_eb, msg_w2, rmsg_w2, upd_w1, upd_w2,
                                    Wcomb, bcomb, WhpT, W2fT, W2rT, UW1T, UW2T);
    // node encoder (fp32) + bf16 copy
    gemm2<4, false><<<dim3(NN / 64, 1), blk, 0, stream>>>(
        node_features, 32, 32, enc_nw, 128, enc_nb, h, nullptr, 128);
    cvt_bf<<<896, blk, 0, stream>>>(h, h_bf);
    // EC = ef @ Wcomb + bcomb  -> bf16
    gemm2<8, true><<<dim3(NE / 128, 4), blk, 0, stream>>>(
        edge_features, 32, 32, Wcomb, 512, bcomb, nullptr, EC, 512);

    for (int step = 0; step < 3; ++step) {
        mfma_gemm<4, false, false, false, true, false, false><<<dim3(112, 8), blk, 0, stream>>>(
            h_bf, nullptr, 128, WhpT, nullptr, nullptr, HP, 1024);
        msg_mfma<<<dim3(256, 2), blk, 0, stream>>>(
            HP, EC, W2fT, W2rT, msg_b2, rmsg_b2, from_idx, to_idx, F, R);
        segsum_kernel<<<NG, blk, 0, stream>>>(F, R, from_idx, to_idx, agg_bf);
        mfma_gemm<8, true, true, false, true, false, true><<<dim3(112, 2), blk, 0, stream>>>(
            agg_bf, h_bf, 128, UW1T, upd_b1, nullptr, hid_bf, 256);
        mfma_gemm<8, true, false, true, false, true, false><<<dim3(112, 1), blk, 0, stream>>>(
            hid_bf, nullptr, 256, UW2T, upd_b2, h, h_bf, 128);
    }

    // final messages -> EM = F + R (in F)
    mfma_gemm<4, false, false, false, true, false, false><<<dim3(112, 8), blk, 0, stream>>>(
        h_bf, nullptr, 128, WhpT, nullptr, nullptr, HP, 1024);
    msg_mfma<<<dim3(256, 2), blk, 0, stream>>>(
        HP, EC, W2fT, W2rT, msg_b2, rmsg_b2, from_idx, to_idx, F, R);
    add_kernel<<<dim3((NE * 128) / 1024), blk, 0, stream>>>(F, R);

    node_kernel<<<NB, blk, 0, stream>>>(
        h, sk_w1, sk_b1, sk_w2, sk_b2, qsizes, csizes, plan, out);
    edge_kernel<<<NB, blk, 0, stream>>>(
        plan, F, from_idx, to_idx, out);
}

// Round 4
// 631.198 us; speedup vs baseline: 2.9911x; 1.1408x over previous
//
#include <hip/hip_runtime.h>
#include <math.h>

#define NPG 28
#define EPG 64
#define NB  256
#define NG  512
#define NN  14336
#define NE  32768
#define TEMPINV 10.0f
#define SINK_ITERS 20
#define CW 0.9f

typedef unsigned int uint;
typedef unsigned short ushort;
typedef __attribute__((ext_vector_type(8))) __bf16 bf16x8;
typedef __attribute__((ext_vector_type(4))) float f32x4;

__device__ __forceinline__ ushort f2bf(float x) {
    uint u = __float_as_uint(x);
    u += 0x7fffu + ((u >> 16) & 1u);
    return (ushort)(u >> 16);
}
__device__ __forceinline__ float bflo(uint w) { return __uint_as_float(w << 16); }
__device__ __forceinline__ float bfhi(uint w) { return __uint_as_float(w & 0xffff0000u); }
__device__ __forceinline__ uint relu_sum_pk(uint w1, uint w2, uint w3) {
    float lo = fmaxf(bflo(w1) + bflo(w2) + bflo(w3), 0.f);
    float hi = fmaxf(bfhi(w1) + bfhi(w2) + bfhi(w3), 0.f);
    return (uint)f2bf(lo) | ((uint)f2bf(hi) << 16);
}
__device__ __forceinline__ f32x4 mfma16(bf16x8 a, bf16x8 b, f32x4 c) {
    return __builtin_amdgcn_mfma_f32_16x16x32_bf16(a, b, c, 0, 0, 0);
}

// ---------------------------------------------------------------------------
// Direct-fragment bf16 MFMA GEMM (verified round-3 core).
// ---------------------------------------------------------------------------
template<int KT, bool BIAS, bool RELU, bool OUTBF, bool CONCAT>
__global__ __launch_bounds__(256) void mfma_gemm(
    const ushort* __restrict__ A, const ushort* __restrict__ A2, int lda,
    const ushort* __restrict__ BT, const float* __restrict__ bias,
    float* __restrict__ Cf, ushort* __restrict__ Cb, int ldc)
{
    const int tid = threadIdx.x;
    const int w = tid >> 6, lane = tid & 63;
    const int li = lane & 15, quad = lane >> 4;
    const int wm = w >> 1, wn = w & 1;
    const int m0 = blockIdx.x * 128 + wm * 64;
    const int n0 = blockIdx.y * 128 + wn * 64;

    const ushort* pa[4]; const ushort* pa2[4]; const ushort* pb[4];
#pragma unroll
    for (int mi = 0; mi < 4; ++mi) {
        const int row = m0 + mi * 16 + li;
        pa[mi] = A + (size_t)row * lda + quad * 8;
        if (CONCAT) pa2[mi] = A2 + (size_t)row * lda + quad * 8;
    }
#pragma unroll
    for (int ni = 0; ni < 4; ++ni)
        pb[ni] = BT + (size_t)(n0 + ni * 16 + li) * (KT * 32) + quad * 8;

    f32x4 acc[4][4];
#pragma unroll
    for (int i = 0; i < 4; ++i)
#pragma unroll
        for (int j = 0; j < 4; ++j) acc[i][j] = f32x4{0.f, 0.f, 0.f, 0.f};

    uint4 ar[4], br[4], an[4], bn[4];
#pragma unroll
    for (int mi = 0; mi < 4; ++mi) ar[mi] = *(const uint4*)pa[mi];
#pragma unroll
    for (int ni = 0; ni < 4; ++ni) br[ni] = *(const uint4*)pb[ni];

#pragma unroll
    for (int kb = 0; kb < KT; ++kb) {
        if (kb + 1 < KT) {
            const int off = (kb + 1) * 32;
#pragma unroll
            for (int mi = 0; mi < 4; ++mi) {
                if (CONCAT && (kb + 1) >= KT / 2)
                    an[mi] = *(const uint4*)(pa2[mi] + off - (KT / 2) * 32);
                else
                    an[mi] = *(const uint4*)(pa[mi] + off);
            }
#pragma unroll
            for (int ni = 0; ni < 4; ++ni) bn[ni] = *(const uint4*)(pb[ni] + off);
        }
        bf16x8 a[4], b[4];
#pragma unroll
        for (int mi = 0; mi < 4; ++mi) a[mi] = __builtin_bit_cast(bf16x8, ar[mi]);
#pragma unroll
        for (int ni = 0; ni < 4; ++ni) b[ni] = __builtin_bit_cast(bf16x8, br[ni]);
#pragma unroll
        for (int mi = 0; mi < 4; ++mi)
#pragma unroll
            for (int ni = 0; ni < 4; ++ni)
                acc[mi][ni] = mfma16(a[mi], b[ni], acc[mi][ni]);
        if (kb + 1 < KT) {
#pragma unroll
            for (int mi = 0; mi < 4; ++mi) ar[mi] = an[mi];
#pragma unroll
            for (int ni = 0; ni < 4; ++ni) br[ni] = bn[ni];
        }
    }

    float bv[4];
#pragma unroll
    for (int ni = 0; ni < 4; ++ni) bv[ni] = BIAS ? bias[n0 + ni * 16 + li] : 0.f;
#pragma unroll
    for (int mi = 0; mi < 4; ++mi) {
#pragma unroll
        for (int ni = 0; ni < 4; ++ni) {
            const int ncol = n0 + ni * 16 + li;
#pragma unroll
            for (int r = 0; r < 4; ++r) {
                const int rowr = m0 + mi * 16 + quad * 4 + r;
                float v = acc[mi][ni][r] + bv[ni];
                if (RELU) v = fmaxf(v, 0.f);
                const size_t idx = (size_t)rowr * ldc + ncol;
                if (OUTBF) Cb[idx] = f2bf(v);
                else       Cf[idx] = v;
            }
        }
    }
}

// ---------------------------------------------------------------------------
// Fused message kernel. One block = 128 edges = graphs (2b, 2b+1).
// SEG mode: F pass -> atomicAdd(+b2f) into LDS acc by to-node; R pass ->
//           atomicAdd(+b2r) by from-node; write agg (bf16) for 56 nodes.
// EMIT mode: F and R accumulate into the SAME registers; write EM fp32.
// ---------------------------------------------------------------------------
template<bool SEG>
__global__ __launch_bounds__(256) void msg_fused(
    const ushort* __restrict__ HP, const ushort* __restrict__ EC,
    const ushort* __restrict__ W2fT, const ushort* __restrict__ W2rT,
    const float* __restrict__ b2f, const float* __restrict__ b2r,
    const int* __restrict__ from_idx, const int* __restrict__ to_idx,
    ushort* __restrict__ agg, float* __restrict__ EM)
{
    __shared__ float acc_s[SEG ? 2 * NPG * 128 : 64];
    __shared__ int fidx[128], tidx[128];
    const int tid = threadIdx.x;
    const int w = tid >> 6, lane = tid & 63;
    const int li = lane & 15, quad = lane >> 4;
    const int wm = w >> 1, wn = w & 1;
    const int n0 = wn * 64;
    const int e0 = blockIdx.x * 128;

    if (tid < 128) {
        fidx[tid] = from_idx[e0 + tid];
        tidx[tid] = to_idx[e0 + tid];
    }
    if (SEG) {
        for (int u = tid; u < 2 * NPG * 128; u += 256) acc_s[u] = 0.f;
    }
    __syncthreads();

    f32x4 acc[4][4];
#pragma unroll
    for (int i = 0; i < 4; ++i)
#pragma unroll
        for (int j = 0; j < 4; ++j) acc[i][j] = f32x4{0.f, 0.f, 0.f, 0.f};

    for (int p = 0; p < 2; ++p) {
        const ushort* BT = p ? W2rT : W2fT;
        const float* bias = p ? b2r : b2f;
        const ushort *p1[4], *p2[4], *pe[4];
#pragma unroll
        for (int mi = 0; mi < 4; ++mi) {
            const int eloc = wm * 64 + mi * 16 + li;
            const int fi = fidx[eloc], ti = tidx[eloc];
            const int i1 = p ? ti : fi;
            const int i2 = p ? fi : ti;
            p1[mi] = HP + (size_t)i1 * 1024 + (p ? 512 : 0) + quad * 8;
            p2[mi] = HP + (size_t)i2 * 1024 + (p ? 768 : 256) + quad * 8;
            pe[mi] = EC + (size_t)(e0 + eloc) * 512 + (p ? 256 : 0) + quad * 8;
        }
        const ushort* pb[4];
#pragma unroll
        for (int ni = 0; ni < 4; ++ni)
            pb[ni] = BT + (size_t)(n0 + ni * 16 + li) * 256 + quad * 8;

        if (SEG && p == 1) {
#pragma unroll
            for (int i = 0; i < 4; ++i)
#pragma unroll
                for (int j = 0; j < 4; ++j) acc[i][j] = f32x4{0.f, 0.f, 0.f, 0.f};
        }

#pragma unroll
        for (int kb = 0; kb < 8; ++kb) {
            const int off = kb * 32;
            bf16x8 a[4], b[4];
#pragma unroll
            for (int ni = 0; ni < 4; ++ni)
                b[ni] = __builtin_bit_cast(bf16x8, *(const uint4*)(pb[ni] + off));
#pragma unroll
            for (int mi = 0; mi < 4; ++mi) {
                const uint4 u1 = *(const uint4*)(p1[mi] + off);
                const uint4 u2 = *(const uint4*)(p2[mi] + off);
                const uint4 ue = *(const uint4*)(pe[mi] + off);
                uint4 o;
                o.x = relu_sum_pk(u1.x, u2.x, ue.x);
                o.y = relu_sum_pk(u1.y, u2.y, ue.y);
                o.z = relu_sum_pk(u1.z, u2.z, ue.z);
                o.w = relu_sum_pk(u1.w, u2.w, ue.w);
                a[mi] = __builtin_bit_cast(bf16x8, o);
            }
#pragma unroll
            for (int mi = 0; mi < 4; ++mi)
#pragma unroll
                for (int ni = 0; ni < 4; ++ni)
                    acc[mi][ni] = mfma16(a[mi], b[ni], acc[mi][ni]);
        }

        if (SEG) {
            const int* targ = p ? fidx : tidx;
            float bv[4];
#pragma unroll
            for (int ni = 0; ni < 4; ++ni) bv[ni] = bias[n0 + ni * 16 + li];
#pragma unroll
            for (int mi = 0; mi < 4; ++mi) {
#pragma unroll
                for (int r = 0; r < 4; ++r) {
                    const int rloc = wm * 64 + mi * 16 + quad * 4 + r;
                    const int gl = rloc >> 6;
                    const int loc = targ[rloc] - (blockIdx.x * 2 + gl) * NPG + gl * NPG;
#pragma unroll
                    for (int ni = 0; ni < 4; ++ni)
                        atomicAdd(&acc_s[loc * 128 + n0 + ni * 16 + li],
                                  acc[mi][ni][r] + bv[ni]);
                }
            }
        }
    }

    if (SEG) {
        __syncthreads();
        const size_t base = (size_t)blockIdx.x * 2 * NPG * 128;
        for (int u = tid; u < 2 * NPG * 128; u += 256)
            agg[base + u] = f2bf(acc_s[u]);
    } else {
        float bv[4];
#pragma unroll
        for (int ni = 0; ni < 4; ++ni) {
            const int c = n0 + ni * 16 + li;
            bv[ni] = b2f[c] + b2r[c];
        }
#pragma unroll
        for (int mi = 0; mi < 4; ++mi) {
#pragma unroll
            for (int ni = 0; ni < 4; ++ni) {
                const int ncol = n0 + ni * 16 + li;
#pragma unroll
                for (int r = 0; r < 4; ++r) {
                    const int rowr = wm * 64 + mi * 16 + quad * 4 + r;
                    EM[(size_t)(e0 + rowr) * 128 + ncol] = acc[mi][ni][r] + bv[ni];
                }
            }
        }
    }
}

// ---------------------------------------------------------------------------
// Fused update MLP: 64-row tile. Phase1: hid = relu([agg|h]@UW1T+b1) -> LDS
// bf16. Phase2: h += hid@UW2T+b2 (fp32), write h_bf.
// ---------------------------------------------------------------------------
__global__ __launch_bounds__(256) void upd_fused(
    const ushort* __restrict__ agg, const ushort* __restrict__ hbf,
    const ushort* __restrict__ UW1T, const float* __restrict__ b1,
    const ushort* __restrict__ UW2T, const float* __restrict__ b2,
    float* __restrict__ h, ushort* __restrict__ h_bf_out)
{
    __shared__ ushort hid_s[64][264];   // stride 132 dwords: even 8-acc/bank
    const int tid = threadIdx.x;
    const int w = tid >> 6, lane = tid & 63;
    const int li = lane & 15, quad = lane >> 4;
    const int m0 = blockIdx.x * 64;

    {   // phase 1: wave w -> cols w*64..w*64+63, rows m0..m0+63
        const int n0 = w * 64;
        f32x4 acc[4][4];
#pragma unroll
        for (int i = 0; i < 4; ++i)
#pragma unroll
            for (int j = 0; j < 4; ++j) acc[i][j] = f32x4{0.f, 0.f, 0.f, 0.f};
        const ushort* pb[4];
#pragma unroll
        for (int ni = 0; ni < 4; ++ni)
            pb[ni] = UW1T + (size_t)(n0 + ni * 16 + li) * 256 + quad * 8;
#pragma unroll
        for (int kb = 0; kb < 8; ++kb) {
            bf16x8 a[4], b[4];
#pragma unroll
            for (int mi = 0; mi < 4; ++mi) {
                const int row = m0 + mi * 16 + li;
                const ushort* src = (kb < 4)
                    ? (agg + (size_t)row * 128 + kb * 32 + quad * 8)
                    : (hbf + (size_t)row * 128 + (kb - 4) * 32 + quad * 8);
                a[mi] = __builtin_bit_cast(bf16x8, *(const uint4*)src);
            }
#pragma unroll
            for (int ni = 0; ni < 4; ++ni)
                b[ni] = __builtin_bit_cast(bf16x8, *(const uint4*)(pb[ni] + kb * 32));
#pragma unroll
            for (int mi = 0; mi < 4; ++mi)
#pragma unroll
                for (int ni = 0; ni < 4; ++ni)
                    acc[mi][ni] = mfma16(a[mi], b[ni], acc[mi][ni]);
        }
        float bv[4];
#pragma unroll
        for (int ni = 0; ni < 4; ++ni) bv[ni] = b1[n0 + ni * 16 + li];
#pragma unroll
        for (int mi = 0; mi < 4; ++mi)
#pragma unroll
            for (int ni = 0; ni < 4; ++ni)
#pragma unroll
                for (int r = 0; r < 4; ++r) {
                    const int rloc = mi * 16 + quad * 4 + r;
                    hid_s[rloc][n0 + ni * 16 + li] =
                        f2bf(fmaxf(acc[mi][ni][r] + bv[ni], 0.f));
                }
    }
    __syncthreads();
    {   // phase 2: wave w -> cols w*32..w*32+31, rows m0..m0+63, K=256
        const int n0 = w * 32;
        f32x4 acc[4][2];
#pragma unroll
        for (int i = 0; i < 4; ++i)
#pragma unroll
            for (int j = 0; j < 2; ++j) acc[i][j] = f32x4{0.f, 0.f, 0.f, 0.f};
        const ushort* pb[2];
#pragma unroll
        for (int ni = 0; ni < 2; ++ni)
            pb[ni] = UW2T + (size_t)(n0 + ni * 16 + li) * 256 + quad * 8;
#pragma unroll
        for (int kb = 0; kb < 8; ++kb) {
            bf16x8 a[4], b[2];
#pragma unroll
            for (int mi = 0; mi < 4; ++mi)
                a[mi] = __builtin_bit_cast(bf16x8,
                    *(const uint4*)&hid_s[mi * 16 + li][kb * 32 + quad * 8]);
#pragma unroll
            for (int ni = 0; ni < 2; ++ni)
                b[ni] = __builtin_bit_cast(bf16x8, *(const uint4*)(pb[ni] + kb * 32));
#pragma unroll
            for (int mi = 0; mi < 4; ++mi)
#pragma unroll
                for (int ni = 0; ni < 2; ++ni)
                    acc[mi][ni] = mfma16(a[mi], b[ni], acc[mi][ni]);
        }
        float bv[2];
#pragma unroll
        for (int ni = 0; ni < 2; ++ni) bv[ni] = b2[n0 + ni * 16 + li];
#pragma unroll
        for (int mi = 0; mi < 4; ++mi)
#pragma unroll
            for (int ni = 0; ni < 2; ++ni) {
                const int ncol = n0 + ni * 16 + li;
#pragma unroll
                for (int r = 0; r < 4; ++r) {
                    const int row = m0 + mi * 16 + quad * 4 + r;
                    const size_t idx = (size_t)row * 128 + ncol;
                    const float nh = h[idx] + acc[mi][ni][r] + bv[ni];
                    h[idx] = nh;
                    h_bf_out[idx] = f2bf(nh);
                }
            }
    }
}

// ---------------------------------------------------------------------------
// fp32 tiled GEMM for K=32 encoders (verified core). OUT2: also write bf16.
// ---------------------------------------------------------------------------
template<int TM, bool OUTBF, bool OUT2>
__global__ __launch_bounds__(256) void gemm2(
    const float* __restrict__ A, int lda, int K,
    const float* __restrict__ W, int ldw, const float* __restrict__ bias,
    float* __restrict__ C, ushort* __restrict__ Cb, int ldc)
{
    constexpr int BM = TM * 16;
    constexpr int AV = BM / 64;
    __shared__ float As[16][BM + 4];
    __shared__ float Bs[16][132];
    const int tid = threadIdx.x;
    const int m0 = blockIdx.x * BM;
    const int n0 = blockIdx.y * 128;
    const int tx = tid & 15, ty = tid >> 4;
    const int arow = (AV == 2) ? (tid >> 1) : (tid >> 2);
    const int a0   = (AV == 2) ? ((tid & 1) * 8) : ((tid & 3) * 4);
    const int brow = ty;
    const int bcol = tx * 8;
    const int nch = K >> 4;

    float4 aC[AV], bC[2], aN[AV], bN[2];
    float acc[TM][8];
#pragma unroll
    for (int i = 0; i < TM; ++i)
#pragma unroll
        for (int j = 0; j < 8; ++j) acc[i][j] = 0.f;

    {
        const float* src = A + (size_t)(m0 + arow) * lda + a0;
        aC[0] = *(const float4*)src;
        if (AV == 2) aC[1] = *(const float4*)(src + 4);
        const float* bsrc = W + (size_t)brow * ldw + n0 + bcol;
        bC[0] = *(const float4*)bsrc;
        bC[1] = *(const float4*)(bsrc + 4);
    }

    for (int ch = 0; ch < nch; ++ch) {
        {
            const float* f = (const float*)aC;
#pragma unroll
            for (int i = 0; i < AV * 4; ++i) As[a0 + i][arow] = f[i];
            *(float4*)&Bs[brow][bcol]     = bC[0];
            *(float4*)&Bs[brow][bcol + 4] = bC[1];
        }
        __syncthreads();
        if (ch + 1 < nch) {
            const int kc = (ch + 1) << 4;
            const float* src = A + (size_t)(m0 + arow) * lda + kc + a0;
            aN[0] = *(const float4*)src;
            if (AV == 2) aN[1] = *(const float4*)(src + 4);
            const float* bsrc = W + (size_t)(kc + brow) * ldw + n0 + bcol;
            bN[0] = *(const float4*)bsrc;
            bN[1] = *(const float4*)(bsrc + 4);
        }
#pragma unroll
        for (int kk = 0; kk < 16; ++kk) {
            float afr[TM], bfr[8];
#pragma unroll
            for (int i = 0; i < TM; i += 4)
                *(float4*)&afr[i] = *(const float4*)&As[kk][ty * TM + i];
            *(float4*)&bfr[0] = *(const float4*)&Bs[kk][tx * 8];
            *(float4*)&bfr[4] = *(const float4*)&Bs[kk][tx * 8 + 4];
#pragma unroll
            for (int i = 0; i < TM; ++i)
#pragma unroll
                for (int j = 0; j < 8; ++j) acc[i][j] = fmaf(afr[i], bfr[j], acc[i][j]);
        }
        __syncthreads();
#pragma unroll
        for (int i = 0; i < AV; ++i) aC[i] = aN[i];
        bC[0] = bN[0]; bC[1] = bN[1];
    }
#pragma unroll
    for (int i = 0; i < TM; ++i) {
        const int row = m0 + ty * TM + i;
#pragma unroll
        for (int j = 0; j < 8; ++j) {
            const int col = n0 + tx * 8 + j;
            float v = acc[i][j] + bias[col];
            if (OUTBF) {
                Cb[(size_t)row * ldc + col] = f2bf(v);
            } else {
                C[(size_t)row * ldc + col] = v;
                if (OUT2) Cb[(size_t)row * ldc + col] = f2bf(v);
            }
        }
    }
}

// ---------------------------------------------------------------------------
// Weight packing (unchanged from verified round-3)
// ---------------------------------------------------------------------------
__global__ __launch_bounds__(256) void pack2(
    const float* __restrict__ msg_w1, const float* __restrict__ rmsg_w1,
    const float* __restrict__ msg_b1, const float* __restrict__ rmsg_b1,
    const float* __restrict__ enc_ew, const float* __restrict__ enc_eb,
    const float* __restrict__ msg_w2, const float* __restrict__ rmsg_w2,
    const float* __restrict__ upd_w1, const float* __restrict__ upd_w2,
    float* __restrict__ Wcomb, float* __restrict__ bcomb,
    ushort* __restrict__ WhpT, ushort* __restrict__ W2fT, ushort* __restrict__ W2rT,
    ushort* __restrict__ UW1T, ushort* __restrict__ UW2T)
{
    const int gid = blockIdx.x, tid = threadIdx.x;
    if (gid < 64) {
        const int idx = gid * 256 + tid;
        const int a = idx >> 9, n = idx & 511;
        const float* Wsrc = (n < 256) ? msg_w1 : rmsg_w1;
        const int nc = n & 255;
        float s = 0.f;
        for (int j = 0; j < 128; ++j)
            s = fmaf(enc_ew[a * 128 + j], Wsrc[(256 + j) * 256 + nc], s);
        Wcomb[idx] = s;
    } else if (gid < 66) {
        const int n = (gid - 64) * 256 + tid;
        const float* Wsrc = (n < 256) ? msg_w1 : rmsg_w1;
        const float* bsrc = (n < 256) ? msg_b1 : rmsg_b1;
        const int nc = n & 255;
        float s = bsrc[nc];
        for (int j = 0; j < 128; ++j)
            s = fmaf(enc_eb[j], Wsrc[(256 + j) * 256 + nc], s);
        bcomb[n] = s;
    } else if (gid < 578) {
        const int idx = (gid - 66) * 256 + tid;
        const int n = idx >> 7, k = idx & 127;
        const float* Wsrc = (n < 512) ? msg_w1 : rmsg_w1;
        const int part = (n >> 8) & 1, col = n & 255;
        WhpT[idx] = f2bf(Wsrc[(part * 128 + k) * 256 + col]);
    } else if (gid < 706) {
        const int idx = (gid - 578) * 256 + tid;
        const int n = idx >> 8, k = idx & 255;
        W2fT[idx] = f2bf(msg_w2[k * 128 + n]);
    } else if (gid < 834) {
        const int idx = (gid - 706) * 256 + tid;
        const int n = idx >> 8, k = idx & 255;
        W2rT[idx] = f2bf(rmsg_w2[k * 128 + n]);
    } else if (gid < 1090) {
        const int idx = (gid - 834) * 256 + tid;
        const int n = idx >> 8, k = idx & 255;
        UW1T[idx] = f2bf(upd_w1[k * 256 + n]);
    } else {
        const int idx = (gid - 1090) * 256 + tid;
        const int n = idx >> 8, k = idx & 255;
        UW2T[idx] = f2bf(upd_w2[k * 128 + n]);
    }
}

// ---------------------------------------------------------------------------
// Node head — hw exp/log
// ---------------------------------------------------------------------------
__global__ __launch_bounds__(256) void node_kernel(
    const float* __restrict__ h,
    const float* __restrict__ w1, const float* __restrict__ b1,
    const float* __restrict__ w2, const float* __restrict__ b2,
    const int* __restrict__ qsz, const int* __restrict__ csz,
    float* __restrict__ plan_out, float* __restrict__ loss_out)
{
    __shared__ float qn[32][128];
    __shared__ float cn[32][128];
    __shared__ float t1[32][64];
    __shared__ float mq[32][68];
    __shared__ float mc[32][68];
    __shared__ float la[32][33];
    __shared__ float red[4];
    const int bb = blockIdx.x;
    const int tid = threadIdx.x;
    const int qs = qsz[bb], cs = csz[bb];
    for (int u = tid * 4; u < 4096; u += 1024) {
        const int p = u >> 7, d = u & 127;
        float4 zq = make_float4(0.f, 0.f, 0.f, 0.f), zc = zq;
        if (p < NPG) {
            zq = *(const float4*)(h + (size_t)((2 * bb) * NPG + p) * 128 + d);
            zc = *(const float4*)(h + (size_t)((2 * bb + 1) * NPG + p) * 128 + d);
        }
        *(float4*)&qn[p][d] = zq;
        *(float4*)&cn[p][d] = zc;
    }
    __syncthreads();
    const int col = tid & 63;
    const int rg  = tid >> 6;
    for (int s = 0; s < 2; ++s) {
        const float (*src)[128] = s ? cn : qn;
        float (*dst)[68] = s ? mc : mq;
        const int sz = s ? cs : qs;
        float a8[8];
#pragma unroll
        for (int u = 0; u < 8; ++u) a8[u] = b1[col];
        for (int k = 0; k < 128; ++k) {
            const float wv = w1[k * 64 + col];
#pragma unroll
            for (int u = 0; u < 8; ++u) a8[u] = fmaf(src[rg + 4 * u][k], wv, a8[u]);
        }
#pragma unroll
        for (int u = 0; u < 8; ++u) t1[rg + 4 * u][col] = fmaxf(a8[u], 0.f);
        __syncthreads();
#pragma unroll
        for (int u = 0; u < 8; ++u) a8[u] = b2[col];
        for (int k = 0; k < 64; ++k) {
            const float wv = w2[k * 64 + col];
#pragma unroll
            for (int u = 0; u < 8; ++u) a8[u] = fmaf(t1[rg + 4 * u][k], wv, a8[u]);
        }
#pragma unroll
        for (int u = 0; u < 8; ++u) {
            const int r = rg + 4 * u;
            dst[r][col] = (r < sz) ? a8[u] : 0.f;
        }
        __syncthreads();
    }
    {
        const int q = tid >> 3, cg = tid & 7;
#pragma unroll
        for (int u = 0; u < 4; ++u) {
            const int c = cg + 8 * u;
            float s = 0.f;
            for (int d = 0; d < 64; ++d) s = fmaf(mq[q][d], mc[c][d], s);
            la[q][c] = s * TEMPINV;
        }
    }
    __syncthreads();
    const int l8 = tid & 7, rq = tid >> 3;
    for (int it = 0; it < SINK_ITERS; ++it) {
        {
            float x[4];
#pragma unroll
            for (int u = 0; u < 4; ++u) x[u] = la[rq][l8 * 4 + u];
            float m = fmaxf(fmaxf(x[0], x[1]), fmaxf(x[2], x[3]));
            m = fmaxf(m, __shfl_xor(m, 1));
            m = fmaxf(m, __shfl_xor(m, 2));
            m = fmaxf(m, __shfl_xor(m, 4));
            float s = __expf(x[0] - m) + __expf(x[1] - m) + __expf(x[2] - m) + __expf(x[3] - m);
            s += __shfl_xor(s, 1);
            s += __shfl_xor(s, 2);
            s += __shfl_xor(s, 4);
            const float lse = m + __logf(s);
#pragma unroll
            for (int u = 0; u < 4; ++u) la[rq][l8 * 4 + u] = x[u] - lse;
        }
        __syncthreads();
        {
            float x[4];
#pragma unroll
            for (int u = 0; u < 4; ++u) x[u] = la[l8 * 4 + u][rq];
            float m = fmaxf(fmaxf(x[0], x[1]), fmaxf(x[2], x[3]));
            m = fmaxf(m, __shfl_xor(m, 1));
            m = fmaxf(m, __shfl_xor(m, 2));
            m = fmaxf(m, __shfl_xor(m, 4));
            float s = __expf(x[0] - m) + __expf(x[1] - m) + __expf(x[2] - m) + __expf(x[3] - m);
            s += __shfl_xor(s, 1);
            s += __shfl_xor(s, 2);
            s += __shfl_xor(s, 4);
            const float lse = m + __logf(s);
#pragma unroll
            for (int u = 0; u < 4; ++u) la[l8 * 4 + u][rq] = x[u] - lse;
        }
        __syncthreads();
    }
    for (int u = tid; u < 1024; u += 256) {
        const int q = u >> 5, c = u & 31;
        const float p = __expf(la[q][c]);
        la[q][c] = p;
        plan_out[(size_t)bb * 1024 + u] = p;
    }
    __syncthreads();
    float lsum = 0.f;
    {
        const int q = tid >> 3, dg = tid & 7;
        for (int u = 0; u < 16; ++u) {
            const int d = dg + 8 * u;
            float pc = 0.f;
#pragma unroll
            for (int c = 0; c < 32; ++c) pc = fmaf(la[q][c], cn[c][d], pc);
            lsum += fmaxf(qn[q][d] - pc, 0.f);
        }
    }
#pragma unroll
    for (int off = 1; off < 64; off <<= 1) lsum += __shfl_xor(lsum, off);
    if ((tid & 63) == 0) red[tid >> 6] = lsum;
    __syncthreads();
    if (tid == 0) loss_out[bb] = -(red[0] + red[1] + red[2] + red[3]);
}

// ---------------------------------------------------------------------------
// Edge head — blocked element mapping (conflict-free) + hw exp/log
// ---------------------------------------------------------------------------
__global__ __launch_bounds__(256) void edge_kernel(
    const float* __restrict__ plan, const float* __restrict__ EM,
    const int* __restrict__ from_idx, const int* __restrict__ to_idx,
    float* __restrict__ loss_out)
{
    __shared__ float T[32][33];
    __shared__ float la[64][65];
    __shared__ float ce[64][128];
    __shared__ int qf[64], qt[64], cfi[64], cti[64];
    __shared__ float red[4];
    const int bb = blockIdx.x;
    const int tid = threadIdx.x;
    for (int u = tid; u < 1024; u += 256) T[u >> 5][u & 31] = plan[(size_t)bb * 1024 + u];
    if (tid < 64) {
        const int gq = 2 * bb, gc = 2 * bb + 1;
        qf[tid]  = from_idx[gq * 64 + tid] - gq * NPG;
        qt[tid]  = to_idx  [gq * 64 + tid] - gq * NPG;
        cfi[tid] = from_idx[gc * 64 + tid] - gc * NPG;
        cti[tid] = to_idx  [gc * 64 + tid] - gc * NPG;
    }
    {
        const int gc = 2 * bb + 1;
        for (int u = tid * 4; u < 8192; u += 1024) {
            const int i = u >> 7, d = u & 127;
            *(float4*)&ce[i][d] = *(const float4*)(EM + (size_t)(gc * 64 + i) * 128 + d);
        }
    }
    __syncthreads();
    {
        const int i = tid >> 2, jg = tid & 3;
        const int a = qf[i], b_ = qt[i];
#pragma unroll
        for (int u = 0; u < 16; ++u) {
            const int j = jg * 16 + u;
            const float s = T[a][cfi[j]] * T[b_][cti[j]] + T[a][cti[j]] * T[b_][cfi[j]];
            la[i][j] = s * TEMPINV;
        }
    }
    __syncthreads();
    const int l4 = tid & 3, rr = tid >> 2;
    for (int it = 0; it < SINK_ITERS; ++it) {
        {
            float x[16];
#pragma unroll
            for (int u = 0; u < 16; ++u) x[u] = la[rr][l4 * 16 + u];
            float m = x[0];
#pragma unroll
            for (int u = 1; u < 16; ++u) m = fmaxf(m, x[u]);
            m = fmaxf(m, __shfl_xor(m, 1));
            m = fmaxf(m, __shfl_xor(m, 2));
            float s = 0.f;
#pragma unroll
            for (int u = 0; u < 16; ++u) s += __expf(x[u] - m);
            s += __shfl_xor(s, 1);
            s += __shfl_xor(s, 2);
            const float lse = m + __logf(s);
#pragma unroll
            for (int u = 0; u < 16; ++u) la[rr][l4 * 16 + u] = x[u] - lse;
        }
        __syncthreads();
        {
            float x[16];
#pragma unroll
            for (int u = 0; u < 16; ++u) x[u] = la[l4 * 16 + u][rr];
            float m = x[0];
#pragma unroll
            for (int u = 1; u < 16; ++u) m = fmaxf(m, x[u]);
            m = fmaxf(m, __shfl_xor(m, 1));
            m = fmaxf(m, __shfl_xor(m, 2));
            float s = 0.f;
#pragma unroll
            for (int u = 0; u < 16; ++u) s += __expf(x[u] - m);
            s += __shfl_xor(s, 1);
            s += __shfl_xor(s, 2);
            const float lse = m + __logf(s);
#pragma unroll
            for (int u = 0; u < 16; ++u) la[l4 * 16 + u][rr] = x[u] - lse;
        }
        __syncthreads();
    }
    for (int u = tid; u < 4096; u += 256) la[u >> 6][u & 63] = __expf(la[u >> 6][u & 63]);
    __syncthreads();
    float lsum = 0.f;
    {
        const int q = tid >> 2, dg = tid & 3;
        const float* qe = EM + (size_t)((2 * bb) * 64 + q) * 128;
        for (int u = 0; u < 32; ++u) {
            const int d = dg + 4 * u;
            float pc = 0.f;
            for (int c = 0; c < 64; ++c) pc = fmaf(la[q][c], ce[c][d], pc);
            lsum += fmaxf(qe[d] - pc, 0.f);
        }
    }
#pragma unroll
    for (int off = 1; off < 64; off <<= 1) lsum += __shfl_xor(lsum, off);
    if ((tid & 63) == 0) red[tid >> 6] = lsum;
    __syncthreads();
    if (tid == 0) loss_out[bb] -= CW * (red[0] + red[1] + red[2] + red[3]);
}

// ---------------------------------------------------------------------------
extern "C" void kernel_launch(void* const* d_in, const int* in_sizes, int n_in,
                              void* d_out, int out_size, void* d_ws, size_t ws_size,
                              hipStream_t stream)
{
    const float* node_features = (const float*)d_in[0];
    const float* edge_features = (const float*)d_in[1];
    const float* enc_nw  = (const float*)d_in[2];
    const float* enc_nb  = (const float*)d_in[3];
    const float* enc_ew  = (const float*)d_in[4];
    const float* enc_eb  = (const float*)d_in[5];
    const float* msg_w1  = (const float*)d_in[6];
    const float* msg_b1  = (const float*)d_in[7];
    const float* msg_w2  = (const float*)d_in[8];
    const float* msg_b2  = (const float*)d_in[9];
    const float* rmsg_w1 = (const float*)d_in[10];
    const float* rmsg_b1 = (const float*)d_in[11];
    const float* rmsg_w2 = (const float*)d_in[12];
    const float* rmsg_b2 = (const float*)d_in[13];
    const float* upd_w1  = (const float*)d_in[14];
    const float* upd_b1  = (const float*)d_in[15];
    const float* upd_w2  = (const float*)d_in[16];
    const float* upd_b2  = (const float*)d_in[17];
    const float* sk_w1   = (const float*)d_in[18];
    const float* sk_b1   = (const float*)d_in[19];
    const float* sk_w2   = (const float*)d_in[20];
    const float* sk_b2   = (const float*)d_in[21];
    const int* from_idx  = (const int*)d_in[22];
    const int* to_idx    = (const int*)d_in[23];
    const int* qsizes    = (const int*)d_in[24];
    const int* csizes    = (const int*)d_in[25];
    float* out = (float*)d_out;

    float* ws    = (float*)d_ws;
    float* h     = ws;                      // NN*128 fp32
    float* EM    = h + 1835008;             // NE*128 fp32
    float* plan  = EM + 4194304;            // NB*1024
    float* Wcomb = plan + 262144;           // 32*512
    float* bcomb = Wcomb + 16384;           // 512
    ushort* h_bf   = (ushort*)(bcomb + 512);    // NN*128
    ushort* HP     = h_bf + 1835008;            // NN*1024
    ushort* EC     = HP + 14680064;             // NE*512
    ushort* agg_bf = EC + 16777216;             // NN*128
    ushort* WhpT   = agg_bf + 1835008;          // 1024*128
    ushort* W2fT   = WhpT + 131072;             // 128*256
    ushort* W2rT   = W2fT + 32768;              // 128*256
    ushort* UW1T   = W2rT + 32768;              // 256*256
    ushort* UW2T   = UW1T + 65536;              // 128*256

    const dim3 blk(256);

    pack2<<<1218, blk, 0, stream>>>(msg_w1, rmsg_w1, msg_b1, rmsg_b1,
                                    enc_ew, enc_eb, msg_w2, rmsg_w2, upd_w1, upd_w2,
                                    Wcomb, bcomb, WhpT, W2fT, W2rT, UW1T, UW2T);
    gemm2<4, false, true><<<dim3(NN / 64, 1), blk, 0, stream>>>(
        node_features, 32, 32, enc_nw, 128, enc_nb, h, h_bf, 128);
    gemm2<8, true, false><<<dim3(NE / 128, 4), blk, 0, stream>>>(
        edge_features, 32, 32, Wcomb, 512, bcomb, nullptr, EC, 512);

    for (int step = 0; step < 3; ++step) {
        mfma_gemm<4, false, false, true, false><<<dim3(112, 8), blk, 0, stream>>>(
            h_bf, nullptr, 128, WhpT, nullptr, nullptr, HP, 1024);
        msg_fused<true><<<dim3(256), blk, 0, stream>>>(
            HP, EC, W2fT, W2rT, msg_b2, rmsg_b2, from_idx, to_idx, agg_bf, nullptr);
        upd_fused<<<dim3(224), blk, 0, stream>>>(
            agg_bf, h_bf, UW1T, upd_b1, UW2T, upd_b2, h, h_bf);
    }

    mfma_gemm<4, false, false, true, false><<<dim3(112, 8), blk, 0, stream>>>(
        h_bf, nullptr, 128, WhpT, nullptr, nullptr, HP, 1024);
    msg_fused<false><<<dim3(256), blk, 0, stream>>>(
        HP, EC, W2fT, W2rT, msg_b2, rmsg_b2, from_idx, to_idx, nullptr, EM);

    node_kernel<<<NB, blk, 0, stream>>>(
        h, sk_w1, sk_b1, sk_w2, sk_b2, qsizes, csizes, plan, out);
    edge_kernel<<<NB, blk, 0, stream>>>(
        plan, EM, from_idx, to_idx, out);
}

// Round 5
// 619.227 us; speedup vs baseline: 3.0489x; 1.0193x over previous
//
#include <hip/hip_runtime.h>
#include <math.h>

#define NPG 28
#define EPG 64
#define NB  256
#define NG  512
#define NN  14336
#define NE  32768
#define TEMPINV 10.0f
#define SINK_ITERS 20
#define CW 0.9f

typedef unsigned int uint;
typedef unsigned short ushort;
typedef __attribute__((ext_vector_type(8))) __bf16 bf16x8;
typedef __attribute__((ext_vector_type(4))) float f32x4;

__device__ __forceinline__ ushort f2bf(float x) {
    uint u = __float_as_uint(x);
    u += 0x7fffu + ((u >> 16) & 1u);
    return (ushort)(u >> 16);
}
__device__ __forceinline__ float bflo(uint w) { return __uint_as_float(w << 16); }
__device__ __forceinline__ float bfhi(uint w) { return __uint_as_float(w & 0xffff0000u); }
__device__ __forceinline__ uint relu_sum_pk(uint w1, uint w2, uint w3) {
    float lo = fmaxf(bflo(w1) + bflo(w2) + bflo(w3), 0.f);
    float hi = fmaxf(bfhi(w1) + bfhi(w2) + bfhi(w3), 0.f);
    return (uint)f2bf(lo) | ((uint)f2bf(hi) << 16);
}
__device__ __forceinline__ f32x4 mfma16(bf16x8 a, bf16x8 b, f32x4 c) {
    return __builtin_amdgcn_mfma_f32_16x16x32_bf16(a, b, c, 0, 0, 0);
}

// ---------------------------------------------------------------------------
// Direct-fragment bf16 MFMA GEMM (verified core). 128x128 tile, 4 waves.
// ---------------------------------------------------------------------------
template<int KT, bool BIAS, bool RELU, bool OUTBF, bool CONCAT>
__global__ __launch_bounds__(256) void mfma_gemm(
    const ushort* __restrict__ A, const ushort* __restrict__ A2, int lda,
    const ushort* __restrict__ BT, const float* __restrict__ bias,
    float* __restrict__ Cf, ushort* __restrict__ Cb, int ldc)
{
    const int tid = threadIdx.x;
    const int w = tid >> 6, lane = tid & 63;
    const int li = lane & 15, quad = lane >> 4;
    const int wm = w >> 1, wn = w & 1;
    const int m0 = blockIdx.x * 128 + wm * 64;
    const int n0 = blockIdx.y * 128 + wn * 64;

    const ushort* pa[4]; const ushort* pa2[4]; const ushort* pb[4];
#pragma unroll
    for (int mi = 0; mi < 4; ++mi) {
        const int row = m0 + mi * 16 + li;
        pa[mi] = A + (size_t)row * lda + quad * 8;
        if (CONCAT) pa2[mi] = A2 + (size_t)row * lda + quad * 8;
    }
#pragma unroll
    for (int ni = 0; ni < 4; ++ni)
        pb[ni] = BT + (size_t)(n0 + ni * 16 + li) * (KT * 32) + quad * 8;

    f32x4 acc[4][4];
#pragma unroll
    for (int i = 0; i < 4; ++i)
#pragma unroll
        for (int j = 0; j < 4; ++j) acc[i][j] = f32x4{0.f, 0.f, 0.f, 0.f};

    uint4 ar[4], br[4], an[4], bn[4];
#pragma unroll
    for (int mi = 0; mi < 4; ++mi) ar[mi] = *(const uint4*)pa[mi];
#pragma unroll
    for (int ni = 0; ni < 4; ++ni) br[ni] = *(const uint4*)pb[ni];

#pragma unroll
    for (int kb = 0; kb < KT; ++kb) {
        if (kb + 1 < KT) {
            const int off = (kb + 1) * 32;
#pragma unroll
            for (int mi = 0; mi < 4; ++mi) {
                if (CONCAT && (kb + 1) >= KT / 2)
                    an[mi] = *(const uint4*)(pa2[mi] + off - (KT / 2) * 32);
                else
                    an[mi] = *(const uint4*)(pa[mi] + off);
            }
#pragma unroll
            for (int ni = 0; ni < 4; ++ni) bn[ni] = *(const uint4*)(pb[ni] + off);
        }
        bf16x8 a[4], b[4];
#pragma unroll
        for (int mi = 0; mi < 4; ++mi) a[mi] = __builtin_bit_cast(bf16x8, ar[mi]);
#pragma unroll
        for (int ni = 0; ni < 4; ++ni) b[ni] = __builtin_bit_cast(bf16x8, br[ni]);
#pragma unroll
        for (int mi = 0; mi < 4; ++mi)
#pragma unroll
            for (int ni = 0; ni < 4; ++ni)
                acc[mi][ni] = mfma16(a[mi], b[ni], acc[mi][ni]);
        if (kb + 1 < KT) {
#pragma unroll
            for (int mi = 0; mi < 4; ++mi) ar[mi] = an[mi];
#pragma unroll
            for (int ni = 0; ni < 4; ++ni) br[ni] = bn[ni];
        }
    }

    float bv[4];
#pragma unroll
    for (int ni = 0; ni < 4; ++ni) bv[ni] = BIAS ? bias[n0 + ni * 16 + li] : 0.f;
#pragma unroll
    for (int mi = 0; mi < 4; ++mi) {
#pragma unroll
        for (int ni = 0; ni < 4; ++ni) {
            const int ncol = n0 + ni * 16 + li;
#pragma unroll
            for (int r = 0; r < 4; ++r) {
                const int rowr = m0 + mi * 16 + quad * 4 + r;
                float v = acc[mi][ni][r] + bv[ni];
                if (RELU) v = fmaxf(v, 0.f);
                const size_t idx = (size_t)rowr * ldc + ncol;
                if (OUTBF) Cb[idx] = f2bf(v);
                else       Cf[idx] = v;
            }
        }
    }
}

// ---------------------------------------------------------------------------
// Fused message kernel v2: one block = one graph (64 edges), 4 waves.
// Per pass p (f,r): build A-tile relu(HP[i1]+HP[i2]+EC) cooperatively into
// LDS ([k/8][edge][8] layout, conflict-free), then each wave MFMAs its
// 64x32 output strip. SEG: atomicAdd(+bias) into per-graph LDS acc, write
// agg bf16. EMIT: F and R share registers, write EM fp32.
// ---------------------------------------------------------------------------
template<bool SEG>
__global__ __launch_bounds__(256) void msg_fused(
    const ushort* __restrict__ HP, const ushort* __restrict__ EC,
    const ushort* __restrict__ W2fT, const ushort* __restrict__ W2rT,
    const float* __restrict__ b2f, const float* __restrict__ b2r,
    const int* __restrict__ from_idx, const int* __restrict__ to_idx,
    ushort* __restrict__ agg, float* __restrict__ EM)
{
    __shared__ ushort As[32][64][8];                 // 32 KB
    __shared__ float acc_s[SEG ? NPG * 128 : 64];    // 14.3 KB (SEG)
    __shared__ int fidx[64], tidx[64];
    const int g = blockIdx.x;
    const int tid = threadIdx.x;
    const int w = tid >> 6, lane = tid & 63;
    const int li = lane & 15, quad = lane >> 4;
    const int n0 = w * 32;
    const int e0 = g * 64;

    if (tid < 64) {
        fidx[tid] = from_idx[e0 + tid];
        tidx[tid] = to_idx[e0 + tid];
    }
    if (SEG) {
        for (int u = tid; u < NPG * 128; u += 256) acc_s[u] = 0.f;
    }
    __syncthreads();

    const int be = tid & 63;           // build: edge index (lane-contiguous)
    const int bk = (tid >> 6) * 64;    // build: k base (64 k's per thread)

    f32x4 acc[4][2];
#pragma unroll
    for (int i = 0; i < 4; ++i)
#pragma unroll
        for (int j = 0; j < 2; ++j) acc[i][j] = f32x4{0.f, 0.f, 0.f, 0.f};

    for (int p = 0; p < 2; ++p) {
        {   // build A-tile for this pass
            const int fi = fidx[be], ti = tidx[be];
            const int i1 = p ? ti : fi, i2 = p ? fi : ti;
            const ushort* p1 = HP + (size_t)i1 * 1024 + (p ? 512 : 0) + bk;
            const ushort* p2 = HP + (size_t)i2 * 1024 + (p ? 768 : 256) + bk;
            const ushort* pe = EC + (size_t)(e0 + be) * 512 + (p ? 256 : 0) + bk;
#pragma unroll
            for (int u = 0; u < 8; ++u) {
                const uint4 u1 = *(const uint4*)(p1 + u * 8);
                const uint4 u2 = *(const uint4*)(p2 + u * 8);
                const uint4 ue = *(const uint4*)(pe + u * 8);
                uint4 o;
                o.x = relu_sum_pk(u1.x, u2.x, ue.x);
                o.y = relu_sum_pk(u1.y, u2.y, ue.y);
                o.z = relu_sum_pk(u1.z, u2.z, ue.z);
                o.w = relu_sum_pk(u1.w, u2.w, ue.w);
                *(uint4*)&As[(bk >> 3) + u][be][0] = o;
            }
        }
        __syncthreads();

        if (SEG && p == 1) {
#pragma unroll
            for (int i = 0; i < 4; ++i)
#pragma unroll
                for (int j = 0; j < 2; ++j) acc[i][j] = f32x4{0.f, 0.f, 0.f, 0.f};
        }

        const ushort* BT = p ? W2rT : W2fT;
        const ushort* pb0 = BT + (size_t)(n0 + li) * 256 + quad * 8;
        const ushort* pb1 = BT + (size_t)(n0 + 16 + li) * 256 + quad * 8;
#pragma unroll
        for (int kb = 0; kb < 8; ++kb) {
            bf16x8 a[4], b[2];
            b[0] = __builtin_bit_cast(bf16x8, *(const uint4*)(pb0 + kb * 32));
            b[1] = __builtin_bit_cast(bf16x8, *(const uint4*)(pb1 + kb * 32));
#pragma unroll
            for (int mi = 0; mi < 4; ++mi)
                a[mi] = __builtin_bit_cast(bf16x8,
                    *(const uint4*)&As[kb * 4 + quad][mi * 16 + li][0]);
#pragma unroll
            for (int mi = 0; mi < 4; ++mi)
#pragma unroll
                for (int ni = 0; ni < 2; ++ni)
                    acc[mi][ni] = mfma16(a[mi], b[ni], acc[mi][ni]);
        }

        if (SEG) {
            const int* targ = p ? fidx : tidx;
            const float* bias = p ? b2r : b2f;
            float bv[2];
#pragma unroll
            for (int ni = 0; ni < 2; ++ni) bv[ni] = bias[n0 + ni * 16 + li];
#pragma unroll
            for (int mi = 0; mi < 4; ++mi) {
#pragma unroll
                for (int r = 0; r < 4; ++r) {
                    const int rloc = mi * 16 + quad * 4 + r;
                    const int loc = targ[rloc] - g * NPG;
#pragma unroll
                    for (int ni = 0; ni < 2; ++ni)
                        atomicAdd(&acc_s[loc * 128 + n0 + ni * 16 + li],
                                  acc[mi][ni][r] + bv[ni]);
                }
            }
        }
        __syncthreads();   // As reusable / LDS atomics drained
    }

    if (SEG) {
        const size_t base = (size_t)g * NPG * 128;
        for (int u = tid; u < NPG * 128; u += 256)
            agg[base + u] = f2bf(acc_s[u]);
    } else {
        float bv[2];
#pragma unroll
        for (int ni = 0; ni < 2; ++ni) {
            const int c = n0 + ni * 16 + li;
            bv[ni] = b2f[c] + b2r[c];
        }
#pragma unroll
        for (int mi = 0; mi < 4; ++mi) {
#pragma unroll
            for (int ni = 0; ni < 2; ++ni) {
                const int ncol = n0 + ni * 16 + li;
#pragma unroll
                for (int r = 0; r < 4; ++r) {
                    const int rloc = mi * 16 + quad * 4 + r;
                    EM[(size_t)(e0 + rloc) * 128 + ncol] = acc[mi][ni][r] + bv[ni];
                }
            }
        }
    }
}

// ---------------------------------------------------------------------------
// Fused update MLP v2: 16-row tiles (896 blocks). Phase1: hid =
// relu([agg|h]@UW1T+b1) -> LDS bf16 (wave w: cols w*64..+63). Phase2:
// h += hid@UW2T+b2 (wave w: cols w*32..+31).
// ---------------------------------------------------------------------------
__global__ __launch_bounds__(256) void upd_fused(
    const ushort* __restrict__ agg, const ushort* __restrict__ hbf,
    const ushort* __restrict__ UW1T, const float* __restrict__ b1,
    const ushort* __restrict__ UW2T, const float* __restrict__ b2,
    float* __restrict__ h, ushort* __restrict__ h_bf_out)
{
    __shared__ ushort hid_s[16][264];
    const int tid = threadIdx.x;
    const int w = tid >> 6, lane = tid & 63;
    const int li = lane & 15, quad = lane >> 4;
    const int m0 = blockIdx.x * 16;

    {   // phase 1
        const int n0 = w * 64;
        f32x4 acc[4];
#pragma unroll
        for (int j = 0; j < 4; ++j) acc[j] = f32x4{0.f, 0.f, 0.f, 0.f};
        const ushort* pb[4];
#pragma unroll
        for (int ni = 0; ni < 4; ++ni)
            pb[ni] = UW1T + (size_t)(n0 + ni * 16 + li) * 256 + quad * 8;
        const ushort* pa_a = agg + (size_t)(m0 + li) * 128 + quad * 8;
        const ushort* pa_h = hbf + (size_t)(m0 + li) * 128 + quad * 8;
#pragma unroll
        for (int kb = 0; kb < 8; ++kb) {
            const ushort* src = (kb < 4) ? (pa_a + kb * 32) : (pa_h + (kb - 4) * 32);
            const bf16x8 a = __builtin_bit_cast(bf16x8, *(const uint4*)src);
            bf16x8 b[4];
#pragma unroll
            for (int ni = 0; ni < 4; ++ni)
                b[ni] = __builtin_bit_cast(bf16x8, *(const uint4*)(pb[ni] + kb * 32));
#pragma unroll
            for (int ni = 0; ni < 4; ++ni) acc[ni] = mfma16(a, b[ni], acc[ni]);
        }
#pragma unroll
        for (int ni = 0; ni < 4; ++ni) {
            const float bv = b1[n0 + ni * 16 + li];
#pragma unroll
            for (int r = 0; r < 4; ++r)
                hid_s[quad * 4 + r][n0 + ni * 16 + li] =
                    f2bf(fmaxf(acc[ni][r] + bv, 0.f));
        }
    }
    __syncthreads();
    {   // phase 2
        const int n0 = w * 32;
        f32x4 acc[2];
#pragma unroll
        for (int j = 0; j < 2; ++j) acc[j] = f32x4{0.f, 0.f, 0.f, 0.f};
        const ushort* pb[2];
#pragma unroll
        for (int ni = 0; ni < 2; ++ni)
            pb[ni] = UW2T + (size_t)(n0 + ni * 16 + li) * 256 + quad * 8;
#pragma unroll
        for (int kb = 0; kb < 8; ++kb) {
            const bf16x8 a = __builtin_bit_cast(bf16x8,
                *(const uint4*)&hid_s[li][kb * 32 + quad * 8]);
            bf16x8 b[2];
#pragma unroll
            for (int ni = 0; ni < 2; ++ni)
                b[ni] = __builtin_bit_cast(bf16x8, *(const uint4*)(pb[ni] + kb * 32));
#pragma unroll
            for (int ni = 0; ni < 2; ++ni) acc[ni] = mfma16(a, b[ni], acc[ni]);
        }
#pragma unroll
        for (int ni = 0; ni < 2; ++ni) {
            const int ncol = n0 + ni * 16 + li;
            const float bv = b2[ncol];
#pragma unroll
            for (int r = 0; r < 4; ++r) {
                const int row = m0 + quad * 4 + r;
                const size_t idx = (size_t)row * 128 + ncol;
                const float nh = h[idx] + acc[ni][r] + bv;
                h[idx] = nh;
                h_bf_out[idx] = f2bf(nh);
            }
        }
    }
}

// ---------------------------------------------------------------------------
// fp32 tiled GEMM for K=32 encoders (verified core). OUT2: also write bf16.
// ---------------------------------------------------------------------------
template<int TM, bool OUTBF, bool OUT2>
__global__ __launch_bounds__(256) void gemm2(
    const float* __restrict__ A, int lda, int K,
    const float* __restrict__ W, int ldw, const float* __restrict__ bias,
    float* __restrict__ C, ushort* __restrict__ Cb, int ldc)
{
    constexpr int BM = TM * 16;
    constexpr int AV = BM / 64;
    __shared__ float As[16][BM + 4];
    __shared__ float Bs[16][132];
    const int tid = threadIdx.x;
    const int m0 = blockIdx.x * BM;
    const int n0 = blockIdx.y * 128;
    const int tx = tid & 15, ty = tid >> 4;
    const int arow = (AV == 2) ? (tid >> 1) : (tid >> 2);
    const int a0   = (AV == 2) ? ((tid & 1) * 8) : ((tid & 3) * 4);
    const int brow = ty;
    const int bcol = tx * 8;
    const int nch = K >> 4;

    float4 aC[AV], bC[2], aN[AV], bN[2];
    float acc[TM][8];
#pragma unroll
    for (int i = 0; i < TM; ++i)
#pragma unroll
        for (int j = 0; j < 8; ++j) acc[i][j] = 0.f;

    {
        const float* src = A + (size_t)(m0 + arow) * lda + a0;
        aC[0] = *(const float4*)src;
        if (AV == 2) aC[1] = *(const float4*)(src + 4);
        const float* bsrc = W + (size_t)brow * ldw + n0 + bcol;
        bC[0] = *(const float4*)bsrc;
        bC[1] = *(const float4*)(bsrc + 4);
    }

    for (int ch = 0; ch < nch; ++ch) {
        {
            const float* f = (const float*)aC;
#pragma unroll
            for (int i = 0; i < AV * 4; ++i) As[a0 + i][arow] = f[i];
            *(float4*)&Bs[brow][bcol]     = bC[0];
            *(float4*)&Bs[brow][bcol + 4] = bC[1];
        }
        __syncthreads();
        if (ch + 1 < nch) {
            const int kc = (ch + 1) << 4;
            const float* src = A + (size_t)(m0 + arow) * lda + kc + a0;
            aN[0] = *(const float4*)src;
            if (AV == 2) aN[1] = *(const float4*)(src + 4);
            const float* bsrc = W + (size_t)(kc + brow) * ldw + n0 + bcol;
            bN[0] = *(const float4*)bsrc;
            bN[1] = *(const float4*)(bsrc + 4);
        }
#pragma unroll
        for (int kk = 0; kk < 16; ++kk) {
            float afr[TM], bfr[8];
#pragma unroll
            for (int i = 0; i < TM; i += 4)
                *(float4*)&afr[i] = *(const float4*)&As[kk][ty * TM + i];
            *(float4*)&bfr[0] = *(const float4*)&Bs[kk][tx * 8];
            *(float4*)&bfr[4] = *(const float4*)&Bs[kk][tx * 8 + 4];
#pragma unroll
            for (int i = 0; i < TM; ++i)
#pragma unroll
                for (int j = 0; j < 8; ++j) acc[i][j] = fmaf(afr[i], bfr[j], acc[i][j]);
        }
        __syncthreads();
#pragma unroll
        for (int i = 0; i < AV; ++i) aC[i] = aN[i];
        bC[0] = bN[0]; bC[1] = bN[1];
    }
#pragma unroll
    for (int i = 0; i < TM; ++i) {
        const int row = m0 + ty * TM + i;
#pragma unroll
        for (int j = 0; j < 8; ++j) {
            const int col = n0 + tx * 8 + j;
            float v = acc[i][j] + bias[col];
            if (OUTBF) {
                Cb[(size_t)row * ldc + col] = f2bf(v);
            } else {
                C[(size_t)row * ldc + col] = v;
                if (OUT2) Cb[(size_t)row * ldc + col] = f2bf(v);
            }
        }
    }
}

// ---------------------------------------------------------------------------
// Weight packing (verified)
// ---------------------------------------------------------------------------
__global__ __launch_bounds__(256) void pack2(
    const float* __restrict__ msg_w1, const float* __restrict__ rmsg_w1,
    const float* __restrict__ msg_b1, const float* __restrict__ rmsg_b1,
    const float* __restrict__ enc_ew, const float* __restrict__ enc_eb,
    const float* __restrict__ msg_w2, const float* __restrict__ rmsg_w2,
    const float* __restrict__ upd_w1, const float* __restrict__ upd_w2,
    float* __restrict__ Wcomb, float* __restrict__ bcomb,
    ushort* __restrict__ WhpT, ushort* __restrict__ W2fT, ushort* __restrict__ W2rT,
    ushort* __restrict__ UW1T, ushort* __restrict__ UW2T)
{
    const int gid = blockIdx.x, tid = threadIdx.x;
    if (gid < 64) {
        const int idx = gid * 256 + tid;
        const int a = idx >> 9, n = idx & 511;
        const float* Wsrc = (n < 256) ? msg_w1 : rmsg_w1;
        const int nc = n & 255;
        float s = 0.f;
        for (int j = 0; j < 128; ++j)
            s = fmaf(enc_ew[a * 128 + j], Wsrc[(256 + j) * 256 + nc], s);
        Wcomb[idx] = s;
    } else if (gid < 66) {
        const int n = (gid - 64) * 256 + tid;
        const float* Wsrc = (n < 256) ? msg_w1 : rmsg_w1;
        const float* bsrc = (n < 256) ? msg_b1 : rmsg_b1;
        const int nc = n & 255;
        float s = bsrc[nc];
        for (int j = 0; j < 128; ++j)
            s = fmaf(enc_eb[j], Wsrc[(256 + j) * 256 + nc], s);
        bcomb[n] = s;
    } else if (gid < 578) {
        const int idx = (gid - 66) * 256 + tid;
        const int n = idx >> 7, k = idx & 127;
        const float* Wsrc = (n < 512) ? msg_w1 : rmsg_w1;
        const int part = (n >> 8) & 1, col = n & 255;
        WhpT[idx] = f2bf(Wsrc[(part * 128 + k) * 256 + col]);
    } else if (gid < 706) {
        const int idx = (gid - 578) * 256 + tid;
        const int n = idx >> 8, k = idx & 255;
        W2fT[idx] = f2bf(msg_w2[k * 128 + n]);
    } else if (gid < 834) {
        const int idx = (gid - 706) * 256 + tid;
        const int n = idx >> 8, k = idx & 255;
        W2rT[idx] = f2bf(rmsg_w2[k * 128 + n]);
    } else if (gid < 1090) {
        const int idx = (gid - 834) * 256 + tid;
        const int n = idx >> 8, k = idx & 255;
        UW1T[idx] = f2bf(upd_w1[k * 256 + n]);
    } else {
        const int idx = (gid - 1090) * 256 + tid;
        const int n = idx >> 8, k = idx & 255;
        UW2T[idx] = f2bf(upd_w2[k * 128 + n]);
    }
}

// ---------------------------------------------------------------------------
// Node head (verified)
// ---------------------------------------------------------------------------
__global__ __launch_bounds__(256) void node_kernel(
    const float* __restrict__ h,
    const float* __restrict__ w1, const float* __restrict__ b1,
    const float* __restrict__ w2, const float* __restrict__ b2,
    const int* __restrict__ qsz, const int* __restrict__ csz,
    float* __restrict__ plan_out, float* __restrict__ loss_out)
{
    __shared__ float qn[32][128];
    __shared__ float cn[32][128];
    __shared__ float t1[32][64];
    __shared__ float mq[32][68];
    __shared__ float mc[32][68];
    __shared__ float la[32][33];
    __shared__ float red[4];
    const int bb = blockIdx.x;
    const int tid = threadIdx.x;
    const int qs = qsz[bb], cs = csz[bb];
    for (int u = tid * 4; u < 4096; u += 1024) {
        const int p = u >> 7, d = u & 127;
        float4 zq = make_float4(0.f, 0.f, 0.f, 0.f), zc = zq;
        if (p < NPG) {
            zq = *(const float4*)(h + (size_t)((2 * bb) * NPG + p) * 128 + d);
            zc = *(const float4*)(h + (size_t)((2 * bb + 1) * NPG + p) * 128 + d);
        }
        *(float4*)&qn[p][d] = zq;
        *(float4*)&cn[p][d] = zc;
    }
    __syncthreads();
    const int col = tid & 63;
    const int rg  = tid >> 6;
    for (int s = 0; s < 2; ++s) {
        const float (*src)[128] = s ? cn : qn;
        float (*dst)[68] = s ? mc : mq;
        const int sz = s ? cs : qs;
        float a8[8];
#pragma unroll
        for (int u = 0; u < 8; ++u) a8[u] = b1[col];
        for (int k = 0; k < 128; ++k) {
            const float wv = w1[k * 64 + col];
#pragma unroll
            for (int u = 0; u < 8; ++u) a8[u] = fmaf(src[rg + 4 * u][k], wv, a8[u]);
        }
#pragma unroll
        for (int u = 0; u < 8; ++u) t1[rg + 4 * u][col] = fmaxf(a8[u], 0.f);
        __syncthreads();
#pragma unroll
        for (int u = 0; u < 8; ++u) a8[u] = b2[col];
        for (int k = 0; k < 64; ++k) {
            const float wv = w2[k * 64 + col];
#pragma unroll
            for (int u = 0; u < 8; ++u) a8[u] = fmaf(t1[rg + 4 * u][k], wv, a8[u]);
        }
#pragma unroll
        for (int u = 0; u < 8; ++u) {
            const int r = rg + 4 * u;
            dst[r][col] = (r < sz) ? a8[u] : 0.f;
        }
        __syncthreads();
    }
    {
        const int q = tid >> 3, cg = tid & 7;
#pragma unroll
        for (int u = 0; u < 4; ++u) {
            const int c = cg + 8 * u;
            float s = 0.f;
            for (int d = 0; d < 64; ++d) s = fmaf(mq[q][d], mc[c][d], s);
            la[q][c] = s * TEMPINV;
        }
    }
    __syncthreads();
    const int l8 = tid & 7, rq = tid >> 3;
    for (int it = 0; it < SINK_ITERS; ++it) {
        {
            float x[4];
#pragma unroll
            for (int u = 0; u < 4; ++u) x[u] = la[rq][l8 * 4 + u];
            float m = fmaxf(fmaxf(x[0], x[1]), fmaxf(x[2], x[3]));
            m = fmaxf(m, __shfl_xor(m, 1));
            m = fmaxf(m, __shfl_xor(m, 2));
            m = fmaxf(m, __shfl_xor(m, 4));
            float s = __expf(x[0] - m) + __expf(x[1] - m) + __expf(x[2] - m) + __expf(x[3] - m);
            s += __shfl_xor(s, 1);
            s += __shfl_xor(s, 2);
            s += __shfl_xor(s, 4);
            const float lse = m + __logf(s);
#pragma unroll
            for (int u = 0; u < 4; ++u) la[rq][l8 * 4 + u] = x[u] - lse;
        }
        __syncthreads();
        {
            float x[4];
#pragma unroll
            for (int u = 0; u < 4; ++u) x[u] = la[l8 * 4 + u][rq];
            float m = fmaxf(fmaxf(x[0], x[1]), fmaxf(x[2], x[3]));
            m = fmaxf(m, __shfl_xor(m, 1));
            m = fmaxf(m, __shfl_xor(m, 2));
            m = fmaxf(m, __shfl_xor(m, 4));
            float s = __expf(x[0] - m) + __expf(x[1] - m) + __expf(x[2] - m) + __expf(x[3] - m);
            s += __shfl_xor(s, 1);
            s += __shfl_xor(s, 2);
            s += __shfl_xor(s, 4);
            const float lse = m + __logf(s);
#pragma unroll
            for (int u = 0; u < 4; ++u) la[l8 * 4 + u][rq] = x[u] - lse;
        }
        __syncthreads();
    }
    for (int u = tid; u < 1024; u += 256) {
        const int q = u >> 5, c = u & 31;
        const float p = __expf(la[q][c]);
        la[q][c] = p;
        plan_out[(size_t)bb * 1024 + u] = p;
    }
    __syncthreads();
    float lsum = 0.f;
    {
        const int q = tid >> 3, dg = tid & 7;
        for (int u = 0; u < 16; ++u) {
            const int d = dg + 8 * u;
            float pc = 0.f;
#pragma unroll
            for (int c = 0; c < 32; ++c) pc = fmaf(la[q][c], cn[c][d], pc);
            lsum += fmaxf(qn[q][d] - pc, 0.f);
        }
    }
#pragma unroll
    for (int off = 1; off < 64; off <<= 1) lsum += __shfl_xor(lsum, off);
    if ((tid & 63) == 0) red[tid >> 6] = lsum;
    __syncthreads();
    if (tid == 0) loss_out[bb] = -(red[0] + red[1] + red[2] + red[3]);
}

// ---------------------------------------------------------------------------
// Edge head (verified)
// ---------------------------------------------------------------------------
__global__ __launch_bounds__(256) void edge_kernel(
    const float* __restrict__ plan, const float* __restrict__ EM,
    const int* __restrict__ from_idx, const int* __restrict__ to_idx,
    float* __restrict__ loss_out)
{
    __shared__ float T[32][33];
    __shared__ float la[64][65];
    __shared__ float ce[64][128];
    __shared__ int qf[64], qt[64], cfi[64], cti[64];
    __shared__ float red[4];
    const int bb = blockIdx.x;
    const int tid = threadIdx.x;
    for (int u = tid; u < 1024; u += 256) T[u >> 5][u & 31] = plan[(size_t)bb * 1024 + u];
    if (tid < 64) {
        const int gq = 2 * bb, gc = 2 * bb + 1;
        qf[tid]  = from_idx[gq * 64 + tid] - gq * NPG;
        qt[tid]  = to_idx  [gq * 64 + tid] - gq * NPG;
        cfi[tid] = from_idx[gc * 64 + tid] - gc * NPG;
        cti[tid] = to_idx  [gc * 64 + tid] - gc * NPG;
    }
    {
        const int gc = 2 * bb + 1;
        for (int u = tid * 4; u < 8192; u += 1024) {
            const int i = u >> 7, d = u & 127;
            *(float4*)&ce[i][d] = *(const float4*)(EM + (size_t)(gc * 64 + i) * 128 + d);
        }
    }
    __syncthreads();
    {
        const int i = tid >> 2, jg = tid & 3;
        const int a = qf[i], b_ = qt[i];
#pragma unroll
        for (int u = 0; u < 16; ++u) {
            const int j = jg * 16 + u;
            const float s = T[a][cfi[j]] * T[b_][cti[j]] + T[a][cti[j]] * T[b_][cfi[j]];
            la[i][j] = s * TEMPINV;
        }
    }
    __syncthreads();
    const int l4 = tid & 3, rr = tid >> 2;
    for (int it = 0; it < SINK_ITERS; ++it) {
        {
            float x[16];
#pragma unroll
            for (int u = 0; u < 16; ++u) x[u] = la[rr][l4 * 16 + u];
            float m = x[0];
#pragma unroll
            for (int u = 1; u < 16; ++u) m = fmaxf(m, x[u]);
            m = fmaxf(m, __shfl_xor(m, 1));
            m = fmaxf(m, __shfl_xor(m, 2));
            float s = 0.f;
#pragma unroll
            for (int u = 0; u < 16; ++u) s += __expf(x[u] - m);
            s += __shfl_xor(s, 1);
            s += __shfl_xor(s, 2);
            const float lse = m + __logf(s);
#pragma unroll
            for (int u = 0; u < 16; ++u) la[rr][l4 * 16 + u] = x[u] - lse;
        }
        __syncthreads();
        {
            float x[16];
#pragma unroll
            for (int u = 0; u < 16; ++u) x[u] = la[l4 * 16 + u][rr];
            float m = x[0];
#pragma unroll
            for (int u = 1; u < 16; ++u) m = fmaxf(m, x[u]);
            m = fmaxf(m, __shfl_xor(m, 1));
            m = fmaxf(m, __shfl_xor(m, 2));
            float s = 0.f;
#pragma unroll
            for (int u = 0; u < 16; ++u) s += __expf(x[u] - m);
            s += __shfl_xor(s, 1);
            s += __shfl_xor(s, 2);
            const float lse = m + __logf(s);
#pragma unroll
            for (int u = 0; u < 16; ++u) la[l4 * 16 + u][rr] = x[u] - lse;
        }
        __syncthreads();
    }
    for (int u = tid; u < 4096; u += 256) la[u >> 6][u & 63] = __expf(la[u >> 6][u & 63]);
    __syncthreads();
    float lsum = 0.f;
    {
        const int q = tid >> 2, dg = tid & 3;
        const float* qe = EM + (size_t)((2 * bb) * 64 + q) * 128;
        for (int u = 0; u < 32; ++u) {
            const int d = dg + 4 * u;
            float pc = 0.f;
            for (int c = 0; c < 64; ++c) pc = fmaf(la[q][c], ce[c][d], pc);
            lsum += fmaxf(qe[d] - pc, 0.f);
        }
    }
#pragma unroll
    for (int off = 1; off < 64; off <<= 1) lsum += __shfl_xor(lsum, off);
    if ((tid & 63) == 0) red[tid >> 6] = lsum;
    __syncthreads();
    if (tid == 0) loss_out[bb] -= CW * (red[0] + red[1] + red[2] + red[3]);
}

// ---------------------------------------------------------------------------
extern "C" void kernel_launch(void* const* d_in, const int* in_sizes, int n_in,
                              void* d_out, int out_size, void* d_ws, size_t ws_size,
                              hipStream_t stream)
{
    const float* node_features = (const float*)d_in[0];
    const float* edge_features = (const float*)d_in[1];
    const float* enc_nw  = (const float*)d_in[2];
    const float* enc_nb  = (const float*)d_in[3];
    const float* enc_ew  = (const float*)d_in[4];
    const float* enc_eb  = (const float*)d_in[5];
    const float* msg_w1  = (const float*)d_in[6];
    const float* msg_b1  = (const float*)d_in[7];
    const float* msg_w2  = (const float*)d_in[8];
    const float* msg_b2  = (const float*)d_in[9];
    const float* rmsg_w1 = (const float*)d_in[10];
    const float* rmsg_b1 = (const float*)d_in[11];
    const float* rmsg_w2 = (const float*)d_in[12];
    const float* rmsg_b2 = (const float*)d_in[13];
    const float* upd_w1  = (const float*)d_in[14];
    const float* upd_b1  = (const float*)d_in[15];
    const float* upd_w2  = (const float*)d_in[16];
    const float* upd_b2  = (const float*)d_in[17];
    const float* sk_w1   = (const float*)d_in[18];
    const float* sk_b1   = (const float*)d_in[19];
    const float* sk_w2   = (const float*)d_in[20];
    const float* sk_b2   = (const float*)d_in[21];
    const int* from_idx  = (const int*)d_in[22];
    const int* to_idx    = (const int*)d_in[23];
    const int* qsizes    = (const int*)d_in[24];
    const int* csizes    = (const int*)d_in[25];
    float* out = (float*)d_out;

    float* ws    = (float*)d_ws;
    float* h     = ws;                      // NN*128 fp32
    float* EM    = h + 1835008;             // NE*128 fp32
    float* plan  = EM + 4194304;            // NB*1024
    float* Wcomb = plan + 262144;           // 32*512
    float* bcomb = Wcomb + 16384;           // 512
    ushort* h_bf   = (ushort*)(bcomb + 512);    // NN*128
    ushort* HP     = h_bf + 1835008;            // NN*1024
    ushort* EC     = HP + 14680064;             // NE*512
    ushort* agg_bf = EC + 16777216;             // NN*128
    ushort* WhpT   = agg_bf + 1835008;          // 1024*128
    ushort* W2fT   = WhpT + 131072;             // 128*256
    ushort* W2rT   = W2fT + 32768;              // 128*256
    ushort* UW1T   = W2rT + 32768;              // 256*256
    ushort* UW2T   = UW1T + 65536;              // 128*256

    const dim3 blk(256);

    pack2<<<1218, blk, 0, stream>>>(msg_w1, rmsg_w1, msg_b1, rmsg_b1,
                                    enc_ew, enc_eb, msg_w2, rmsg_w2, upd_w1, upd_w2,
                                    Wcomb, bcomb, WhpT, W2fT, W2rT, UW1T, UW2T);
    gemm2<4, false, true><<<dim3(NN / 64, 1), blk, 0, stream>>>(
        node_features, 32, 32, enc_nw, 128, enc_nb, h, h_bf, 128);
    gemm2<8, true, false><<<dim3(NE / 128, 4), blk, 0, stream>>>(
        edge_features, 32, 32, Wcomb, 512, bcomb, nullptr, EC, 512);

    for (int step = 0; step < 3; ++step) {
        mfma_gemm<4, false, false, true, false><<<dim3(112, 8), blk, 0, stream>>>(
            h_bf, nullptr, 128, WhpT, nullptr, nullptr, HP, 1024);
        msg_fused<true><<<dim3(NG), blk, 0, stream>>>(
            HP, EC, W2fT, W2rT, msg_b2, rmsg_b2, from_idx, to_idx, agg_bf, nullptr);
        upd_fused<<<dim3(NN / 16), blk, 0, stream>>>(
            agg_bf, h_bf, UW1T, upd_b1, UW2T, upd_b2, h, h_bf);
    }

    mfma_gemm<4, false, false, true, false><<<dim3(112, 8), blk, 0, stream>>>(
        h_bf, nullptr, 128, WhpT, nullptr, nullptr, HP, 1024);
    msg_fused<false><<<dim3(NG), blk, 0, stream>>>(
        HP, EC, W2fT, W2rT, msg_b2, rmsg_b2, from_idx, to_idx, nullptr, EM);

    node_kernel<<<NB, blk, 0, stream>>>(
        h, sk_w1, sk_b1, sk_w2, sk_b2, qsizes, csizes, plan, out);
    edge_kernel<<<NB, blk, 0, stream>>>(
        plan, EM, from_idx, to_idx, out);
}

// Round 6
// 593.325 us; speedup vs baseline: 3.1820x; 1.0437x over previous
//
#include <hip/hip_runtime.h>
#include <math.h>

#define NPG 28
#define EPG 64
#define NB  256
#define NG  512
#define NN  14336
#define NE  32768
#define TEMPINV 10.0f
#define SINK_ITERS 20
#define CW 0.9f

typedef unsigned int uint;
typedef unsigned short ushort;
typedef __attribute__((ext_vector_type(8))) __bf16 bf16x8;
typedef __attribute__((ext_vector_type(4))) float f32x4;

__device__ __forceinline__ ushort f2bf(float x) {
    uint u = __float_as_uint(x);
    u += 0x7fffu + ((u >> 16) & 1u);
    return (ushort)(u >> 16);
}
__device__ __forceinline__ float bflo(uint w) { return __uint_as_float(w << 16); }
__device__ __forceinline__ float bfhi(uint w) { return __uint_as_float(w & 0xffff0000u); }
__device__ __forceinline__ uint relu_sum_pk(uint w1, uint w2, uint w3) {
    float lo = fmaxf(bflo(w1) + bflo(w2) + bflo(w3), 0.f);
    float hi = fmaxf(bfhi(w1) + bfhi(w2) + bfhi(w3), 0.f);
    return (uint)f2bf(lo) | ((uint)f2bf(hi) << 16);
}
__device__ __forceinline__ f32x4 mfma16(bf16x8 a, bf16x8 b, f32x4 c) {
    return __builtin_amdgcn_mfma_f32_16x16x32_bf16(a, b, c, 0, 0, 0);
}

// ---------------------------------------------------------------------------
// Fused message kernel v3: one block = one graph. Fuses HP = h@Whp (MFMA into
// LDS, per-pass 512-col half), then the msg layer-2 GEMM with A built from
// LDS HP gathers + coalesced EC2 reads. SEG: LDS segment-sum -> agg bf16.
// EMIT: both passes share acc registers -> EM fp32.
// LDS: HPs 29.1KB + ht 8.7KB + acc_s 14.3KB (SEG) + idx ~0.5KB = 52.7KB.
// ---------------------------------------------------------------------------
template<bool SEG>
__global__ __launch_bounds__(256) void msg_fused(
    const ushort* __restrict__ h_bf, const ushort* __restrict__ EC2,
    const ushort* __restrict__ WhpL,
    const ushort* __restrict__ W2fL, const ushort* __restrict__ W2rL,
    const float* __restrict__ b2f, const float* __restrict__ b2r,
    const int* __restrict__ from_idx, const int* __restrict__ to_idx,
    ushort* __restrict__ agg, float* __restrict__ EM)
{
    __shared__ ushort HPs[NPG * 520];        // row stride 520 (1040B, 16B-aligned)
    __shared__ ushort ht[32 * 136];          // h tile, stride 136 (272B)
    __shared__ float acc_s[SEG ? NPG * 128 : 64];
    __shared__ int fl[64], tl[64];
    const int g = blockIdx.x;
    const int tid = threadIdx.x;
    const int w = tid >> 6, lane = tid & 63;
    const int li = lane & 15, quad = lane >> 4;

    if (tid < 64) {
        fl[tid] = from_idx[g * 64 + tid] - g * NPG;
        tl[tid] = to_idx[g * 64 + tid] - g * NPG;
    }
    {   // stage h rows (contiguous, coalesced)
        const ushort* src = h_bf + (size_t)g * (NPG * 128);
        for (int u = tid; u < 448; u += 256)
            *(uint4*)&ht[(u >> 4) * 136 + (u & 15) * 8] = *(const uint4*)(src + u * 8);
        if (tid < 68) *(uint4*)&ht[NPG * 136 + tid * 8] = make_uint4(0u, 0u, 0u, 0u);
    }
    if (SEG) {
        for (int u = tid; u < NPG * 128; u += 256) acc_s[u] = 0.f;
    }
    __syncthreads();

    // cache h a-frags in registers (reused for both HP halves)
    uint4 ha[2][4];
#pragma unroll
    for (int mi = 0; mi < 2; ++mi)
#pragma unroll
        for (int kb = 0; kb < 4; ++kb)
            ha[mi][kb] = *(const uint4*)&ht[(mi * 16 + li) * 136 + kb * 32 + quad * 8];

    f32x4 acc[4][2];
#pragma unroll
    for (int i = 0; i < 4; ++i)
#pragma unroll
        for (int j = 0; j < 2; ++j) acc[i][j] = f32x4{0.f, 0.f, 0.f, 0.f};

    for (int p = 0; p < 2; ++p) {
        {   // ---- HP half-p compute: global cols [p*512, p*512+512) -> HPs
            const int colw = w * 128;
#pragma unroll
            for (int ni = 0; ni < 8; ++ni) {
                const int col = colw + ni * 16 + li;         // local col [0,512)
                const ushort* pb = WhpL + (size_t)(p * 512 + col) * 32 + quad * 8;
                f32x4 c0 = f32x4{0.f, 0.f, 0.f, 0.f};
                f32x4 c1 = f32x4{0.f, 0.f, 0.f, 0.f};
#pragma unroll
                for (int kb = 0; kb < 4; ++kb) {
                    const bf16x8 b = __builtin_bit_cast(bf16x8,
                        *(const uint4*)(pb + (size_t)kb * 32768));
                    c0 = mfma16(__builtin_bit_cast(bf16x8, ha[0][kb]), b, c0);
                    c1 = mfma16(__builtin_bit_cast(bf16x8, ha[1][kb]), b, c1);
                }
#pragma unroll
                for (int r = 0; r < 4; ++r) {
                    const int r0 = quad * 4 + r;
                    HPs[r0 * 520 + col] = f2bf(c0[r]);
                    const int r1 = 16 + quad * 4 + r;
                    if (r1 < NPG) HPs[r1 * 520 + col] = f2bf(c1[r]);
                }
            }
        }
        __syncthreads();

        if (SEG && p == 1) {
#pragma unroll
            for (int i = 0; i < 4; ++i)
#pragma unroll
                for (int j = 0; j < 2; ++j) acc[i][j] = f32x4{0.f, 0.f, 0.f, 0.f};
        }

        // ---- pass-p layer-2 GEMM (K=256, out 64x32 per wave over 64 edges)
        int ad1[4], ad2[4], ade[4];
#pragma unroll
        for (int mi = 0; mi < 4; ++mi) {
            const int e = mi * 16 + li;
            const int i1 = p ? tl[e] : fl[e];
            const int i2 = p ? fl[e] : tl[e];
            ad1[mi] = i1 * 520 + quad * 8;
            ad2[mi] = i2 * 520 + 256 + quad * 8;
            ade[mi] = e * 32 + quad * 8;
        }
        const ushort* ecb = EC2 + (size_t)(g * 2 + p) * 16384;
        const ushort* W2L = p ? W2rL : W2fL;
        const ushort* pb0 = W2L + (size_t)(w * 32 + li) * 32 + quad * 8;
        const ushort* pb1 = W2L + (size_t)(w * 32 + 16 + li) * 32 + quad * 8;
#pragma unroll
        for (int kb = 0; kb < 8; ++kb) {
            const bf16x8 b0 = __builtin_bit_cast(bf16x8, *(const uint4*)(pb0 + (size_t)kb * 4096));
            const bf16x8 b1 = __builtin_bit_cast(bf16x8, *(const uint4*)(pb1 + (size_t)kb * 4096));
            bf16x8 a[4];
#pragma unroll
            for (int mi = 0; mi < 4; ++mi) {
                const uint4 u1 = *(const uint4*)&HPs[ad1[mi] + kb * 32];
                const uint4 u2 = *(const uint4*)&HPs[ad2[mi] + kb * 32];
                const uint4 ue = *(const uint4*)(ecb + kb * 2048 + ade[mi]);
                uint4 o;
                o.x = relu_sum_pk(u1.x, u2.x, ue.x);
                o.y = relu_sum_pk(u1.y, u2.y, ue.y);
                o.z = relu_sum_pk(u1.z, u2.z, ue.z);
                o.w = relu_sum_pk(u1.w, u2.w, ue.w);
                a[mi] = __builtin_bit_cast(bf16x8, o);
            }
#pragma unroll
            for (int mi = 0; mi < 4; ++mi) {
                acc[mi][0] = mfma16(a[mi], b0, acc[mi][0]);
                acc[mi][1] = mfma16(a[mi], b1, acc[mi][1]);
            }
        }

        if (SEG) {
            const int* targ = p ? fl : tl;
            const float* bias = p ? b2r : b2f;
            const int n0 = w * 32;
            const float bv0 = bias[n0 + li], bv1 = bias[n0 + 16 + li];
#pragma unroll
            for (int mi = 0; mi < 4; ++mi)
#pragma unroll
                for (int r = 0; r < 4; ++r) {
                    const int loc = targ[mi * 16 + quad * 4 + r];
                    atomicAdd(&acc_s[loc * 128 + n0 + li], acc[mi][0][r] + bv0);
                    atomicAdd(&acc_s[loc * 128 + n0 + 16 + li], acc[mi][1][r] + bv1);
                }
        }
        __syncthreads();
    }

    if (SEG) {
        ushort* dst = agg + (size_t)g * (NPG * 128);
        for (int u = tid; u < NPG * 128; u += 256) dst[u] = f2bf(acc_s[u]);
    } else {
        const int n0 = w * 32;
        const float bv0 = b2f[n0 + li] + b2r[n0 + li];
        const float bv1 = b2f[n0 + 16 + li] + b2r[n0 + 16 + li];
#pragma unroll
        for (int mi = 0; mi < 4; ++mi)
#pragma unroll
            for (int r = 0; r < 4; ++r) {
                const int e = g * 64 + mi * 16 + quad * 4 + r;
                EM[(size_t)e * 128 + n0 + li] = acc[mi][0][r] + bv0;
                EM[(size_t)e * 128 + n0 + 16 + li] = acc[mi][1][r] + bv1;
            }
    }
}

// ---------------------------------------------------------------------------
// Fused update MLP (verified round-5 core): 16-row tiles.
// ---------------------------------------------------------------------------
__global__ __launch_bounds__(256) void upd_fused(
    const ushort* __restrict__ agg, const ushort* __restrict__ hbf,
    const ushort* __restrict__ UW1T, const float* __restrict__ b1,
    const ushort* __restrict__ UW2T, const float* __restrict__ b2,
    float* __restrict__ h, ushort* __restrict__ h_bf_out)
{
    __shared__ ushort hid_s[16][264];
    const int tid = threadIdx.x;
    const int w = tid >> 6, lane = tid & 63;
    const int li = lane & 15, quad = lane >> 4;
    const int m0 = blockIdx.x * 16;

    {   // phase 1
        const int n0 = w * 64;
        f32x4 acc[4];
#pragma unroll
        for (int j = 0; j < 4; ++j) acc[j] = f32x4{0.f, 0.f, 0.f, 0.f};
        const ushort* pb[4];
#pragma unroll
        for (int ni = 0; ni < 4; ++ni)
            pb[ni] = UW1T + (size_t)(n0 + ni * 16 + li) * 256 + quad * 8;
        const ushort* pa_a = agg + (size_t)(m0 + li) * 128 + quad * 8;
        const ushort* pa_h = hbf + (size_t)(m0 + li) * 128 + quad * 8;
#pragma unroll
        for (int kb = 0; kb < 8; ++kb) {
            const ushort* src = (kb < 4) ? (pa_a + kb * 32) : (pa_h + (kb - 4) * 32);
            const bf16x8 a = __builtin_bit_cast(bf16x8, *(const uint4*)src);
            bf16x8 b[4];
#pragma unroll
            for (int ni = 0; ni < 4; ++ni)
                b[ni] = __builtin_bit_cast(bf16x8, *(const uint4*)(pb[ni] + kb * 32));
#pragma unroll
            for (int ni = 0; ni < 4; ++ni) acc[ni] = mfma16(a, b[ni], acc[ni]);
        }
#pragma unroll
        for (int ni = 0; ni < 4; ++ni) {
            const float bv = b1[n0 + ni * 16 + li];
#pragma unroll
            for (int r = 0; r < 4; ++r)
                hid_s[quad * 4 + r][n0 + ni * 16 + li] =
                    f2bf(fmaxf(acc[ni][r] + bv, 0.f));
        }
    }
    __syncthreads();
    {   // phase 2
        const int n0 = w * 32;
        f32x4 acc[2];
#pragma unroll
        for (int j = 0; j < 2; ++j) acc[j] = f32x4{0.f, 0.f, 0.f, 0.f};
        const ushort* pb[2];
#pragma unroll
        for (int ni = 0; ni < 2; ++ni)
            pb[ni] = UW2T + (size_t)(n0 + ni * 16 + li) * 256 + quad * 8;
#pragma unroll
        for (int kb = 0; kb < 8; ++kb) {
            const bf16x8 a = __builtin_bit_cast(bf16x8,
                *(const uint4*)&hid_s[li][kb * 32 + quad * 8]);
            bf16x8 b[2];
#pragma unroll
            for (int ni = 0; ni < 2; ++ni)
                b[ni] = __builtin_bit_cast(bf16x8, *(const uint4*)(pb[ni] + kb * 32));
#pragma unroll
            for (int ni = 0; ni < 2; ++ni) acc[ni] = mfma16(a, b[ni], acc[ni]);
        }
#pragma unroll
        for (int ni = 0; ni < 2; ++ni) {
            const int ncol = n0 + ni * 16 + li;
            const float bv = b2[ncol];
#pragma unroll
            for (int r = 0; r < 4; ++r) {
                const int row = m0 + quad * 4 + r;
                const size_t idx = (size_t)row * 128 + ncol;
                const float nh = h[idx] + acc[ni][r] + bv;
                h[idx] = nh;
                h_bf_out[idx] = f2bf(nh);
            }
        }
    }
}

// ---------------------------------------------------------------------------
// fp32 tiled GEMM for K=32 encoders (verified core).
// OUT2: also write bf16. ECL: scatter into EC2 fragment layout.
// ---------------------------------------------------------------------------
template<int TM, bool OUTBF, bool OUT2, bool ECL>
__global__ __launch_bounds__(256) void gemm2(
    const float* __restrict__ A, int lda, int K,
    const float* __restrict__ W, int ldw, const float* __restrict__ bias,
    float* __restrict__ C, ushort* __restrict__ Cb, int ldc)
{
    constexpr int BM = TM * 16;
    constexpr int AV = BM / 64;
    __shared__ float As[16][BM + 4];
    __shared__ float Bs[16][132];
    const int tid = threadIdx.x;
    const int m0 = blockIdx.x * BM;
    const int n0 = blockIdx.y * 128;
    const int tx = tid & 15, ty = tid >> 4;
    const int arow = (AV == 2) ? (tid >> 1) : (tid >> 2);
    const int a0   = (AV == 2) ? ((tid & 1) * 8) : ((tid & 3) * 4);
    const int brow = ty;
    const int bcol = tx * 8;
    const int nch = K >> 4;

    float4 aC[AV], bC[2], aN[AV], bN[2];
    float acc[TM][8];
#pragma unroll
    for (int i = 0; i < TM; ++i)
#pragma unroll
        for (int j = 0; j < 8; ++j) acc[i][j] = 0.f;

    {
        const float* src = A + (size_t)(m0 + arow) * lda + a0;
        aC[0] = *(const float4*)src;
        if (AV == 2) aC[1] = *(const float4*)(src + 4);
        const float* bsrc = W + (size_t)brow * ldw + n0 + bcol;
        bC[0] = *(const float4*)bsrc;
        bC[1] = *(const float4*)(bsrc + 4);
    }

    for (int ch = 0; ch < nch; ++ch) {
        {
            const float* f = (const float*)aC;
#pragma unroll
            for (int i = 0; i < AV * 4; ++i) As[a0 + i][arow] = f[i];
            *(float4*)&Bs[brow][bcol]     = bC[0];
            *(float4*)&Bs[brow][bcol + 4] = bC[1];
        }
        __syncthreads();
        if (ch + 1 < nch) {
            const int kc = (ch + 1) << 4;
            const float* src = A + (size_t)(m0 + arow) * lda + kc + a0;
            aN[0] = *(const float4*)src;
            if (AV == 2) aN[1] = *(const float4*)(src + 4);
            const float* bsrc = W + (size_t)(kc + brow) * ldw + n0 + bcol;
            bN[0] = *(const float4*)bsrc;
            bN[1] = *(const float4*)(bsrc + 4);
        }
#pragma unroll
        for (int kk = 0; kk < 16; ++kk) {
            float afr[TM], bfr[8];
#pragma unroll
            for (int i = 0; i < TM; i += 4)
                *(float4*)&afr[i] = *(const float4*)&As[kk][ty * TM + i];
            *(float4*)&bfr[0] = *(const float4*)&Bs[kk][tx * 8];
            *(float4*)&bfr[4] = *(const float4*)&Bs[kk][tx * 8 + 4];
#pragma unroll
            for (int i = 0; i < TM; ++i)
#pragma unroll
                for (int j = 0; j < 8; ++j) acc[i][j] = fmaf(afr[i], bfr[j], acc[i][j]);
        }
        __syncthreads();
#pragma unroll
        for (int i = 0; i < AV; ++i) aC[i] = aN[i];
        bC[0] = bN[0]; bC[1] = bN[1];
    }
#pragma unroll
    for (int i = 0; i < TM; ++i) {
        const int row = m0 + ty * TM + i;
#pragma unroll
        for (int j = 0; j < 8; ++j) {
            const int col = n0 + tx * 8 + j;
            float v = acc[i][j] + bias[col];
            if (ECL) {
                const int gg = row >> 6, eloc = row & 63;
                const int p = col >> 8, kb = (col >> 5) & 7, jj = col & 31;
                Cb[(size_t)(((gg * 2 + p) * 8 + kb)) * 2048 + eloc * 32 + jj] = f2bf(v);
            } else if (OUTBF) {
                Cb[(size_t)row * ldc + col] = f2bf(v);
            } else {
                C[(size_t)row * ldc + col] = v;
                if (OUT2) Cb[(size_t)row * ldc + col] = f2bf(v);
            }
        }
    }
}

// ---------------------------------------------------------------------------
// Weight packing. WhpL: [(k>>5)][n][k&31] fragment layout (131072).
// W2fL/W2rL: [(k>>5)][n][k&31] (32768 each). UW1T/UW2T: N x K (unchanged).
// ---------------------------------------------------------------------------
__global__ __launch_bounds__(256) void pack2(
    const float* __restrict__ msg_w1, const float* __restrict__ rmsg_w1,
    const float* __restrict__ msg_b1, const float* __restrict__ rmsg_b1,
    const float* __restrict__ enc_ew, const float* __restrict__ enc_eb,
    const float* __restrict__ msg_w2, const float* __restrict__ rmsg_w2,
    const float* __restrict__ upd_w1, const float* __restrict__ upd_w2,
    float* __restrict__ Wcomb, float* __restrict__ bcomb,
    ushort* __restrict__ WhpL, ushort* __restrict__ W2fL, ushort* __restrict__ W2rL,
    ushort* __restrict__ UW1T, ushort* __restrict__ UW2T)
{
    const int gid = blockIdx.x, tid = threadIdx.x;
    if (gid < 64) {
        const int idx = gid * 256 + tid;
        const int a = idx >> 9, n = idx & 511;
        const float* Wsrc = (n < 256) ? msg_w1 : rmsg_w1;
        const int nc = n & 255;
        float s = 0.f;
        for (int j = 0; j < 128; ++j)
            s = fmaf(enc_ew[a * 128 + j], Wsrc[(256 + j) * 256 + nc], s);
        Wcomb[idx] = s;
    } else if (gid < 66) {
        const int n = (gid - 64) * 256 + tid;
        const float* Wsrc = (n < 256) ? msg_w1 : rmsg_w1;
        const float* bsrc = (n < 256) ? msg_b1 : rmsg_b1;
        const int nc = n & 255;
        float s = bsrc[nc];
        for (int j = 0; j < 128; ++j)
            s = fmaf(enc_eb[j], Wsrc[(256 + j) * 256 + nc], s);
        bcomb[n] = s;
    } else if (gid < 578) {
        const int idx = (gid - 66) * 256 + tid;        // [0,131072)
        const int n = idx >> 7, k = idx & 127;
        const float* Wsrc = (n < 512) ? msg_w1 : rmsg_w1;
        const int part = (n >> 8) & 1, col = n & 255;
        WhpL[(size_t)(k >> 5) * 32768 + n * 32 + (k & 31)] =
            f2bf(Wsrc[(part * 128 + k) * 256 + col]);
    } else if (gid < 706) {
        const int idx = (gid - 578) * 256 + tid;       // [0,32768)
        const int n = idx >> 8, k = idx & 255;
        W2fL[(size_t)(k >> 5) * 4096 + n * 32 + (k & 31)] = f2bf(msg_w2[k * 128 + n]);
    } else if (gid < 834) {
        const int idx = (gid - 706) * 256 + tid;
        const int n = idx >> 8, k = idx & 255;
        W2rL[(size_t)(k >> 5) * 4096 + n * 32 + (k & 31)] = f2bf(rmsg_w2[k * 128 + n]);
    } else if (gid < 1090) {
        const int idx = (gid - 834) * 256 + tid;
        const int n = idx >> 8, k = idx & 255;
        UW1T[idx] = f2bf(upd_w1[k * 256 + n]);
    } else {
        const int idx = (gid - 1090) * 256 + tid;
        const int n = idx >> 8, k = idx & 255;
        UW2T[idx] = f2bf(upd_w2[k * 128 + n]);
    }
}

// ---------------------------------------------------------------------------
// Node head (verified)
// ---------------------------------------------------------------------------
__global__ __launch_bounds__(256) void node_kernel(
    const float* __restrict__ h,
    const float* __restrict__ w1, const float* __restrict__ b1,
    const float* __restrict__ w2, const float* __restrict__ b2,
    const int* __restrict__ qsz, const int* __restrict__ csz,
    float* __restrict__ plan_out, float* __restrict__ loss_out)
{
    __shared__ float qn[32][128];
    __shared__ float cn[32][128];
    __shared__ float t1[32][64];
    __shared__ float mq[32][68];
    __shared__ float mc[32][68];
    __shared__ float la[32][33];
    __shared__ float red[4];
    const int bb = blockIdx.x;
    const int tid = threadIdx.x;
    const int qs = qsz[bb], cs = csz[bb];
    for (int u = tid * 4; u < 4096; u += 1024) {
        const int p = u >> 7, d = u & 127;
        float4 zq = make_float4(0.f, 0.f, 0.f, 0.f), zc = zq;
        if (p < NPG) {
            zq = *(const float4*)(h + (size_t)((2 * bb) * NPG + p) * 128 + d);
            zc = *(const float4*)(h + (size_t)((2 * bb + 1) * NPG + p) * 128 + d);
        }
        *(float4*)&qn[p][d] = zq;
        *(float4*)&cn[p][d] = zc;
    }
    __syncthreads();
    const int col = tid & 63;
    const int rg  = tid >> 6;
    for (int s = 0; s < 2; ++s) {
        const float (*src)[128] = s ? cn : qn;
        float (*dst)[68] = s ? mc : mq;
        const int sz = s ? cs : qs;
        float a8[8];
#pragma unroll
        for (int u = 0; u < 8; ++u) a8[u] = b1[col];
        for (int k = 0; k < 128; ++k) {
            const float wv = w1[k * 64 + col];
#pragma unroll
            for (int u = 0; u < 8; ++u) a8[u] = fmaf(src[rg + 4 * u][k], wv, a8[u]);
        }
#pragma unroll
        for (int u = 0; u < 8; ++u) t1[rg + 4 * u][col] = fmaxf(a8[u], 0.f);
        __syncthreads();
#pragma unroll
        for (int u = 0; u < 8; ++u) a8[u] = b2[col];
        for (int k = 0; k < 64; ++k) {
            const float wv = w2[k * 64 + col];
#pragma unroll
            for (int u = 0; u < 8; ++u) a8[u] = fmaf(t1[rg + 4 * u][k], wv, a8[u]);
        }
#pragma unroll
        for (int u = 0; u < 8; ++u) {
            const int r = rg + 4 * u;
            dst[r][col] = (r < sz) ? a8[u] : 0.f;
        }
        __syncthreads();
    }
    {
        const int q = tid >> 3, cg = tid & 7;
#pragma unroll
        for (int u = 0; u < 4; ++u) {
            const int c = cg + 8 * u;
            float s = 0.f;
            for (int d = 0; d < 64; ++d) s = fmaf(mq[q][d], mc[c][d], s);
            la[q][c] = s * TEMPINV;
        }
    }
    __syncthreads();
    const int l8 = tid & 7, rq = tid >> 3;
    for (int it = 0; it < SINK_ITERS; ++it) {
        {
            float x[4];
#pragma unroll
            for (int u = 0; u < 4; ++u) x[u] = la[rq][l8 * 4 + u];
            float m = fmaxf(fmaxf(x[0], x[1]), fmaxf(x[2], x[3]));
            m = fmaxf(m, __shfl_xor(m, 1));
            m = fmaxf(m, __shfl_xor(m, 2));
            m = fmaxf(m, __shfl_xor(m, 4));
            float s = __expf(x[0] - m) + __expf(x[1] - m) + __expf(x[2] - m) + __expf(x[3] - m);
            s += __shfl_xor(s, 1);
            s += __shfl_xor(s, 2);
            s += __shfl_xor(s, 4);
            const float lse = m + __logf(s);
#pragma unroll
            for (int u = 0; u < 4; ++u) la[rq][l8 * 4 + u] = x[u] - lse;
        }
        __syncthreads();
        {
            float x[4];
#pragma unroll
            for (int u = 0; u < 4; ++u) x[u] = la[l8 * 4 + u][rq];
            float m = fmaxf(fmaxf(x[0], x[1]), fmaxf(x[2], x[3]));
            m = fmaxf(m, __shfl_xor(m, 1));
            m = fmaxf(m, __shfl_xor(m, 2));
            m = fmaxf(m, __shfl_xor(m, 4));
            float s = __expf(x[0] - m) + __expf(x[1] - m) + __expf(x[2] - m) + __expf(x[3] - m);
            s += __shfl_xor(s, 1);
            s += __shfl_xor(s, 2);
            s += __shfl_xor(s, 4);
            const float lse = m + __logf(s);
#pragma unroll
            for (int u = 0; u < 4; ++u) la[l8 * 4 + u][rq] = x[u] - lse;
        }
        __syncthreads();
    }
    for (int u = tid; u < 1024; u += 256) {
        const int q = u >> 5, c = u & 31;
        const float p = __expf(la[q][c]);
        la[q][c] = p;
        plan_out[(size_t)bb * 1024 + u] = p;
    }
    __syncthreads();
    float lsum = 0.f;
    {
        const int q = tid >> 3, dg = tid & 7;
        for (int u = 0; u < 16; ++u) {
            const int d = dg + 8 * u;
            float pc = 0.f;
#pragma unroll
            for (int c = 0; c < 32; ++c) pc = fmaf(la[q][c], cn[c][d], pc);
            lsum += fmaxf(qn[q][d] - pc, 0.f);
        }
    }
#pragma unroll
    for (int off = 1; off < 64; off <<= 1) lsum += __shfl_xor(lsum, off);
    if ((tid & 63) == 0) red[tid >> 6] = lsum;
    __syncthreads();
    if (tid == 0) loss_out[bb] = -(red[0] + red[1] + red[2] + red[3]);
}

// ---------------------------------------------------------------------------
// Edge head (verified)
// ---------------------------------------------------------------------------
__global__ __launch_bounds__(256) void edge_kernel(
    const float* __restrict__ plan, const float* __restrict__ EM,
    const int* __restrict__ from_idx, const int* __restrict__ to_idx,
    float* __restrict__ loss_out)
{
    __shared__ float T[32][33];
    __shared__ float la[64][65];
    __shared__ float ce[64][128];
    __shared__ int qf[64], qt[64], cfi[64], cti[64];
    __shared__ float red[4];
    const int bb = blockIdx.x;
    const int tid = threadIdx.x;
    for (int u = tid; u < 1024; u += 256) T[u >> 5][u & 31] = plan[(size_t)bb * 1024 + u];
    if (tid < 64) {
        const int gq = 2 * bb, gc = 2 * bb + 1;
        qf[tid]  = from_idx[gq * 64 + tid] - gq * NPG;
        qt[tid]  = to_idx  [gq * 64 + tid] - gq * NPG;
        cfi[tid] = from_idx[gc * 64 + tid] - gc * NPG;
        cti[tid] = to_idx  [gc * 64 + tid] - gc * NPG;
    }
    {
        const int gc = 2 * bb + 1;
        for (int u = tid * 4; u < 8192; u += 1024) {
            const int i = u >> 7, d = u & 127;
            *(float4*)&ce[i][d] = *(const float4*)(EM + (size_t)(gc * 64 + i) * 128 + d);
        }
    }
    __syncthreads();
    {
        const int i = tid >> 2, jg = tid & 3;
        const int a = qf[i], b_ = qt[i];
#pragma unroll
        for (int u = 0; u < 16; ++u) {
            const int j = jg * 16 + u;
            const float s = T[a][cfi[j]] * T[b_][cti[j]] + T[a][cti[j]] * T[b_][cfi[j]];
            la[i][j] = s * TEMPINV;
        }
    }
    __syncthreads();
    const int l4 = tid & 3, rr = tid >> 2;
    for (int it = 0; it < SINK_ITERS; ++it) {
        {
            float x[16];
#pragma unroll
            for (int u = 0; u < 16; ++u) x[u] = la[rr][l4 * 16 + u];
            float m = x[0];
#pragma unroll
            for (int u = 1; u < 16; ++u) m = fmaxf(m, x[u]);
            m = fmaxf(m, __shfl_xor(m, 1));
            m = fmaxf(m, __shfl_xor(m, 2));
            float s = 0.f;
#pragma unroll
            for (int u = 0; u < 16; ++u) s += __expf(x[u] - m);
            s += __shfl_xor(s, 1);
            s += __shfl_xor(s, 2);
            const float lse = m + __logf(s);
#pragma unroll
            for (int u = 0; u < 16; ++u) la[rr][l4 * 16 + u] = x[u] - lse;
        }
        __syncthreads();
        {
            float x[16];
#pragma unroll
            for (int u = 0; u < 16; ++u) x[u] = la[l4 * 16 + u][rr];
            float m = x[0];
#pragma unroll
            for (int u = 1; u < 16; ++u) m = fmaxf(m, x[u]);
            m = fmaxf(m, __shfl_xor(m, 1));
            m = fmaxf(m, __shfl_xor(m, 2));
            float s = 0.f;
#pragma unroll
            for (int u = 0; u < 16; ++u) s += __expf(x[u] - m);
            s += __shfl_xor(s, 1);
            s += __shfl_xor(s, 2);
            const float lse = m + __logf(s);
#pragma unroll
            for (int u = 0; u < 16; ++u) la[l4 * 16 + u][rr] = x[u] - lse;
        }
        __syncthreads();
    }
    for (int u = tid; u < 4096; u += 256) la[u >> 6][u & 63] = __expf(la[u >> 6][u & 63]);
    __syncthreads();
    float lsum = 0.f;
    {
        const int q = tid >> 2, dg = tid & 3;
        const float* qe = EM + (size_t)((2 * bb) * 64 + q) * 128;
        for (int u = 0; u < 32; ++u) {
            const int d = dg + 4 * u;
            float pc = 0.f;
            for (int c = 0; c < 64; ++c) pc = fmaf(la[q][c], ce[c][d], pc);
            lsum += fmaxf(qe[d] - pc, 0.f);
        }
    }
#pragma unroll
    for (int off = 1; off < 64; off <<= 1) lsum += __shfl_xor(lsum, off);
    if ((tid & 63) == 0) red[tid >> 6] = lsum;
    __syncthreads();
    if (tid == 0) loss_out[bb] -= CW * (red[0] + red[1] + red[2] + red[3]);
}

// ---------------------------------------------------------------------------
extern "C" void kernel_launch(void* const* d_in, const int* in_sizes, int n_in,
                              void* d_out, int out_size, void* d_ws, size_t ws_size,
                              hipStream_t stream)
{
    const float* node_features = (const float*)d_in[0];
    const float* edge_features = (const float*)d_in[1];
    const float* enc_nw  = (const float*)d_in[2];
    const float* enc_nb  = (const float*)d_in[3];
    const float* enc_ew  = (const float*)d_in[4];
    const float* enc_eb  = (const float*)d_in[5];
    const float* msg_w1  = (const float*)d_in[6];
    const float* msg_b1  = (const float*)d_in[7];
    const float* msg_w2  = (const float*)d_in[8];
    const float* msg_b2  = (const float*)d_in[9];
    const float* rmsg_w1 = (const float*)d_in[10];
    const float* rmsg_b1 = (const float*)d_in[11];
    const float* rmsg_w2 = (const float*)d_in[12];
    const float* rmsg_b2 = (const float*)d_in[13];
    const float* upd_w1  = (const float*)d_in[14];
    const float* upd_b1  = (const float*)d_in[15];
    const float* upd_w2  = (const float*)d_in[16];
    const float* upd_b2  = (const float*)d_in[17];
    const float* sk_w1   = (const float*)d_in[18];
    const float* sk_b1   = (const float*)d_in[19];
    const float* sk_w2   = (const float*)d_in[20];
    const float* sk_b2   = (const float*)d_in[21];
    const int* from_idx  = (const int*)d_in[22];
    const int* to_idx    = (const int*)d_in[23];
    const int* qsizes    = (const int*)d_in[24];
    const int* csizes    = (const int*)d_in[25];
    float* out = (float*)d_out;

    float* ws    = (float*)d_ws;
    float* h     = ws;                          // NN*128 fp32
    float* EM    = h + (size_t)NN * 128;        // NE*128 fp32
    float* plan  = EM + (size_t)NE * 128;       // NB*1024
    float* Wcomb = plan + (size_t)NB * 1024;    // 32*512
    float* bcomb = Wcomb + 16384;               // 512
    ushort* h_bf = (ushort*)(bcomb + 512);      // NN*128
    ushort* EC2  = h_bf + (size_t)NN * 128;     // NE*512
    ushort* agg  = EC2 + (size_t)NE * 512;      // NN*128
    ushort* WhpL = agg + (size_t)NN * 128;      // 131072
    ushort* W2fL = WhpL + 131072;               // 32768
    ushort* W2rL = W2fL + 32768;                // 32768
    ushort* UW1T = W2rL + 32768;                // 65536
    ushort* UW2T = UW1T + 65536;                // 32768

    const dim3 blk(256);

    pack2<<<1218, blk, 0, stream>>>(msg_w1, rmsg_w1, msg_b1, rmsg_b1,
                                    enc_ew, enc_eb, msg_w2, rmsg_w2, upd_w1, upd_w2,
                                    Wcomb, bcomb, WhpL, W2fL, W2rL, UW1T, UW2T);
    // node encoder: h (fp32) + h_bf
    gemm2<4, false, true, false><<<dim3(NN / 64, 1), blk, 0, stream>>>(
        node_features, 32, 32, enc_nw, 128, enc_nb, h, h_bf, 128);
    // edge encoder folded with msg layer-1 edge slice -> EC2 fragment layout
    gemm2<8, false, false, true><<<dim3(NE / 128, 4), blk, 0, stream>>>(
        edge_features, 32, 32, Wcomb, 512, bcomb, nullptr, EC2, 512);

    for (int step = 0; step < 3; ++step) {
        msg_fused<true><<<dim3(NG), blk, 0, stream>>>(
            h_bf, EC2, WhpL, W2fL, W2rL, msg_b2, rmsg_b2, from_idx, to_idx,
            agg, nullptr);
        upd_fused<<<dim3(NN / 16), blk, 0, stream>>>(
            agg, h_bf, UW1T, upd_b1, UW2T, upd_b2, h, h_bf);
    }

    msg_fused<false><<<dim3(NG), blk, 0, stream>>>(
        h_bf, EC2, WhpL, W2fL, W2rL, msg_b2, rmsg_b2, from_idx, to_idx,
        nullptr, EM);

    node_kernel<<<NB, blk, 0, stream>>>(
        h, sk_w1, sk_b1, sk_w2, sk_b2, qsizes, csizes, plan, out);
    edge_kernel<<<NB, blk, 0, stream>>>(
        plan, EM, from_idx, to_idx, out);
}